// Round 1
// baseline (1223.519 us; speedup 1.0000x reference)
//
#include <hip/hip_runtime.h>
#include <math.h>

#define BB_ 2
#define HH 48
#define WW 48
#define LL 2304
#define CIN 96
#define DD 192
#define KK 4
#define NN 16
#define RR 6
#define NCH 24   // chunks
#define LC 96    // chunk length
#define COUT 192
#define OH 24
#define OW 24
#define OHW 576
#define EPSF 1e-5f

// ---------------- K1: per-pixel LN stats + folded weight prep ----------------
__global__ __launch_bounds__(256) void k_prep(const float* __restrict__ x,
                                              const float* __restrict__ g,
                                              const float* __restrict__ b,
                                              const float* __restrict__ inw,
                                              float* __restrict__ stats,
                                              float* __restrict__ Wg,
                                              float* __restrict__ sWg,
                                              float* __restrict__ sWb) {
  int bx = blockIdx.x;
  if (bx < 72) {
    int bb = bx / 36; int l0 = (bx % 36) * 64;
    int p = threadIdx.x >> 2, q = threadIdx.x & 3;
    int l = l0 + p;
    const float* xp = x + bb * CIN * LL + l;
    float s = 0.f, ss = 0.f;
    for (int c = q; c < CIN; c += 4) { float v = xp[c * LL]; s += v; ss += v * v; }
    s += __shfl_xor(s, 1, 64); s += __shfl_xor(s, 2, 64);
    ss += __shfl_xor(ss, 1, 64); ss += __shfl_xor(ss, 2, 64);
    if (q == 0) {
      float m = s / CIN; float var = ss / CIN - m * m;
      stats[(bb * LL + l) * 2 + 0] = m;
      stats[(bb * LL + l) * 2 + 1] = rsqrtf(var + EPSF);
    }
  } else {
    for (int e = threadIdx.x; e < 2 * DD; e += 256) {
      float swg = 0.f, swb = 0.f;
      for (int c = 0; c < CIN; c++) {
        float w = inw[e * CIN + c];
        float wg = w * g[c];
        Wg[e * CIN + c] = wg;
        swg += wg; swb += w * b[c];
      }
      sWg[e] = swg; sWb[e] = swb;
    }
  }
}

// ---------------- K2: in_proj GEMM (LN folded) -> xin (B,192,L), z (B,L,192) --
__global__ __launch_bounds__(256) void k_inproj(const float* __restrict__ x,
                                                const float* __restrict__ stats,
                                                const float* __restrict__ Wg,
                                                const float* __restrict__ sWg,
                                                const float* __restrict__ sWb,
                                                float* __restrict__ xin,
                                                float* __restrict__ z) {
  int bx = blockIdx.x; int bb = bx / 36; int l0 = (bx % 36) * 64;
  int tx = threadIdx.x & 63, ty = threadIdx.x >> 6;
  int e = blockIdx.y * 4 + ty;
  int l = l0 + tx;
  const float* xp = x + bb * CIN * LL + l;
  const float* wp = Wg + e * CIN;
  float acc = 0.f;
#pragma unroll 8
  for (int c = 0; c < CIN; c++) acc += wp[c] * xp[c * LL];
  float m = stats[(bb * LL + l) * 2], r = stats[(bb * LL + l) * 2 + 1];
  float val = r * (acc - m * sWg[e]) + sWb[e];
  if (e < DD) xin[(bb * DD + e) * LL + l] = val;
  else z[(bb * LL + l) * DD + (e - DD)] = val;
}

// ---------------- K3: depthwise 3x3 + silu -> xs in 4 directional layouts ----
__global__ __launch_bounds__(256) void k_dwconv(const float* __restrict__ xin,
                                                const float* __restrict__ wdw,
                                                const float* __restrict__ bdw,
                                                float* __restrict__ xs) {
  int idx = blockIdx.x * 256 + threadIdx.x;
  if (idx >= BB_ * DD * LL) return;
  int l = idx % LL; int d = (idx / LL) % DD; int bb = idx / (LL * DD);
  int h = l / WW, w = l % WW;
  const float* xp = xin + (bb * DD + d) * LL;
  const float* wq = wdw + d * 9;
  float acc = bdw[d];
#pragma unroll
  for (int kh = 0; kh < 3; kh++) {
    int ih = h + kh - 1; if (ih < 0 || ih >= HH) continue;
#pragma unroll
    for (int kw = 0; kw < 3; kw++) {
      int iw = w + kw - 1; if (iw < 0 || iw >= WW) continue;
      acc += xp[ih * WW + iw] * wq[kh * 3 + kw];
    }
  }
  float v = acc / (1.f + __expf(-acc)); // silu
  int lt = w * HH + h;
  xs[((bb * KK + 0) * DD + d) * LL + l] = v;
  xs[((bb * KK + 1) * DD + d) * LL + lt] = v;
  xs[((bb * KK + 2) * DD + d) * LL + (LL - 1 - l)] = v;
  xs[((bb * KK + 3) * DD + d) * LL + (LL - 1 - lt)] = v;
}

// ---------------- K4: x_proj (38x192) + delta=softplus(dt_w . dts + dt_b) ----
__global__ __launch_bounds__(256) void k_xproj(const float* __restrict__ xs,
                                               const float* __restrict__ xpw,
                                               const float* __restrict__ dtw,
                                               const float* __restrict__ dtb,
                                               float* __restrict__ Bsb,
                                               float* __restrict__ Csb,
                                               float* __restrict__ delta) {
  __shared__ float xls[DD * 64];
  __shared__ float dts[RR * 64];
  int bid = blockIdx.x;
  int tile = bid % 36; int bk = bid / 36; int k = bk % KK;
  int l0 = tile * 64;
  int tid = threadIdx.x;
  const float* xp = xs + bk * DD * LL;
  for (int i = tid; i < DD * 64; i += 256) { int d = i >> 6, l = i & 63; xls[i] = xp[d * LL + l0 + l]; }
  __syncthreads();
  int tx = tid & 63, ty = tid >> 6;
  for (int r = ty; r < RR + 2 * NN; r += 4) {
    const float* wr = xpw + (k * (RR + 2 * NN) + r) * DD;
    float acc = 0.f;
#pragma unroll 8
    for (int d = 0; d < DD; d++) acc += wr[d] * xls[(d << 6) | tx];
    if (r < RR) dts[(r << 6) | tx] = acc;
    else if (r < RR + NN) Bsb[(bk * NN + (r - RR)) * LL + l0 + tx] = acc;
    else Csb[(bk * NN + (r - RR - NN)) * LL + l0 + tx] = acc;
  }
  __syncthreads();
  for (int d = ty; d < DD; d += 4) {
    const float* wd = dtw + (k * DD + d) * RR;
    float acc = dtb[k * DD + d];
#pragma unroll
    for (int r = 0; r < RR; r++) acc += wd[r] * dts[(r << 6) | tx];
    float sp = acc > 20.f ? acc : log1pf(__expf(acc));
    delta[(bk * DD + d) * LL + l0 + tx] = sp;
  }
}

// ---------------- K5a: chunked scan pass 1: per-chunk P (decay prod), S ------
__global__ __launch_bounds__(256) void k_scan1(const float* __restrict__ delta,
                                               const float* __restrict__ xs,
                                               const float* __restrict__ Bsb,
                                               const float* __restrict__ A_logs,
                                               float* __restrict__ Pbuf,
                                               float* __restrict__ Sbuf) {
  int bid = blockIdx.x;                 // ((bk)*12+dg)*NCH + c
  int c = bid % NCH; int t0 = c * LC;
  int bkdg = bid / NCH;
  int dg = bkdg % 12; int bk = bkdg / 12; int k = bk % KK;
  int tid = threadIdx.x;
  int n = tid & 15;
  int dl = ((tid >> 6) << 2) | ((tid >> 4) & 3);
  int d = dg * 16 + dl;
  float A = -__expf(A_logs[(k * DD + d) * NN + n]);
  const float* dp = delta + (bk * DD + d) * LL;
  const float* xp = xs + (bk * DD + d) * LL;
  const float* bp = Bsb + (bk * NN + n) * LL;
  float h = 0.f, P = 1.f;
  for (int t = t0; t < t0 + LC; ++t) {
    float dt = dp[t], xv = xp[t], bv = bp[t];
    float dA = __expf(dt * A);
    h = dA * h + dt * bv * xv;
    P *= dA;
  }
  int chn = (bk * DD + d) * NN + n;
  Pbuf[c * 24576 + chn] = P;
  Sbuf[c * 24576 + chn] = h;
}

// ---------------- K5b: combine chunks serially -> h_init per chunk -----------
__global__ __launch_bounds__(256) void k_scan2(const float* __restrict__ Pbuf,
                                               const float* __restrict__ Sbuf,
                                               float* __restrict__ Hinit) {
  int idx = blockIdx.x * 256 + threadIdx.x; // 0..24575
  float h = 0.f;
  for (int c = 0; c < NCH; c++) {
    Hinit[c * 24576 + idx] = h;
    h = Pbuf[c * 24576 + idx] * h + Sbuf[c * 24576 + idx];
  }
}

// ---------------- K5c: pass 3: replay with h_init, emit ys (B,K,L,192) -------
__global__ __launch_bounds__(256) void k_scan3(const float* __restrict__ delta,
                                               const float* __restrict__ xs,
                                               const float* __restrict__ Bsb,
                                               const float* __restrict__ Csb,
                                               const float* __restrict__ A_logs,
                                               const float* __restrict__ Ds,
                                               const float* __restrict__ Hinit,
                                               float* __restrict__ ys) {
  int bid = blockIdx.x;
  int c = bid % NCH; int t0 = c * LC;
  int bkdg = bid / NCH;
  int dg = bkdg % 12; int bk = bkdg / 12; int k = bk % KK;
  int tid = threadIdx.x;
  int n = tid & 15;
  int dl = ((tid >> 6) << 2) | ((tid >> 4) & 3);
  int d = dg * 16 + dl;
  float A = -__expf(A_logs[(k * DD + d) * NN + n]);
  float Dv = Ds[k * DD + d];
  const float* dp = delta + (bk * DD + d) * LL;
  const float* xp = xs + (bk * DD + d) * LL;
  const float* bp = Bsb + (bk * NN + n) * LL;
  const float* cp = Csb + (bk * NN + n) * LL;
  int chn = (bk * DD + d) * NN + n;
  float h = Hinit[c * 24576 + chn];
  for (int t = t0; t < t0 + LC; ++t) {
    float dt = dp[t], xv = xp[t], bv = bp[t];
    float dA = __expf(dt * A);
    h = dA * h + dt * bv * xv;
    float yv = h * cp[t];
    yv += __shfl_xor(yv, 1, 64);
    yv += __shfl_xor(yv, 2, 64);
    yv += __shfl_xor(yv, 4, 64);
    yv += __shfl_xor(yv, 8, 64);
    if (n == 0) ys[(bk * LL + t) * DD + d] = yv + Dv * xv;
  }
}

// ---------------- K6a: gather 4 dirs + out_norm LN + silu(z) -> ya (B,192,L) -
__global__ __launch_bounds__(256) void k_combine(const float* __restrict__ ys,
                                                 const float* __restrict__ z,
                                                 const float* __restrict__ ong,
                                                 const float* __restrict__ onb,
                                                 float* __restrict__ ya) {
  __shared__ float yt[64 * 201];
  int bx = blockIdx.x; int bb = bx / 36; int l0 = (bx % 36) * 64;
  int tid = threadIdx.x;
  for (int i = tid; i < 64 * DD; i += 256) {
    int p = i / DD, d = i - p * DD;
    int l = l0 + p; int h = l / WW, w = l - h * WW;
    int t1 = w * HH + h;
    float v = ys[((bb * KK + 0) * LL + l) * DD + d]
            + ys[((bb * KK + 1) * LL + t1) * DD + d]
            + ys[((bb * KK + 2) * LL + (LL - 1 - l)) * DD + d]
            + ys[((bb * KK + 3) * LL + (LL - 1 - t1)) * DD + d];
    yt[p * 201 + d] = v;
  }
  __syncthreads();
  int p = tid >> 2, q = tid & 3;
  int l = l0 + p;
  float s = 0.f, ss = 0.f;
  for (int d = q * 48; d < q * 48 + 48; d++) { float v = yt[p * 201 + d]; s += v; ss += v * v; }
  s += __shfl_xor(s, 1, 64); s += __shfl_xor(s, 2, 64);
  ss += __shfl_xor(ss, 1, 64); ss += __shfl_xor(ss, 2, 64);
  float m = s / DD, var = ss / DD - m * m;
  float rr = rsqrtf(var + EPSF);
  const float* zp = z + (bb * LL + l) * DD;
  for (int d = q * 48; d < q * 48 + 48; d++) {
    float v = (yt[p * 201 + d] - m) * rr * ong[d] + onb[d];
    float zv = zp[d];
    yt[p * 201 + d] = v * zv / (1.f + __expf(-zv));
  }
  __syncthreads();
  for (int i = tid; i < 64 * DD; i += 256) {
    int d = i >> 6, p2 = i & 63;
    ya[(bb * DD + d) * LL + l0 + p2] = yt[p2 * 201 + d];
  }
}

// ---------------- K6b: out_proj GEMM + residual -> xm (B,96,48,48) -----------
__global__ __launch_bounds__(256) void k_outproj(const float* __restrict__ ya,
                                                 const float* __restrict__ wout,
                                                 const float* __restrict__ x,
                                                 float* __restrict__ xm) {
  int bx = blockIdx.x; int bb = bx / 36; int l0 = (bx % 36) * 64;
  int tx = threadIdx.x & 63, ty = threadIdx.x >> 6;
  int cc = blockIdx.y * 4 + ty;
  int l = l0 + tx;
  const float* yp = ya + bb * DD * LL + l;
  const float* wp = wout + cc * DD;
  float acc = 0.f;
#pragma unroll 8
  for (int d = 0; d < DD; d++) acc += yp[d * LL] * wp[d];
  xm[(bb * CIN + cc) * LL + l] = x[(bb * CIN + cc) * LL + l] + acc;
}

// ---------------- K7: conv 3x3 s2 (96->192) branch-3 stage a -----------------
__global__ __launch_bounds__(256) void k_conv3a(const float* __restrict__ xm,
                                                const float* __restrict__ w32,
                                                const float* __restrict__ b32,
                                                float* __restrict__ t3) {
  int bid = blockIdx.x;
  int bb = bid / COUT, co = bid % COUT;
  const float* wp = w32 + co * CIN * 9;
  float bias = b32[co];
  for (int o = threadIdx.x; o < OHW; o += 256) {
    int oh = o / OW, ow = o % OW;
    float acc = bias;
    for (int ci = 0; ci < CIN; ci++) {
      const float* xp = xm + (bb * CIN + ci) * LL;
      const float* wq = wp + ci * 9;
#pragma unroll
      for (int kh = 0; kh < 3; kh++) {
        int ih = 2 * oh + kh - 1; if (ih < 0 || ih >= HH) continue;
#pragma unroll
        for (int kw = 0; kw < 3; kw++) {
          int iw = 2 * ow + kw - 1; if (iw < 0 || iw >= WW) continue;
          acc += xp[ih * WW + iw] * wq[kh * 3 + kw];
        }
      }
    }
    t3[(bb * COUT + co) * OHW + o] = acc;
  }
}

// ---------------- K8: x1 / x2 / x3b + BN + PReLU -> out -----------------------
__global__ __launch_bounds__(256) void k_final(const float* __restrict__ xm,
                                               const float* __restrict__ t3,
                                               const float* __restrict__ w1,
                                               const float* __restrict__ b1,
                                               const float* __restrict__ w31,
                                               const float* __restrict__ b31,
                                               const float* __restrict__ w33,
                                               const float* __restrict__ b33,
                                               const float* __restrict__ bn_g,
                                               const float* __restrict__ bn_b,
                                               const float* __restrict__ bn_m,
                                               const float* __restrict__ bn_v,
                                               const float* __restrict__ prelu_a,
                                               float* __restrict__ out) {
  int bid = blockIdx.x;
  int bb = bid / 576, cc = bid % 576;
  float scale = rsqrtf(bn_v[cc] + EPSF) * bn_g[cc];
  float shift = bn_b[cc] - bn_m[cc] * scale;
  float aslope = prelu_a[0];
  for (int o = threadIdx.x; o < OHW; o += 256) {
    int oh = o / OW, ow = o % OW;
    float acc;
    if (cc < COUT) {
      int co = cc;
      acc = b1[co];
      const float* wp = w1 + co * CIN;
      const float* xp = xm + bb * CIN * LL + (2 * oh) * WW + 2 * ow;
#pragma unroll 8
      for (int ci = 0; ci < CIN; ci++) acc += xp[ci * LL] * wp[ci];
    } else if (cc < 2 * COUT) {
      int co = cc - COUT;
      acc = b31[co];
      const float* wp = w31 + co * CIN * 9;
      for (int ci = 0; ci < CIN; ci++) {
        const float* xp = xm + (bb * CIN + ci) * LL;
        const float* wq = wp + ci * 9;
#pragma unroll
        for (int kh = 0; kh < 3; kh++) {
          int ih = 2 * oh + kh - 1; if (ih < 0 || ih >= HH) continue;
#pragma unroll
          for (int kw = 0; kw < 3; kw++) {
            int iw = 2 * ow + kw - 1; if (iw < 0 || iw >= WW) continue;
            acc += xp[ih * WW + iw] * wq[kh * 3 + kw];
          }
        }
      }
    } else {
      int co = cc - 2 * COUT;
      acc = b33[co];
      const float* wp = w33 + co * COUT * 9;
      for (int ci = 0; ci < COUT; ci++) {
        const float* xp = t3 + (bb * COUT + ci) * OHW;
        const float* wq = wp + ci * 9;
#pragma unroll
        for (int kh = 0; kh < 3; kh++) {
          int ih = oh + kh - 1; if (ih < 0 || ih >= OH) continue;
#pragma unroll
          for (int kw = 0; kw < 3; kw++) {
            int iw = ow + kw - 1; if (iw < 0 || iw >= OW) continue;
            acc += xp[ih * OW + iw] * wq[kh * 3 + kw];
          }
        }
      }
    }
    float v = acc * scale + shift;
    out[(bb * 576 + cc) * OHW + o] = v > 0.f ? v : aslope * v;
  }
}

extern "C" void kernel_launch(void* const* d_in, const int* in_sizes, int n_in,
                              void* d_out, int out_size, void* d_ws, size_t ws_size,
                              hipStream_t stream) {
  const float* x        = (const float*)d_in[0];
  const float* ln_g     = (const float*)d_in[1];
  const float* ln_b     = (const float*)d_in[2];
  const float* in_proj_w= (const float*)d_in[3];
  const float* dwconv_w = (const float*)d_in[4];
  const float* dwconv_b = (const float*)d_in[5];
  const float* x_proj_w = (const float*)d_in[6];
  const float* dt_w     = (const float*)d_in[7];
  const float* dt_b     = (const float*)d_in[8];
  const float* A_logs   = (const float*)d_in[9];
  const float* Ds       = (const float*)d_in[10];
  const float* out_norm_g = (const float*)d_in[11];
  const float* out_norm_b = (const float*)d_in[12];
  const float* out_proj_w = (const float*)d_in[13];
  const float* w1  = (const float*)d_in[14];
  const float* b1  = (const float*)d_in[15];
  const float* w31 = (const float*)d_in[16];
  const float* b31 = (const float*)d_in[17];
  const float* w32 = (const float*)d_in[18];
  const float* b32 = (const float*)d_in[19];
  const float* w33 = (const float*)d_in[20];
  const float* b33 = (const float*)d_in[21];
  const float* bn_g = (const float*)d_in[22];
  const float* bn_b = (const float*)d_in[23];
  const float* bn_m = (const float*)d_in[24];
  const float* bn_v = (const float*)d_in[25];
  const float* prelu_a = (const float*)d_in[26];

  float* ws = (float*)d_ws;
  // layout (floats); unions noted
  float* ya    = ws;                    // 884736 (live K6a..K6b)
  float* xin   = ws + 884736;           // 884736 (live K2..K3)
  float* xm    = xin;                   // 442368 (live K6b..K8; xin dead)
  float* t3    = xin + 442368;          // 221184 (live K7..K8)
  float* z     = ws + 1769472;          // 884736
  float* xs    = ws + 2654208;          // 3538944
  float* delta = ws + 6193152;          // 3538944
  float* ys    = ws + 9732096;          // 3538944 (P/S union: dead before pass3 writes)
  float* Pbuf  = ys;                    // 589824
  float* Sbuf  = ys + 589824;           // 589824
  float* Bsb   = ws + 13271040;         // 294912
  float* Csb   = ws + 13565952;         // 294912
  float* Hinit = ws + 13860864;         // 589824
  float* Wg    = ws + 14450688;         // 36864
  float* sWg   = ws + 14487552;         // 384
  float* sWb   = ws + 14487936;         // 384
  float* stats = ws + 14488320;         // 9216  (total 14497536 floats = 58 MB)
  float* out = (float*)d_out;

  k_prep<<<73, 256, 0, stream>>>(x, ln_g, ln_b, in_proj_w, stats, Wg, sWg, sWb);
  k_inproj<<<dim3(72, 96), 256, 0, stream>>>(x, stats, Wg, sWg, sWb, xin, z);
  k_dwconv<<<3456, 256, 0, stream>>>(xin, dwconv_w, dwconv_b, xs);
  k_xproj<<<288, 256, 0, stream>>>(xs, x_proj_w, dt_w, dt_b, Bsb, Csb, delta);
  k_scan1<<<2304, 256, 0, stream>>>(delta, xs, Bsb, A_logs, Pbuf, Sbuf);
  k_scan2<<<96, 256, 0, stream>>>(Pbuf, Sbuf, Hinit);
  k_scan3<<<2304, 256, 0, stream>>>(delta, xs, Bsb, Csb, A_logs, Ds, Hinit, ys);
  k_combine<<<72, 256, 0, stream>>>(ys, z, out_norm_g, out_norm_b, ya);
  k_outproj<<<dim3(72, 24), 256, 0, stream>>>(ya, out_proj_w, x, xm);
  k_conv3a<<<384, 256, 0, stream>>>(xm, w32, b32, t3);
  k_final<<<1152, 256, 0, stream>>>(xm, t3, w1, b1, w31, b31, w33, b33,
                                    bn_g, bn_b, bn_m, bn_v, prelu_a, out);
}

// Round 2
// 520.579 us; speedup vs baseline: 2.3503x; 2.3503x over previous
//
#include <hip/hip_runtime.h>
#include <math.h>

#define BB_ 2
#define HH 48
#define WW 48
#define LL 2304
#define CIN 96
#define DD 192
#define KK 4
#define NN 16
#define RR 6
#define NCH 24
#define LC 96
#define COUT 192
#define OH 24
#define OW 24
#define OHW 576
#define NPX 1152
#define EPSF 1e-5f

// ---------------- K1: per-pixel LN stats + folded weight prep ----------------
__global__ __launch_bounds__(256) void k_prep(const float* __restrict__ x,
                                              const float* __restrict__ g,
                                              const float* __restrict__ b,
                                              const float* __restrict__ inw,
                                              float* __restrict__ stats,
                                              float* __restrict__ Wg,
                                              float* __restrict__ sWg,
                                              float* __restrict__ sWb) {
  int bx = blockIdx.x;
  if (bx < 72) {
    int bb = bx / 36; int l0 = (bx % 36) * 64;
    int p = threadIdx.x >> 2, q = threadIdx.x & 3;
    int l = l0 + p;
    const float* xp = x + bb * CIN * LL + l;
    float s = 0.f, ss = 0.f;
    for (int c = q; c < CIN; c += 4) { float v = xp[c * LL]; s += v; ss += v * v; }
    s += __shfl_xor(s, 1, 64); s += __shfl_xor(s, 2, 64);
    ss += __shfl_xor(ss, 1, 64); ss += __shfl_xor(ss, 2, 64);
    if (q == 0) {
      float m = s / CIN; float var = ss / CIN - m * m;
      stats[(bb * LL + l) * 2 + 0] = m;
      stats[(bb * LL + l) * 2 + 1] = rsqrtf(var + EPSF);
    }
  } else {
    for (int e = threadIdx.x; e < 2 * DD; e += 256) {
      float swg = 0.f, swb = 0.f;
      for (int c = 0; c < CIN; c++) {
        float w = inw[e * CIN + c];
        float wg = w * g[c];
        Wg[e * CIN + c] = wg;
        swg += wg; swb += w * b[c];
      }
      sWg[e] = swg; sWb[e] = swb;
    }
  }
}

// ---------------- K2: in_proj GEMM (LN folded) -------------------------------
__global__ __launch_bounds__(256) void k_inproj(const float* __restrict__ x,
                                                const float* __restrict__ stats,
                                                const float* __restrict__ Wg,
                                                const float* __restrict__ sWg,
                                                const float* __restrict__ sWb,
                                                float* __restrict__ xin,
                                                float* __restrict__ z) {
  int bx = blockIdx.x; int bb = bx / 36; int l0 = (bx % 36) * 64;
  int tx = threadIdx.x & 63, ty = threadIdx.x >> 6;
  int e = blockIdx.y * 4 + ty;
  int l = l0 + tx;
  const float* xp = x + bb * CIN * LL + l;
  const float* wp = Wg + e * CIN;
  float acc = 0.f;
#pragma unroll 8
  for (int c = 0; c < CIN; c++) acc += wp[c] * xp[c * LL];
  float m = stats[(bb * LL + l) * 2], r = stats[(bb * LL + l) * 2 + 1];
  float val = r * (acc - m * sWg[e]) + sWb[e];
  if (e < DD) xin[(bb * DD + e) * LL + l] = val;
  else z[(bb * LL + l) * DD + (e - DD)] = val;
}

// ---------------- K3: depthwise 3x3 + silu -> xs 4 layouts -------------------
__global__ __launch_bounds__(256) void k_dwconv(const float* __restrict__ xin,
                                                const float* __restrict__ wdw,
                                                const float* __restrict__ bdw,
                                                float* __restrict__ xs) {
  int idx = blockIdx.x * 256 + threadIdx.x;
  if (idx >= BB_ * DD * LL) return;
  int l = idx % LL; int d = (idx / LL) % DD; int bb = idx / (LL * DD);
  int h = l / WW, w = l % WW;
  const float* xp = xin + (bb * DD + d) * LL;
  const float* wq = wdw + d * 9;
  float acc = bdw[d];
#pragma unroll
  for (int kh = 0; kh < 3; kh++) {
    int ih = h + kh - 1; if (ih < 0 || ih >= HH) continue;
#pragma unroll
    for (int kw = 0; kw < 3; kw++) {
      int iw = w + kw - 1; if (iw < 0 || iw >= WW) continue;
      acc += xp[ih * WW + iw] * wq[kh * 3 + kw];
    }
  }
  float v = acc / (1.f + __expf(-acc));
  int lt = w * HH + h;
  xs[((bb * KK + 0) * DD + d) * LL + l] = v;
  xs[((bb * KK + 1) * DD + d) * LL + lt] = v;
  xs[((bb * KK + 2) * DD + d) * LL + (LL - 1 - l)] = v;
  xs[((bb * KK + 3) * DD + d) * LL + (LL - 1 - lt)] = v;
}

// ---------------- K4: x_proj + delta ----------------------------------------
__global__ __launch_bounds__(256) void k_xproj(const float* __restrict__ xs,
                                               const float* __restrict__ xpw,
                                               const float* __restrict__ dtw,
                                               const float* __restrict__ dtb,
                                               float* __restrict__ Bsb,
                                               float* __restrict__ Csb,
                                               float* __restrict__ delta) {
  __shared__ float xls[DD * 64];
  __shared__ float dts[RR * 64];
  int bid = blockIdx.x;
  int tile = bid % 36; int bk = bid / 36; int k = bk % KK;
  int l0 = tile * 64;
  int tid = threadIdx.x;
  const float* xp = xs + bk * DD * LL;
  for (int i = tid; i < DD * 64; i += 256) { int d = i >> 6, l = i & 63; xls[i] = xp[d * LL + l0 + l]; }
  __syncthreads();
  int tx = tid & 63, ty = tid >> 6;
  for (int r = ty; r < RR + 2 * NN; r += 4) {
    const float* wr = xpw + (k * (RR + 2 * NN) + r) * DD;
    float acc = 0.f;
#pragma unroll 8
    for (int d = 0; d < DD; d++) acc += wr[d] * xls[(d << 6) | tx];
    if (r < RR) dts[(r << 6) | tx] = acc;
    else if (r < RR + NN) Bsb[(bk * NN + (r - RR)) * LL + l0 + tx] = acc;
    else Csb[(bk * NN + (r - RR - NN)) * LL + l0 + tx] = acc;
  }
  __syncthreads();
  for (int d = ty; d < DD; d += 4) {
    const float* wd = dtw + (k * DD + d) * RR;
    float acc = dtb[k * DD + d];
#pragma unroll
    for (int r = 0; r < RR; r++) acc += wd[r] * dts[(r << 6) | tx];
    float sp = acc > 20.f ? acc : log1pf(__expf(acc));
    delta[(bk * DD + d) * LL + l0 + tx] = sp;
  }
}

// ---------------- K5a ---------------------------------------------------------
__global__ __launch_bounds__(256) void k_scan1(const float* __restrict__ delta,
                                               const float* __restrict__ xs,
                                               const float* __restrict__ Bsb,
                                               const float* __restrict__ A_logs,
                                               float* __restrict__ Pbuf,
                                               float* __restrict__ Sbuf) {
  int bid = blockIdx.x;
  int c = bid % NCH; int t0 = c * LC;
  int bkdg = bid / NCH;
  int dg = bkdg % 12; int bk = bkdg / 12; int k = bk % KK;
  int tid = threadIdx.x;
  int n = tid & 15;
  int dl = ((tid >> 6) << 2) | ((tid >> 4) & 3);
  int d = dg * 16 + dl;
  float A = -__expf(A_logs[(k * DD + d) * NN + n]);
  const float* dp = delta + (bk * DD + d) * LL;
  const float* xp = xs + (bk * DD + d) * LL;
  const float* bp = Bsb + (bk * NN + n) * LL;
  float h = 0.f, P = 1.f;
  for (int t = t0; t < t0 + LC; ++t) {
    float dt = dp[t], xv = xp[t], bv = bp[t];
    float dA = __expf(dt * A);
    h = dA * h + dt * bv * xv;
    P *= dA;
  }
  int chn = (bk * DD + d) * NN + n;
  Pbuf[c * 24576 + chn] = P;
  Sbuf[c * 24576 + chn] = h;
}

// ---------------- K5b ---------------------------------------------------------
__global__ __launch_bounds__(256) void k_scan2(const float* __restrict__ Pbuf,
                                               const float* __restrict__ Sbuf,
                                               float* __restrict__ Hinit) {
  int idx = blockIdx.x * 256 + threadIdx.x;
  float h = 0.f;
  for (int c = 0; c < NCH; c++) {
    Hinit[c * 24576 + idx] = h;
    h = Pbuf[c * 24576 + idx] * h + Sbuf[c * 24576 + idx];
  }
}

// ---------------- K5c ---------------------------------------------------------
__global__ __launch_bounds__(256) void k_scan3(const float* __restrict__ delta,
                                               const float* __restrict__ xs,
                                               const float* __restrict__ Bsb,
                                               const float* __restrict__ Csb,
                                               const float* __restrict__ A_logs,
                                               const float* __restrict__ Ds,
                                               const float* __restrict__ Hinit,
                                               float* __restrict__ ys) {
  int bid = blockIdx.x;
  int c = bid % NCH; int t0 = c * LC;
  int bkdg = bid / NCH;
  int dg = bkdg % 12; int bk = bkdg / 12; int k = bk % KK;
  int tid = threadIdx.x;
  int n = tid & 15;
  int dl = ((tid >> 6) << 2) | ((tid >> 4) & 3);
  int d = dg * 16 + dl;
  float A = -__expf(A_logs[(k * DD + d) * NN + n]);
  float Dv = Ds[k * DD + d];
  const float* dp = delta + (bk * DD + d) * LL;
  const float* xp = xs + (bk * DD + d) * LL;
  const float* bp = Bsb + (bk * NN + n) * LL;
  const float* cp = Csb + (bk * NN + n) * LL;
  int chn = (bk * DD + d) * NN + n;
  float h = Hinit[c * 24576 + chn];
  for (int t = t0; t < t0 + LC; ++t) {
    float dt = dp[t], xv = xp[t], bv = bp[t];
    float dA = __expf(dt * A);
    h = dA * h + dt * bv * xv;
    float yv = h * cp[t];
    yv += __shfl_xor(yv, 1, 64);
    yv += __shfl_xor(yv, 2, 64);
    yv += __shfl_xor(yv, 4, 64);
    yv += __shfl_xor(yv, 8, 64);
    if (n == 0) ys[(bk * LL + t) * DD + d] = yv + Dv * xv;
  }
}

// ---------------- K6a ---------------------------------------------------------
__global__ __launch_bounds__(256) void k_combine(const float* __restrict__ ys,
                                                 const float* __restrict__ z,
                                                 const float* __restrict__ ong,
                                                 const float* __restrict__ onb,
                                                 float* __restrict__ ya) {
  __shared__ float yt[64 * 201];
  int bx = blockIdx.x; int bb = bx / 36; int l0 = (bx % 36) * 64;
  int tid = threadIdx.x;
  for (int i = tid; i < 64 * DD; i += 256) {
    int p = i / DD, d = i - p * DD;
    int l = l0 + p; int h = l / WW, w = l - h * WW;
    int t1 = w * HH + h;
    float v = ys[((bb * KK + 0) * LL + l) * DD + d]
            + ys[((bb * KK + 1) * LL + t1) * DD + d]
            + ys[((bb * KK + 2) * LL + (LL - 1 - l)) * DD + d]
            + ys[((bb * KK + 3) * LL + (LL - 1 - t1)) * DD + d];
    yt[p * 201 + d] = v;
  }
  __syncthreads();
  int p = tid >> 2, q = tid & 3;
  int l = l0 + p;
  float s = 0.f, ss = 0.f;
  for (int d = q * 48; d < q * 48 + 48; d++) { float v = yt[p * 201 + d]; s += v; ss += v * v; }
  s += __shfl_xor(s, 1, 64); s += __shfl_xor(s, 2, 64);
  ss += __shfl_xor(ss, 1, 64); ss += __shfl_xor(ss, 2, 64);
  float m = s / DD, var = ss / DD - m * m;
  float rr = rsqrtf(var + EPSF);
  const float* zp = z + (bb * LL + l) * DD;
  for (int d = q * 48; d < q * 48 + 48; d++) {
    float v = (yt[p * 201 + d] - m) * rr * ong[d] + onb[d];
    float zv = zp[d];
    yt[p * 201 + d] = v * zv / (1.f + __expf(-zv));
  }
  __syncthreads();
  for (int i = tid; i < 64 * DD; i += 256) {
    int d = i >> 6, p2 = i & 63;
    ya[(bb * DD + d) * LL + l0 + p2] = yt[p2 * 201 + d];
  }
}

// ---------------- K6b ---------------------------------------------------------
__global__ __launch_bounds__(256) void k_outproj(const float* __restrict__ ya,
                                                 const float* __restrict__ wout,
                                                 const float* __restrict__ x,
                                                 float* __restrict__ xm) {
  int bx = blockIdx.x; int bb = bx / 36; int l0 = (bx % 36) * 64;
  int tx = threadIdx.x & 63, ty = threadIdx.x >> 6;
  int cc = blockIdx.y * 4 + ty;
  int l = l0 + tx;
  const float* yp = ya + bb * DD * LL + l;
  const float* wp = wout + cc * DD;
  float acc = 0.f;
#pragma unroll 8
  for (int d = 0; d < DD; d++) acc += yp[d * LL] * wp[d];
  xm[(bb * CIN + cc) * LL + l] = x[(bb * CIN + cc) * LL + l] + acc;
}

// ---------------- K7: weight transpose/concat --------------------------------
__global__ __launch_bounds__(256) void k_prepw(const float* __restrict__ w31,
                                               const float* __restrict__ w32,
                                               const float* __restrict__ w33,
                                               const float* __restrict__ w1,
                                               float* __restrict__ At1,
                                               float* __restrict__ At2,
                                               float* __restrict__ w1t) {
  int idx = blockIdx.x * 256 + threadIdx.x;
  if (idx < 331776) {
    int k = idx / 384, m = idx % 384;
    At1[idx] = (m < 192) ? w31[m * 864 + k] : w32[(m - 192) * 864 + k];
  } else if (idx < 663552) {
    int i = idx - 331776; int k = i / 192, m = i % 192;
    At2[i] = w33[m * 1728 + k];
  } else if (idx < 681984) {
    int i = idx - 663552; int k = i / 192, m = i % 192;
    w1t[i] = w1[m * 96 + k];
  }
}

// ---------------- K8: im2col (stride-2 3x3) over xm --------------------------
__global__ __launch_bounds__(256) void k_pack1(const float* __restrict__ xm,
                                               float* __restrict__ Bm1) {
  int idx4 = blockIdx.x * 256 + threadIdx.x;
  if (idx4 >= 864 * 288) return;
  int k = idx4 / 288; int n = (idx4 % 288) * 4;
  int ci = k / 9, r9 = k % 9, kh = r9 / 3, kw = r9 % 3;
  int bb = n / OHW, rem = n % OHW, oh = rem / OW, ow0 = rem % OW;
  int ih = 2 * oh + kh - 1;
  float4 v = {0.f, 0.f, 0.f, 0.f};
  if (ih >= 0 && ih < HH) {
    const float* base = xm + (bb * CIN + ci) * LL + ih * WW;
    int iw0 = 2 * ow0 + kw - 1;
    v.x = (iw0 >= 0) ? base[iw0] : 0.f;
    v.y = base[iw0 + 2];
    v.z = base[iw0 + 4];
    v.w = base[iw0 + 6];
  }
  *(float4*)&Bm1[k * NPX + n] = v;
}

// ---------------- K9: im2col (stride-1 3x3) over t3 --------------------------
__global__ __launch_bounds__(256) void k_pack2(const float* __restrict__ t3,
                                               float* __restrict__ Bm2) {
  int idx4 = blockIdx.x * 256 + threadIdx.x;
  if (idx4 >= 1728 * 288) return;
  int k = idx4 / 288; int n = (idx4 % 288) * 4;
  int ci = k / 9, r9 = k % 9, kh = r9 / 3, kw = r9 % 3;
  int bb = n / OHW, rem = n % OHW, oh = rem / OW, ow0 = rem % OW;
  int ih = oh + kh - 1;
  float4 v = {0.f, 0.f, 0.f, 0.f};
  if (ih >= 0 && ih < OH) {
    const float* base = t3 + (bb * COUT + ci) * OHW + ih * OW;
    int iw0 = ow0 + kw - 1;
    v.x = (iw0 >= 0) ? base[iw0] : 0.f;
    v.y = base[iw0 + 1];
    v.z = base[iw0 + 2];
    v.w = (iw0 + 3 < OW) ? base[iw0 + 3] : 0.f;
  }
  *(float4*)&Bm2[k * NPX + n] = v;
}

// ---------------- K10: tiled GEMM, 64x64 block tile, 4x4 micro, split-K ------
template<int MT, int KCHUNK, int BROWMUL, int BROWADD, int EPI>
__global__ __launch_bounds__(256) void k_gemm(const float* __restrict__ At,
                                              const float* __restrict__ Bm,
                                              float* __restrict__ Cout,
                                              const float* __restrict__ bias,
                                              const float* __restrict__ bn_g,
                                              const float* __restrict__ bn_b,
                                              const float* __restrict__ bn_m,
                                              const float* __restrict__ bn_v,
                                              const float* __restrict__ prelu_a,
                                              int bnoff) {
  __shared__ float As[16][64];
  __shared__ float Bs[16][64];
  int n0 = blockIdx.x * 64;
  int m0 = blockIdx.y * 64;
  int kz = blockIdx.z;
  int k0 = kz * KCHUNK;
  int tid = threadIdx.x;
  int lr = tid >> 4;
  int lc = (tid & 15) * 4;
  int tm = tid >> 4;
  int tn = tid & 15;
  float acc[4][4] = {};
  for (int ks = 0; ks < KCHUNK; ks += 16) {
    int kg = k0 + ks + lr;
    *(float4*)&As[lr][lc] = *(const float4*)&At[kg * MT + m0 + lc];
    *(float4*)&Bs[lr][lc] = *(const float4*)&Bm[(kg * BROWMUL + BROWADD) * NPX + n0 + lc];
    __syncthreads();
#pragma unroll
    for (int kk = 0; kk < 16; kk++) {
      float4 a = *(float4*)&As[kk][tm * 4];
      float4 b = *(float4*)&Bs[kk][tn * 4];
      acc[0][0] += a.x * b.x; acc[0][1] += a.x * b.y; acc[0][2] += a.x * b.z; acc[0][3] += a.x * b.w;
      acc[1][0] += a.y * b.x; acc[1][1] += a.y * b.y; acc[1][2] += a.y * b.z; acc[1][3] += a.y * b.w;
      acc[2][0] += a.z * b.x; acc[2][1] += a.z * b.y; acc[2][2] += a.z * b.z; acc[2][3] += a.z * b.w;
      acc[3][0] += a.w * b.x; acc[3][1] += a.w * b.y; acc[3][2] += a.w * b.z; acc[3][3] += a.w * b.w;
    }
    __syncthreads();
  }
  if (EPI == 0) {
    float* cp = Cout + ((size_t)kz * MT + m0) * NPX + n0;
#pragma unroll
    for (int i = 0; i < 4; i++) {
      float4 v = {acc[i][0], acc[i][1], acc[i][2], acc[i][3]};
      *(float4*)&cp[(tm * 4 + i) * NPX + tn * 4] = v;
    }
  } else {
    int n = n0 + tn * 4;
    int bb = n / OHW, o = n % OHW;
    float aslope = prelu_a[0];
#pragma unroll
    for (int i = 0; i < 4; i++) {
      int co = m0 + tm * 4 + i;
      int cc = bnoff + co;
      float scale = rsqrtf(bn_v[cc] + EPSF) * bn_g[cc];
      float shift = bn_b[cc] - bn_m[cc] * scale;
      float bv = bias[co];
      float4 v;
      v.x = (acc[i][0] + bv) * scale + shift;
      v.y = (acc[i][1] + bv) * scale + shift;
      v.z = (acc[i][2] + bv) * scale + shift;
      v.w = (acc[i][3] + bv) * scale + shift;
      v.x = v.x > 0.f ? v.x : aslope * v.x;
      v.y = v.y > 0.f ? v.y : aslope * v.y;
      v.z = v.z > 0.f ? v.z : aslope * v.z;
      v.w = v.w > 0.f ? v.w : aslope * v.w;
      *(float4*)&Cout[((size_t)bb * 576 + cc) * OHW + o] = v;
    }
  }
}

// ---------------- K11: reduce split-K (w31 -> out x2 w/ BN; w32 -> t3) -------
__global__ __launch_bounds__(256) void k_reduce1(const float* __restrict__ Cp1,
                                                 const float* __restrict__ b31,
                                                 const float* __restrict__ b32,
                                                 const float* __restrict__ bn_g,
                                                 const float* __restrict__ bn_b,
                                                 const float* __restrict__ bn_m,
                                                 const float* __restrict__ bn_v,
                                                 const float* __restrict__ prelu_a,
                                                 float* __restrict__ out,
                                                 float* __restrict__ t3) {
  int idx = blockIdx.x * 256 + threadIdx.x;
  if (idx >= 384 * NPX) return;
  int m = idx / NPX, n = idx % NPX;
  float s = 0.f;
#pragma unroll
  for (int c = 0; c < 6; c++) s += Cp1[(size_t)c * 384 * NPX + idx];
  int bb = n / OHW, o = n % OHW;
  if (m < 192) {
    s += b31[m];
    int cc = 192 + m;
    float scale = rsqrtf(bn_v[cc] + EPSF) * bn_g[cc];
    float v = s * scale + (bn_b[cc] - bn_m[cc] * scale);
    float a = prelu_a[0];
    out[((size_t)bb * 576 + cc) * OHW + o] = v > 0.f ? v : a * v;
  } else {
    s += b32[m - 192];
    t3[((size_t)bb * COUT + (m - 192)) * OHW + o] = s;
  }
}

// ---------------- K12: reduce split-K for w33 -> out x3 w/ BN ----------------
__global__ __launch_bounds__(256) void k_reduce2(const float* __restrict__ Cp2,
                                                 const float* __restrict__ b33,
                                                 const float* __restrict__ bn_g,
                                                 const float* __restrict__ bn_b,
                                                 const float* __restrict__ bn_m,
                                                 const float* __restrict__ bn_v,
                                                 const float* __restrict__ prelu_a,
                                                 float* __restrict__ out) {
  int idx = blockIdx.x * 256 + threadIdx.x;
  if (idx >= 192 * NPX) return;
  int m = idx / NPX, n = idx % NPX;
  float s = b33[m];
#pragma unroll
  for (int c = 0; c < 9; c++) s += Cp2[(size_t)c * 192 * NPX + idx];
  int bb = n / OHW, o = n % OHW;
  int cc = 384 + m;
  float scale = rsqrtf(bn_v[cc] + EPSF) * bn_g[cc];
  float v = s * scale + (bn_b[cc] - bn_m[cc] * scale);
  float a = prelu_a[0];
  out[((size_t)bb * 576 + cc) * OHW + o] = v > 0.f ? v : a * v;
}

extern "C" void kernel_launch(void* const* d_in, const int* in_sizes, int n_in,
                              void* d_out, int out_size, void* d_ws, size_t ws_size,
                              hipStream_t stream) {
  const float* x        = (const float*)d_in[0];
  const float* ln_g     = (const float*)d_in[1];
  const float* ln_b     = (const float*)d_in[2];
  const float* in_proj_w= (const float*)d_in[3];
  const float* dwconv_w = (const float*)d_in[4];
  const float* dwconv_b = (const float*)d_in[5];
  const float* x_proj_w = (const float*)d_in[6];
  const float* dt_w     = (const float*)d_in[7];
  const float* dt_b     = (const float*)d_in[8];
  const float* A_logs   = (const float*)d_in[9];
  const float* Ds       = (const float*)d_in[10];
  const float* out_norm_g = (const float*)d_in[11];
  const float* out_norm_b = (const float*)d_in[12];
  const float* out_proj_w = (const float*)d_in[13];
  const float* w1  = (const float*)d_in[14];
  const float* b1  = (const float*)d_in[15];
  const float* w31 = (const float*)d_in[16];
  const float* b31 = (const float*)d_in[17];
  const float* w32 = (const float*)d_in[18];
  const float* b32 = (const float*)d_in[19];
  const float* w33 = (const float*)d_in[20];
  const float* b33 = (const float*)d_in[21];
  const float* bn_g = (const float*)d_in[22];
  const float* bn_b = (const float*)d_in[23];
  const float* bn_m = (const float*)d_in[24];
  const float* bn_v = (const float*)d_in[25];
  const float* prelu_a = (const float*)d_in[26];

  float* ws = (float*)d_ws;
  // persistent pipeline buffers (same footprint as round 1: 58 MB ok)
  float* ya    = ws;                    // 884736   (live K6a..K6b)
  float* xin   = ws + 884736;           // 884736   (K2..K3); later xm
  float* xm    = xin;                   // 442368   (K6b..end)
  float* t3    = xin + 442368;          // 221184   (reduce1..pack2)
  float* z     = ws + 1769472;          // 884736   (K2..K6a)
  float* xs    = ws + 2654208;          // 3538944  (K3..K5c)
  float* delta = ws + 6193152;          // 3538944  (K4..K5c)
  float* ys    = ws + 9732096;          // 3538944  (K5c..K6a)
  float* Pbuf  = ys;                    // 589824   (scan1..scan2)
  float* Sbuf  = ys + 589824;           // 589824
  float* Bsb   = ws + 13271040;         // 294912
  float* Csb   = ws + 13565952;         // 294912
  float* Hinit = ws + 13860864;         // 589824
  float* Wg    = ws + 14450688;         // 36864
  float* sWg   = ws + 14487552;         // 384
  float* sWb   = ws + 14487936;         // 384
  float* stats = ws + 14488320;         // 9216
  // conv-stage pool reuses the dead scan pool (z..Hinit all dead by then)
  float* At1 = ws + 1769472;            // 331776  (written after k_combine)
  float* At2 = ws + 2101248;            // 331776
  float* w1t = ws + 2433024;            // 18432
  float* Bm1 = ws + 2451456;            // 995328
  float* Bm2 = ws + 3446784;            // 1990656
  float* Cp1 = ws + 5437440;            // 2654208 (6*384*1152)
  float* Cp2 = ws + 8091648;            // 1990656 (9*192*1152)
  float* out = (float*)d_out;

  k_prep<<<73, 256, 0, stream>>>(x, ln_g, ln_b, in_proj_w, stats, Wg, sWg, sWb);
  k_inproj<<<dim3(72, 96), 256, 0, stream>>>(x, stats, Wg, sWg, sWb, xin, z);
  k_dwconv<<<3456, 256, 0, stream>>>(xin, dwconv_w, dwconv_b, xs);
  k_xproj<<<288, 256, 0, stream>>>(xs, x_proj_w, dt_w, dt_b, Bsb, Csb, delta);
  k_scan1<<<2304, 256, 0, stream>>>(delta, xs, Bsb, A_logs, Pbuf, Sbuf);
  k_scan2<<<96, 256, 0, stream>>>(Pbuf, Sbuf, Hinit);
  k_scan3<<<2304, 256, 0, stream>>>(delta, xs, Bsb, Csb, A_logs, Ds, Hinit, ys);
  k_combine<<<72, 256, 0, stream>>>(ys, z, out_norm_g, out_norm_b, ya);
  k_prepw<<<2665, 256, 0, stream>>>(w31, w32, w33, w1, At1, At2, w1t);
  k_outproj<<<dim3(72, 24), 256, 0, stream>>>(ya, out_proj_w, x, xm);
  k_pack1<<<972, 256, 0, stream>>>(xm, Bm1);
  // x2 + x3a combined GEMM: M=384, K=864, split 6x144
  k_gemm<384, 144, 1, 0, 0><<<dim3(18, 6, 6), 256, 0, stream>>>(
      At1, Bm1, Cp1, nullptr, nullptr, nullptr, nullptr, nullptr, nullptr, 0);
  // x1 GEMM: M=192, K=96 over Bm1 rows ci*9+4; BN+PReLU fused, out ch 0..191
  k_gemm<192, 96, 9, 4, 1><<<dim3(18, 3, 1), 256, 0, stream>>>(
      w1t, Bm1, out, b1, bn_g, bn_b, bn_m, bn_v, prelu_a, 0);
  k_reduce1<<<1728, 256, 0, stream>>>(Cp1, b31, b32, bn_g, bn_b, bn_m, bn_v,
                                      prelu_a, out, t3);
  k_pack2<<<1944, 256, 0, stream>>>(t3, Bm2);
  // x3b GEMM: M=192, K=1728, split 9x192
  k_gemm<192, 192, 1, 0, 0><<<dim3(18, 3, 9), 256, 0, stream>>>(
      At2, Bm2, Cp2, nullptr, nullptr, nullptr, nullptr, nullptr, nullptr, 0);
  k_reduce2<<<864, 256, 0, stream>>>(Cp2, b33, bn_g, bn_b, bn_m, bn_v, prelu_a, out);
}

// Round 3
// 396.579 us; speedup vs baseline: 3.0852x; 1.3127x over previous
//
#include <hip/hip_runtime.h>
#include <math.h>

#define BB_ 2
#define HH 48
#define WW 48
#define LL 2304
#define CIN 96
#define DD 192
#define KK 4
#define NN 16
#define RR 6
#define NCH 24
#define LC 96
#define COUT 192
#define OH 24
#define OW 24
#define OHW 576
#define NPX 1152
#define EPSF 1e-5f

// ---------------- K1: per-pixel LN stats + folded weight prep ----------------
__global__ __launch_bounds__(256) void k_prep(const float* __restrict__ x,
                                              const float* __restrict__ g,
                                              const float* __restrict__ b,
                                              const float* __restrict__ inw,
                                              float* __restrict__ stats,
                                              float* __restrict__ Wg,
                                              float* __restrict__ sWg,
                                              float* __restrict__ sWb) {
  int bx = blockIdx.x;
  if (bx < 72) {
    int bb = bx / 36; int l0 = (bx % 36) * 64;
    int p = threadIdx.x >> 2, q = threadIdx.x & 3;
    int l = l0 + p;
    const float* xp = x + bb * CIN * LL + l;
    float s = 0.f, ss = 0.f;
    for (int c = q; c < CIN; c += 4) { float v = xp[c * LL]; s += v; ss += v * v; }
    s += __shfl_xor(s, 1, 64); s += __shfl_xor(s, 2, 64);
    ss += __shfl_xor(ss, 1, 64); ss += __shfl_xor(ss, 2, 64);
    if (q == 0) {
      float m = s / CIN; float var = ss / CIN - m * m;
      stats[(bb * LL + l) * 2 + 0] = m;
      stats[(bb * LL + l) * 2 + 1] = rsqrtf(var + EPSF);
    }
  } else {
    for (int e = threadIdx.x; e < 2 * DD; e += 256) {
      float swg = 0.f, swb = 0.f;
      for (int c = 0; c < CIN; c++) {
        float w = inw[e * CIN + c];
        float wg = w * g[c];
        Wg[e * CIN + c] = wg;
        swg += wg; swb += w * b[c];
      }
      sWg[e] = swg; sWb[e] = swb;
    }
  }
}

// ---------------- K2: in_proj GEMM (LN folded) -> xin (B,192,L), z (B,L,192) -
__global__ __launch_bounds__(256) void k_inproj(const float* __restrict__ x,
                                                const float* __restrict__ stats,
                                                const float* __restrict__ Wg,
                                                const float* __restrict__ sWg,
                                                const float* __restrict__ sWb,
                                                float* __restrict__ xin,
                                                float* __restrict__ z) {
  int bx = blockIdx.x; int bb = bx / 36; int l0 = (bx % 36) * 64;
  int tx = threadIdx.x & 63, ty = threadIdx.x >> 6;
  int e = blockIdx.y * 4 + ty;
  int l = l0 + tx;
  const float* xp = x + bb * CIN * LL + l;
  const float* wp = Wg + e * CIN;
  float acc = 0.f;
#pragma unroll 8
  for (int c = 0; c < CIN; c++) acc += wp[c] * xp[c * LL];
  float m = stats[(bb * LL + l) * 2], r = stats[(bb * LL + l) * 2 + 1];
  float val = r * (acc - m * sWg[e]) + sWb[e];
  if (e < DD) xin[(bb * DD + e) * LL + l] = val;
  else z[(bb * LL + l) * DD + (e - DD)] = val;
}

// ---------------- K3: depthwise 3x3 + silu -> xs t-major, 4 directions -------
// xs layout: [(bk)*LL + pos]*DD + d   (t-major, d contiguous)
__global__ __launch_bounds__(256) void k_dwconv(const float* __restrict__ xin,
                                                const float* __restrict__ wdw,
                                                const float* __restrict__ bdw,
                                                float* __restrict__ xs) {
  __shared__ float vt[32 * 194];
  int bid = blockIdx.x;                 // bb*72 + tile
  int bb = bid / 72; int l0 = (bid % 72) * 32;
  for (int i = threadIdx.x; i < 32 * 192; i += 256) {
    int lj = i & 31, d = i >> 5;
    int l = l0 + lj;
    int h = l / WW, w = l % WW;
    const float* xp = xin + (bb * DD + d) * LL;
    const float* wq = wdw + d * 9;
    float acc = bdw[d];
#pragma unroll
    for (int kh = 0; kh < 3; kh++) {
      int ih = h + kh - 1; if (ih < 0 || ih >= HH) continue;
#pragma unroll
      for (int kw = 0; kw < 3; kw++) {
        int iw = w + kw - 1; if (iw < 0 || iw >= WW) continue;
        acc += xp[ih * WW + iw] * wq[kh * 3 + kw];
      }
    }
    vt[lj * 194 + d] = acc / (1.f + __expf(-acc));
  }
  __syncthreads();
  for (int j = threadIdx.x; j < 32 * 192; j += 256) {
    int d = j % 192, lj = j / 192;
    int l = l0 + lj;
    int h = l / WW, w = l % WW;
    int lt = w * HH + h;
    float v = vt[lj * 194 + d];
    xs[(((size_t)bb * KK + 0) * LL + l) * DD + d] = v;
    xs[(((size_t)bb * KK + 1) * LL + lt) * DD + d] = v;
    xs[(((size_t)bb * KK + 2) * LL + (LL - 1 - l)) * DD + d] = v;
    xs[(((size_t)bb * KK + 3) * LL + (LL - 1 - lt)) * DD + d] = v;
  }
}

// ---------------- K4: x_proj + delta; outputs t-major ------------------------
// Bsb/Csb: [(bk*LL + l)*16 + n] ; delta: [(bk*LL + l)*192 + d]
__global__ __launch_bounds__(256) void k_xproj(const float* __restrict__ xs,
                                               const float* __restrict__ xpw,
                                               const float* __restrict__ dtw,
                                               const float* __restrict__ dtb,
                                               float* __restrict__ Bsb,
                                               float* __restrict__ Csb,
                                               float* __restrict__ delta) {
  __shared__ float xls[192 * 65];       // [d][l] padded
  __shared__ float dts[6 * 64];         // [r][l]
  __shared__ float bcls[32 * 66];       // [n-row][l] padded
  int bid = blockIdx.x;
  int tile = bid % 36; int bk = bid / 36; int k = bk % KK;
  int l0 = tile * 64;
  int tid = threadIdx.x;
  const float* xp = xs + (size_t)bk * LL * DD;
  for (int i = tid; i < 64 * 192; i += 256) {
    int l = i / 192, d = i % 192;
    xls[d * 65 + l] = xp[(l0 + l) * DD + d];
  }
  __syncthreads();
  int tx = tid & 63, ty = tid >> 6;
  for (int r = ty; r < RR + 2 * NN; r += 4) {
    const float* wr = xpw + (k * (RR + 2 * NN) + r) * DD;
    float acc = 0.f;
#pragma unroll 8
    for (int d = 0; d < DD; d++) acc += wr[d] * xls[d * 65 + tx];
    if (r < RR) dts[(r << 6) | tx] = acc;
    else bcls[(r - RR) * 66 + tx] = acc;
  }
  __syncthreads();
  for (int i = tid; i < 64 * 16; i += 256) {
    int l = i >> 4, n = i & 15;
    Bsb[((size_t)bk * LL + l0 + l) * NN + n] = bcls[n * 66 + l];
    Csb[((size_t)bk * LL + l0 + l) * NN + n] = bcls[(16 + n) * 66 + l];
  }
  for (int i = tid; i < 64 * 192; i += 256) {
    int l = i / 192, d = i % 192;
    const float* wd = dtw + (k * DD + d) * RR;
    float acc = dtb[k * DD + d];
#pragma unroll
    for (int r = 0; r < RR; r++) acc += wd[r] * dts[(r << 6) | l];
    float sp = acc > 20.f ? acc : log1pf(__expf(acc));
    delta[((size_t)bk * LL + l0 + l) * DD + d] = sp;
  }
}

// ---------------- K5a: chunked scan pass 1 (t-major reads) -------------------
__global__ __launch_bounds__(256) void k_scan1(const float* __restrict__ delta,
                                               const float* __restrict__ xs,
                                               const float* __restrict__ Bsb,
                                               const float* __restrict__ A_logs,
                                               float* __restrict__ Pbuf,
                                               float* __restrict__ Sbuf) {
  int bid = blockIdx.x;
  int c = bid % NCH; int t0 = c * LC;
  int bkdg = bid / NCH;
  int dg = bkdg % 12; int bk = bkdg / 12; int k = bk % KK;
  int tid = threadIdx.x;
  int n = tid & 15;
  int dl = ((tid >> 6) << 2) | ((tid >> 4) & 3);
  int d = dg * 16 + dl;
  float A = -__expf(A_logs[(k * DD + d) * NN + n]);
  const float* dp = delta + (size_t)bk * LL * DD;
  const float* xp = xs + (size_t)bk * LL * DD;
  const float* bp = Bsb + (size_t)bk * LL * NN;
  float h = 0.f, P = 1.f;
#pragma unroll 4
  for (int t = t0; t < t0 + LC; ++t) {
    float dt = dp[t * DD + d], xv = xp[t * DD + d], bv = bp[t * NN + n];
    float dA = __expf(dt * A);
    h = dA * h + dt * bv * xv;
    P *= dA;
  }
  int chn = (bk * DD + d) * NN + n;
  Pbuf[c * 24576 + chn] = P;
  Sbuf[c * 24576 + chn] = h;
}

// ---------------- K5b: combine chunks ----------------------------------------
__global__ __launch_bounds__(256) void k_scan2(const float* __restrict__ Pbuf,
                                               const float* __restrict__ Sbuf,
                                               float* __restrict__ Hinit) {
  int idx = blockIdx.x * 256 + threadIdx.x;
  float h = 0.f;
  for (int c = 0; c < NCH; c++) {
    Hinit[c * 24576 + idx] = h;
    h = Pbuf[c * 24576 + idx] * h + Sbuf[c * 24576 + idx];
  }
}

// ---------------- K5c: replay + emit ys (B,K,L,192) (t-major reads) ----------
__global__ __launch_bounds__(256) void k_scan3(const float* __restrict__ delta,
                                               const float* __restrict__ xs,
                                               const float* __restrict__ Bsb,
                                               const float* __restrict__ Csb,
                                               const float* __restrict__ A_logs,
                                               const float* __restrict__ Ds,
                                               const float* __restrict__ Hinit,
                                               float* __restrict__ ys) {
  int bid = blockIdx.x;
  int c = bid % NCH; int t0 = c * LC;
  int bkdg = bid / NCH;
  int dg = bkdg % 12; int bk = bkdg / 12; int k = bk % KK;
  int tid = threadIdx.x;
  int n = tid & 15;
  int dl = ((tid >> 6) << 2) | ((tid >> 4) & 3);
  int d = dg * 16 + dl;
  float A = -__expf(A_logs[(k * DD + d) * NN + n]);
  float Dv = Ds[k * DD + d];
  const float* dp = delta + (size_t)bk * LL * DD;
  const float* xp = xs + (size_t)bk * LL * DD;
  const float* bp = Bsb + (size_t)bk * LL * NN;
  const float* cp = Csb + (size_t)bk * LL * NN;
  int chn = (bk * DD + d) * NN + n;
  float h = Hinit[c * 24576 + chn];
#pragma unroll 4
  for (int t = t0; t < t0 + LC; ++t) {
    float dt = dp[t * DD + d], xv = xp[t * DD + d], bv = bp[t * NN + n];
    float dA = __expf(dt * A);
    h = dA * h + dt * bv * xv;
    float yv = h * cp[t * NN + n];
    yv += __shfl_xor(yv, 1, 64);
    yv += __shfl_xor(yv, 2, 64);
    yv += __shfl_xor(yv, 4, 64);
    yv += __shfl_xor(yv, 8, 64);
    if (n == 0) ys[((size_t)bk * LL + t) * DD + d] = yv + Dv * xv;
  }
}

// ---------------- K6a: gather 4 dirs + out_norm LN + silu(z) -----------------
__global__ __launch_bounds__(256) void k_combine(const float* __restrict__ ys,
                                                 const float* __restrict__ z,
                                                 const float* __restrict__ ong,
                                                 const float* __restrict__ onb,
                                                 float* __restrict__ ya) {
  __shared__ float yt[64 * 201];
  int bx = blockIdx.x; int bb = bx / 36; int l0 = (bx % 36) * 64;
  int tid = threadIdx.x;
  for (int i = tid; i < 64 * DD; i += 256) {
    int p = i / DD, d = i - p * DD;
    int l = l0 + p; int h = l / WW, w = l - h * WW;
    int t1 = w * HH + h;
    float v = ys[(((size_t)bb * KK + 0) * LL + l) * DD + d]
            + ys[(((size_t)bb * KK + 1) * LL + t1) * DD + d]
            + ys[(((size_t)bb * KK + 2) * LL + (LL - 1 - l)) * DD + d]
            + ys[(((size_t)bb * KK + 3) * LL + (LL - 1 - t1)) * DD + d];
    yt[p * 201 + d] = v;
  }
  __syncthreads();
  int p = tid >> 2, q = tid & 3;
  int l = l0 + p;
  float s = 0.f, ss = 0.f;
  for (int d = q * 48; d < q * 48 + 48; d++) { float v = yt[p * 201 + d]; s += v; ss += v * v; }
  s += __shfl_xor(s, 1, 64); s += __shfl_xor(s, 2, 64);
  ss += __shfl_xor(ss, 1, 64); ss += __shfl_xor(ss, 2, 64);
  float m = s / DD, var = ss / DD - m * m;
  float rr = rsqrtf(var + EPSF);
  const float* zp = z + (bb * LL + l) * DD;
  for (int d = q * 48; d < q * 48 + 48; d++) {
    float v = (yt[p * 201 + d] - m) * rr * ong[d] + onb[d];
    float zv = zp[d];
    yt[p * 201 + d] = v * zv / (1.f + __expf(-zv));
  }
  __syncthreads();
  for (int i = tid; i < 64 * DD; i += 256) {
    int d = i >> 6, p2 = i & 63;
    ya[(bb * DD + d) * LL + l0 + p2] = yt[p2 * 201 + d];
  }
}

// ---------------- K6b: out_proj GEMM + residual -> xm ------------------------
__global__ __launch_bounds__(256) void k_outproj(const float* __restrict__ ya,
                                                 const float* __restrict__ wout,
                                                 const float* __restrict__ x,
                                                 float* __restrict__ xm) {
  int bx = blockIdx.x; int bb = bx / 36; int l0 = (bx % 36) * 64;
  int tx = threadIdx.x & 63, ty = threadIdx.x >> 6;
  int cc = blockIdx.y * 4 + ty;
  int l = l0 + tx;
  const float* yp = ya + bb * DD * LL + l;
  const float* wp = wout + cc * DD;
  float acc = 0.f;
#pragma unroll 8
  for (int d = 0; d < DD; d++) acc += yp[d * LL] * wp[d];
  xm[(bb * CIN + cc) * LL + l] = x[(bb * CIN + cc) * LL + l] + acc;
}

// ---------------- K7: weight transpose/concat --------------------------------
__global__ __launch_bounds__(256) void k_prepw(const float* __restrict__ w31,
                                               const float* __restrict__ w32,
                                               const float* __restrict__ w33,
                                               const float* __restrict__ w1,
                                               float* __restrict__ At1,
                                               float* __restrict__ At2,
                                               float* __restrict__ w1t) {
  int idx = blockIdx.x * 256 + threadIdx.x;
  if (idx < 331776) {
    int k = idx / 384, m = idx % 384;
    At1[idx] = (m < 192) ? w31[m * 864 + k] : w32[(m - 192) * 864 + k];
  } else if (idx < 663552) {
    int i = idx - 331776; int k = i / 192, m = i % 192;
    At2[i] = w33[m * 1728 + k];
  } else if (idx < 681984) {
    int i = idx - 663552; int k = i / 192, m = i % 192;
    w1t[i] = w1[m * 96 + k];
  }
}

// ---------------- K8: im2col (stride-2 3x3) over xm --------------------------
__global__ __launch_bounds__(256) void k_pack1(const float* __restrict__ xm,
                                               float* __restrict__ Bm1) {
  int idx4 = blockIdx.x * 256 + threadIdx.x;
  if (idx4 >= 864 * 288) return;
  int k = idx4 / 288; int n = (idx4 % 288) * 4;
  int ci = k / 9, r9 = k % 9, kh = r9 / 3, kw = r9 % 3;
  int bb = n / OHW, rem = n % OHW, oh = rem / OW, ow0 = rem % OW;
  int ih = 2 * oh + kh - 1;
  float4 v = {0.f, 0.f, 0.f, 0.f};
  if (ih >= 0 && ih < HH) {
    const float* base = xm + (bb * CIN + ci) * LL + ih * WW;
    int iw0 = 2 * ow0 + kw - 1;
    v.x = (iw0 >= 0) ? base[iw0] : 0.f;
    v.y = base[iw0 + 2];
    v.z = base[iw0 + 4];
    v.w = base[iw0 + 6];
  }
  *(float4*)&Bm1[k * NPX + n] = v;
}

// ---------------- K9: im2col (stride-1 3x3) over t3 --------------------------
__global__ __launch_bounds__(256) void k_pack2(const float* __restrict__ t3,
                                               float* __restrict__ Bm2) {
  int idx4 = blockIdx.x * 256 + threadIdx.x;
  if (idx4 >= 1728 * 288) return;
  int k = idx4 / 288; int n = (idx4 % 288) * 4;
  int ci = k / 9, r9 = k % 9, kh = r9 / 3, kw = r9 % 3;
  int bb = n / OHW, rem = n % OHW, oh = rem / OW, ow0 = rem % OW;
  int ih = oh + kh - 1;
  float4 v = {0.f, 0.f, 0.f, 0.f};
  if (ih >= 0 && ih < OH) {
    const float* base = t3 + (bb * COUT + ci) * OHW + ih * OW;
    int iw0 = ow0 + kw - 1;
    v.x = (iw0 >= 0) ? base[iw0] : 0.f;
    v.y = base[iw0 + 1];
    v.z = base[iw0 + 2];
    v.w = (iw0 + 3 < OW) ? base[iw0 + 3] : 0.f;
  }
  *(float4*)&Bm2[k * NPX + n] = v;
}

// ---------------- K10: tiled GEMM, 64x64 block tile, 4x4 micro, split-K ------
template<int MT, int KCHUNK, int BROWMUL, int BROWADD, int EPI>
__global__ __launch_bounds__(256) void k_gemm(const float* __restrict__ At,
                                              const float* __restrict__ Bm,
                                              float* __restrict__ Cout,
                                              const float* __restrict__ bias,
                                              const float* __restrict__ bn_g,
                                              const float* __restrict__ bn_b,
                                              const float* __restrict__ bn_m,
                                              const float* __restrict__ bn_v,
                                              const float* __restrict__ prelu_a,
                                              int bnoff) {
  __shared__ float As[16][64];
  __shared__ float Bs[16][64];
  int n0 = blockIdx.x * 64;
  int m0 = blockIdx.y * 64;
  int kz = blockIdx.z;
  int k0 = kz * KCHUNK;
  int tid = threadIdx.x;
  int lr = tid >> 4;
  int lc = (tid & 15) * 4;
  int tm = tid >> 4;
  int tn = tid & 15;
  float acc[4][4] = {};
  for (int ks = 0; ks < KCHUNK; ks += 16) {
    int kg = k0 + ks + lr;
    *(float4*)&As[lr][lc] = *(const float4*)&At[kg * MT + m0 + lc];
    *(float4*)&Bs[lr][lc] = *(const float4*)&Bm[(kg * BROWMUL + BROWADD) * NPX + n0 + lc];
    __syncthreads();
#pragma unroll
    for (int kk = 0; kk < 16; kk++) {
      float4 a = *(float4*)&As[kk][tm * 4];
      float4 b = *(float4*)&Bs[kk][tn * 4];
      acc[0][0] += a.x * b.x; acc[0][1] += a.x * b.y; acc[0][2] += a.x * b.z; acc[0][3] += a.x * b.w;
      acc[1][0] += a.y * b.x; acc[1][1] += a.y * b.y; acc[1][2] += a.y * b.z; acc[1][3] += a.y * b.w;
      acc[2][0] += a.z * b.x; acc[2][1] += a.z * b.y; acc[2][2] += a.z * b.z; acc[2][3] += a.z * b.w;
      acc[3][0] += a.w * b.x; acc[3][1] += a.w * b.y; acc[3][2] += a.w * b.z; acc[3][3] += a.w * b.w;
    }
    __syncthreads();
  }
  if (EPI == 0) {
    float* cp = Cout + ((size_t)kz * MT + m0) * NPX + n0;
#pragma unroll
    for (int i = 0; i < 4; i++) {
      float4 v = {acc[i][0], acc[i][1], acc[i][2], acc[i][3]};
      *(float4*)&cp[(tm * 4 + i) * NPX + tn * 4] = v;
    }
  } else {
    int n = n0 + tn * 4;
    int bb = n / OHW, o = n % OHW;
    float aslope = prelu_a[0];
#pragma unroll
    for (int i = 0; i < 4; i++) {
      int co = m0 + tm * 4 + i;
      int cc = bnoff + co;
      float scale = rsqrtf(bn_v[cc] + EPSF) * bn_g[cc];
      float shift = bn_b[cc] - bn_m[cc] * scale;
      float bv = bias[co];
      float4 v;
      v.x = (acc[i][0] + bv) * scale + shift;
      v.y = (acc[i][1] + bv) * scale + shift;
      v.z = (acc[i][2] + bv) * scale + shift;
      v.w = (acc[i][3] + bv) * scale + shift;
      v.x = v.x > 0.f ? v.x : aslope * v.x;
      v.y = v.y > 0.f ? v.y : aslope * v.y;
      v.z = v.z > 0.f ? v.z : aslope * v.z;
      v.w = v.w > 0.f ? v.w : aslope * v.w;
      *(float4*)&Cout[((size_t)bb * 576 + cc) * OHW + o] = v;
    }
  }
}

// ---------------- K11: reduce split-K (w31 -> out x2 w/ BN; w32 -> t3) -------
__global__ __launch_bounds__(256) void k_reduce1(const float* __restrict__ Cp1,
                                                 const float* __restrict__ b31,
                                                 const float* __restrict__ b32,
                                                 const float* __restrict__ bn_g,
                                                 const float* __restrict__ bn_b,
                                                 const float* __restrict__ bn_m,
                                                 const float* __restrict__ bn_v,
                                                 const float* __restrict__ prelu_a,
                                                 float* __restrict__ out,
                                                 float* __restrict__ t3) {
  int idx = blockIdx.x * 256 + threadIdx.x;
  if (idx >= 384 * NPX) return;
  int m = idx / NPX, n = idx % NPX;
  float s = 0.f;
#pragma unroll
  for (int c = 0; c < 6; c++) s += Cp1[(size_t)c * 384 * NPX + idx];
  int bb = n / OHW, o = n % OHW;
  if (m < 192) {
    s += b31[m];
    int cc = 192 + m;
    float scale = rsqrtf(bn_v[cc] + EPSF) * bn_g[cc];
    float v = s * scale + (bn_b[cc] - bn_m[cc] * scale);
    float a = prelu_a[0];
    out[((size_t)bb * 576 + cc) * OHW + o] = v > 0.f ? v : a * v;
  } else {
    s += b32[m - 192];
    t3[((size_t)bb * COUT + (m - 192)) * OHW + o] = s;
  }
}

// ---------------- K12: reduce split-K for w33 -> out x3 w/ BN ----------------
__global__ __launch_bounds__(256) void k_reduce2(const float* __restrict__ Cp2,
                                                 const float* __restrict__ b33,
                                                 const float* __restrict__ bn_g,
                                                 const float* __restrict__ bn_b,
                                                 const float* __restrict__ bn_m,
                                                 const float* __restrict__ bn_v,
                                                 const float* __restrict__ prelu_a,
                                                 float* __restrict__ out) {
  int idx = blockIdx.x * 256 + threadIdx.x;
  if (idx >= 192 * NPX) return;
  int m = idx / NPX, n = idx % NPX;
  float s = b33[m];
#pragma unroll
  for (int c = 0; c < 9; c++) s += Cp2[(size_t)c * 192 * NPX + idx];
  int bb = n / OHW, o = n % OHW;
  int cc = 384 + m;
  float scale = rsqrtf(bn_v[cc] + EPSF) * bn_g[cc];
  float v = s * scale + (bn_b[cc] - bn_m[cc] * scale);
  float a = prelu_a[0];
  out[((size_t)bb * 576 + cc) * OHW + o] = v > 0.f ? v : a * v;
}

extern "C" void kernel_launch(void* const* d_in, const int* in_sizes, int n_in,
                              void* d_out, int out_size, void* d_ws, size_t ws_size,
                              hipStream_t stream) {
  const float* x        = (const float*)d_in[0];
  const float* ln_g     = (const float*)d_in[1];
  const float* ln_b     = (const float*)d_in[2];
  const float* in_proj_w= (const float*)d_in[3];
  const float* dwconv_w = (const float*)d_in[4];
  const float* dwconv_b = (const float*)d_in[5];
  const float* x_proj_w = (const float*)d_in[6];
  const float* dt_w     = (const float*)d_in[7];
  const float* dt_b     = (const float*)d_in[8];
  const float* A_logs   = (const float*)d_in[9];
  const float* Ds       = (const float*)d_in[10];
  const float* out_norm_g = (const float*)d_in[11];
  const float* out_norm_b = (const float*)d_in[12];
  const float* out_proj_w = (const float*)d_in[13];
  const float* w1  = (const float*)d_in[14];
  const float* b1  = (const float*)d_in[15];
  const float* w31 = (const float*)d_in[16];
  const float* b31 = (const float*)d_in[17];
  const float* w32 = (const float*)d_in[18];
  const float* b32 = (const float*)d_in[19];
  const float* w33 = (const float*)d_in[20];
  const float* b33 = (const float*)d_in[21];
  const float* bn_g = (const float*)d_in[22];
  const float* bn_b = (const float*)d_in[23];
  const float* bn_m = (const float*)d_in[24];
  const float* bn_v = (const float*)d_in[25];
  const float* prelu_a = (const float*)d_in[26];

  float* ws = (float*)d_ws;
  float* ya    = ws;                    // 884736
  float* xin   = ws + 884736;           // 884736 ; later xm/t3
  float* xm    = xin;                   // 442368
  float* t3    = xin + 442368;          // 221184
  float* z     = ws + 1769472;          // 884736
  float* xs    = ws + 2654208;          // 3538944
  float* delta = ws + 6193152;          // 3538944
  float* ys    = ws + 9732096;          // 3538944 (P/S union)
  float* Pbuf  = ys;                    // 589824
  float* Sbuf  = ys + 589824;           // 589824
  float* Bsb   = ws + 13271040;         // 294912
  float* Csb   = ws + 13565952;         // 294912
  float* Hinit = ws + 13860864;         // 589824
  float* Wg    = ws + 14450688;         // 36864
  float* sWg   = ws + 14487552;         // 384
  float* sWb   = ws + 14487936;         // 384
  float* stats = ws + 14488320;         // 9216
  // conv-stage pool reuses dead scan pool
  float* At1 = ws + 1769472;            // 331776
  float* At2 = ws + 2101248;            // 331776
  float* w1t = ws + 2433024;            // 18432
  float* Bm1 = ws + 2451456;            // 995328
  float* Bm2 = ws + 3446784;            // 1990656
  float* Cp1 = ws + 5437440;            // 2654208
  float* Cp2 = ws + 8091648;            // 1990656
  float* out = (float*)d_out;

  k_prep<<<73, 256, 0, stream>>>(x, ln_g, ln_b, in_proj_w, stats, Wg, sWg, sWb);
  k_inproj<<<dim3(72, 96), 256, 0, stream>>>(x, stats, Wg, sWg, sWb, xin, z);
  k_dwconv<<<144, 256, 0, stream>>>(xin, dwconv_w, dwconv_b, xs);
  k_xproj<<<288, 256, 0, stream>>>(xs, x_proj_w, dt_w, dt_b, Bsb, Csb, delta);
  k_scan1<<<2304, 256, 0, stream>>>(delta, xs, Bsb, A_logs, Pbuf, Sbuf);
  k_scan2<<<96, 256, 0, stream>>>(Pbuf, Sbuf, Hinit);
  k_scan3<<<2304, 256, 0, stream>>>(delta, xs, Bsb, Csb, A_logs, Ds, Hinit, ys);
  k_combine<<<72, 256, 0, stream>>>(ys, z, out_norm_g, out_norm_b, ya);
  k_prepw<<<2665, 256, 0, stream>>>(w31, w32, w33, w1, At1, At2, w1t);
  k_outproj<<<dim3(72, 24), 256, 0, stream>>>(ya, out_proj_w, x, xm);
  k_pack1<<<972, 256, 0, stream>>>(xm, Bm1);
  k_gemm<384, 144, 1, 0, 0><<<dim3(18, 6, 6), 256, 0, stream>>>(
      At1, Bm1, Cp1, nullptr, nullptr, nullptr, nullptr, nullptr, nullptr, 0);
  k_gemm<192, 96, 9, 4, 1><<<dim3(18, 3, 1), 256, 0, stream>>>(
      w1t, Bm1, out, b1, bn_g, bn_b, bn_m, bn_v, prelu_a, 0);
  k_reduce1<<<1728, 256, 0, stream>>>(Cp1, b31, b32, bn_g, bn_b, bn_m, bn_v,
                                      prelu_a, out, t3);
  k_pack2<<<1944, 256, 0, stream>>>(t3, Bm2);
  k_gemm<192, 192, 1, 0, 0><<<dim3(18, 3, 9), 256, 0, stream>>>(
      At2, Bm2, Cp2, nullptr, nullptr, nullptr, nullptr, nullptr, nullptr, 0);
  k_reduce2<<<864, 256, 0, stream>>>(Cp2, b33, bn_g, bn_b, bn_m, bn_v, prelu_a, out);
}

// Round 4
// 345.375 us; speedup vs baseline: 3.5426x; 1.1483x over previous
//
#include <hip/hip_runtime.h>
#include <math.h>

#define BB_ 2
#define HH 48
#define WW 48
#define LL 2304
#define CIN 96
#define DD 192
#define KK 4
#define NN 16
#define RR 6
#define NCH 32
#define LC 72
#define COUT 192
#define OH 24
#define OW 24
#define OHW 576
#define NPX 1152
#define EPSF 1e-5f

// ---------------- K1: per-pixel LN stats + folded weight prep ----------------
__global__ __launch_bounds__(256) void k_prep(const float* __restrict__ x,
                                              const float* __restrict__ g,
                                              const float* __restrict__ b,
                                              const float* __restrict__ inw,
                                              float* __restrict__ stats,
                                              float* __restrict__ Wg,
                                              float* __restrict__ sWg,
                                              float* __restrict__ sWb) {
  int bx = blockIdx.x;
  if (bx < 72) {
    int bb = bx / 36; int l0 = (bx % 36) * 64;
    int p = threadIdx.x >> 2, q = threadIdx.x & 3;
    int l = l0 + p;
    const float* xp = x + bb * CIN * LL + l;
    float s = 0.f, ss = 0.f;
    for (int c = q; c < CIN; c += 4) { float v = xp[c * LL]; s += v; ss += v * v; }
    s += __shfl_xor(s, 1, 64); s += __shfl_xor(s, 2, 64);
    ss += __shfl_xor(ss, 1, 64); ss += __shfl_xor(ss, 2, 64);
    if (q == 0) {
      float m = s / CIN; float var = ss / CIN - m * m;
      stats[(bb * LL + l) * 2 + 0] = m;
      stats[(bb * LL + l) * 2 + 1] = rsqrtf(var + EPSF);
    }
  } else {
    for (int e = threadIdx.x; e < 2 * DD; e += 256) {
      float swg = 0.f, swb = 0.f;
      for (int c = 0; c < CIN; c++) {
        float w = inw[e * CIN + c];
        float wg = w * g[c];
        Wg[e * CIN + c] = wg;
        swg += wg; swb += w * b[c];
      }
      sWg[e] = swg; sWb[e] = swb;
    }
  }
}

// ---------------- K2: in_proj GEMM (LN folded) -------------------------------
__global__ __launch_bounds__(256) void k_inproj(const float* __restrict__ x,
                                                const float* __restrict__ stats,
                                                const float* __restrict__ Wg,
                                                const float* __restrict__ sWg,
                                                const float* __restrict__ sWb,
                                                float* __restrict__ xin,
                                                float* __restrict__ z) {
  int bx = blockIdx.x; int bb = bx / 36; int l0 = (bx % 36) * 64;
  int tx = threadIdx.x & 63, ty = threadIdx.x >> 6;
  int e = blockIdx.y * 4 + ty;
  int l = l0 + tx;
  const float* xp = x + bb * CIN * LL + l;
  const float* wp = Wg + e * CIN;
  float acc = 0.f;
#pragma unroll 8
  for (int c = 0; c < CIN; c++) acc += wp[c] * xp[c * LL];
  float m = stats[(bb * LL + l) * 2], r = stats[(bb * LL + l) * 2 + 1];
  float val = r * (acc - m * sWg[e]) + sWb[e];
  if (e < DD) xin[(bb * DD + e) * LL + l] = val;
  else z[(bb * LL + l) * DD + (e - DD)] = val;
}

// ---------------- K3: depthwise 3x3 + silu -> xs t-major, 4 directions -------
__global__ __launch_bounds__(256) void k_dwconv(const float* __restrict__ xin,
                                                const float* __restrict__ wdw,
                                                const float* __restrict__ bdw,
                                                float* __restrict__ xs) {
  __shared__ float vt[32 * 194];
  int bid = blockIdx.x;
  int bb = bid / 72; int l0 = (bid % 72) * 32;
  for (int i = threadIdx.x; i < 32 * 192; i += 256) {
    int lj = i & 31, d = i >> 5;
    int l = l0 + lj;
    int h = l / WW, w = l % WW;
    const float* xp = xin + (bb * DD + d) * LL;
    const float* wq = wdw + d * 9;
    float acc = bdw[d];
#pragma unroll
    for (int kh = 0; kh < 3; kh++) {
      int ih = h + kh - 1; if (ih < 0 || ih >= HH) continue;
#pragma unroll
      for (int kw = 0; kw < 3; kw++) {
        int iw = w + kw - 1; if (iw < 0 || iw >= WW) continue;
        acc += xp[ih * WW + iw] * wq[kh * 3 + kw];
      }
    }
    vt[lj * 194 + d] = acc / (1.f + __expf(-acc));
  }
  __syncthreads();
  for (int j = threadIdx.x; j < 32 * 192; j += 256) {
    int d = j % 192, lj = j / 192;
    int l = l0 + lj;
    int h = l / WW, w = l % WW;
    int lt = w * HH + h;
    float v = vt[lj * 194 + d];
    xs[(((size_t)bb * KK + 0) * LL + l) * DD + d] = v;
    xs[(((size_t)bb * KK + 1) * LL + lt) * DD + d] = v;
    xs[(((size_t)bb * KK + 2) * LL + (LL - 1 - l)) * DD + d] = v;
    xs[(((size_t)bb * KK + 3) * LL + (LL - 1 - lt)) * DD + d] = v;
  }
}

// ---------------- K4: x_proj + delta; outputs t-major ------------------------
__global__ __launch_bounds__(256) void k_xproj(const float* __restrict__ xs,
                                               const float* __restrict__ xpw,
                                               const float* __restrict__ dtw,
                                               const float* __restrict__ dtb,
                                               float* __restrict__ Bsb,
                                               float* __restrict__ Csb,
                                               float* __restrict__ delta) {
  __shared__ float xls[192 * 65];
  __shared__ float dts[6 * 64];
  __shared__ float bcls[32 * 66];
  int bid = blockIdx.x;
  int tile = bid % 36; int bk = bid / 36; int k = bk % KK;
  int l0 = tile * 64;
  int tid = threadIdx.x;
  const float* xp = xs + (size_t)bk * LL * DD;
  for (int i = tid; i < 64 * 192; i += 256) {
    int l = i / 192, d = i % 192;
    xls[d * 65 + l] = xp[(l0 + l) * DD + d];
  }
  __syncthreads();
  int tx = tid & 63, ty = tid >> 6;
  for (int r = ty; r < RR + 2 * NN; r += 4) {
    const float* wr = xpw + (k * (RR + 2 * NN) + r) * DD;
    float acc = 0.f;
#pragma unroll 8
    for (int d = 0; d < DD; d++) acc += wr[d] * xls[d * 65 + tx];
    if (r < RR) dts[(r << 6) | tx] = acc;
    else bcls[(r - RR) * 66 + tx] = acc;
  }
  __syncthreads();
  for (int i = tid; i < 64 * 16; i += 256) {
    int l = i >> 4, n = i & 15;
    Bsb[((size_t)bk * LL + l0 + l) * NN + n] = bcls[n * 66 + l];
    Csb[((size_t)bk * LL + l0 + l) * NN + n] = bcls[(16 + n) * 66 + l];
  }
  for (int i = tid; i < 64 * 192; i += 256) {
    int l = i / 192, d = i % 192;
    const float* wd = dtw + (k * DD + d) * RR;
    float acc = dtb[k * DD + d];
#pragma unroll
    for (int r = 0; r < RR; r++) acc += wd[r] * dts[(r << 6) | l];
    float sp = acc > 20.f ? acc : log1pf(__expf(acc));
    delta[((size_t)bk * LL + l0 + l) * DD + d] = sp;
  }
}

// ---------------- K5a: chunked scan pass 1 — lane-owns-d, h[16] in VGPR ------
__global__ __launch_bounds__(192) void k_scan1(const float* __restrict__ delta,
                                               const float* __restrict__ xs,
                                               const float* __restrict__ Bsb,
                                               const float* __restrict__ A_logs,
                                               float* __restrict__ Pbuf,
                                               float* __restrict__ Sbuf) {
  __shared__ float Bls[LC * NN];
  int bid = blockIdx.x;
  int c = bid & (NCH - 1); int bk = bid >> 5; int k = bk & 3;
  int t0 = c * LC;
  int d = threadIdx.x;
  const float* bp = Bsb + ((size_t)bk * LL + t0) * NN;
  for (int i = d; i < LC * NN; i += 192) Bls[i] = bp[i];
  float A[NN];
  {
    const float4* ap = (const float4*)(A_logs + (k * DD + d) * NN);
#pragma unroll
    for (int j = 0; j < 4; j++) {
      float4 a4 = ap[j];
      A[4 * j + 0] = -__expf(a4.x); A[4 * j + 1] = -__expf(a4.y);
      A[4 * j + 2] = -__expf(a4.z); A[4 * j + 3] = -__expf(a4.w);
    }
  }
  float h[NN];
#pragma unroll
  for (int n = 0; n < NN; n++) h[n] = 0.f;
  float sd = 0.f;
  __syncthreads();
  const float* dp = delta + ((size_t)bk * LL + t0) * DD + d;
  const float* xp = xs + ((size_t)bk * LL + t0) * DD + d;
#pragma unroll 2
  for (int t = 0; t < LC; ++t) {
    float dt = dp[t * DD];
    float xv = xp[t * DD];
    float u = dt * xv;
    sd += dt;
    const float4* b4 = (const float4*)&Bls[t * NN];
#pragma unroll
    for (int j = 0; j < 4; j++) {
      float4 b = b4[j];
      h[4 * j + 0] = __expf(dt * A[4 * j + 0]) * h[4 * j + 0] + u * b.x;
      h[4 * j + 1] = __expf(dt * A[4 * j + 1]) * h[4 * j + 1] + u * b.y;
      h[4 * j + 2] = __expf(dt * A[4 * j + 2]) * h[4 * j + 2] + u * b.z;
      h[4 * j + 3] = __expf(dt * A[4 * j + 3]) * h[4 * j + 3] + u * b.w;
    }
  }
  int chn = (bk * DD + d) * NN;
  float* pp = Pbuf + (size_t)c * 24576 + chn;
  float* sp = Sbuf + (size_t)c * 24576 + chn;
#pragma unroll
  for (int n = 0; n < NN; n++) { pp[n] = __expf(A[n] * sd); sp[n] = h[n]; }
}

// ---------------- K5b: combine chunks ----------------------------------------
__global__ __launch_bounds__(256) void k_scan2(const float* __restrict__ Pbuf,
                                               const float* __restrict__ Sbuf,
                                               float* __restrict__ Hinit) {
  int idx = blockIdx.x * 256 + threadIdx.x;
  float h = 0.f;
  for (int c = 0; c < NCH; c++) {
    Hinit[(size_t)c * 24576 + idx] = h;
    h = Pbuf[(size_t)c * 24576 + idx] * h + Sbuf[(size_t)c * 24576 + idx];
  }
}

// ---------------- K5c: replay + emit ys — lane-owns-d, no shuffles -----------
__global__ __launch_bounds__(192) void k_scan3(const float* __restrict__ delta,
                                               const float* __restrict__ xs,
                                               const float* __restrict__ Bsb,
                                               const float* __restrict__ Csb,
                                               const float* __restrict__ A_logs,
                                               const float* __restrict__ Ds,
                                               const float* __restrict__ Hinit,
                                               float* __restrict__ ys) {
  __shared__ float Bls[LC * NN];
  __shared__ float Cls[LC * NN];
  int bid = blockIdx.x;
  int c = bid & (NCH - 1); int bk = bid >> 5; int k = bk & 3;
  int t0 = c * LC;
  int d = threadIdx.x;
  const float* bp = Bsb + ((size_t)bk * LL + t0) * NN;
  const float* cp = Csb + ((size_t)bk * LL + t0) * NN;
  for (int i = d; i < LC * NN; i += 192) { Bls[i] = bp[i]; Cls[i] = cp[i]; }
  float A[NN];
  {
    const float4* ap = (const float4*)(A_logs + (k * DD + d) * NN);
#pragma unroll
    for (int j = 0; j < 4; j++) {
      float4 a4 = ap[j];
      A[4 * j + 0] = -__expf(a4.x); A[4 * j + 1] = -__expf(a4.y);
      A[4 * j + 2] = -__expf(a4.z); A[4 * j + 3] = -__expf(a4.w);
    }
  }
  float Dv = Ds[k * DD + d];
  float h[NN];
  {
    const float4* hp = (const float4*)(Hinit + (size_t)c * 24576 + (bk * DD + d) * NN);
#pragma unroll
    for (int j = 0; j < 4; j++) {
      float4 h4 = hp[j];
      h[4 * j + 0] = h4.x; h[4 * j + 1] = h4.y;
      h[4 * j + 2] = h4.z; h[4 * j + 3] = h4.w;
    }
  }
  __syncthreads();
  const float* dp = delta + ((size_t)bk * LL + t0) * DD + d;
  const float* xp = xs + ((size_t)bk * LL + t0) * DD + d;
  float* yp = ys + ((size_t)bk * LL + t0) * DD + d;
#pragma unroll 2
  for (int t = 0; t < LC; ++t) {
    float dt = dp[t * DD];
    float xv = xp[t * DD];
    float u = dt * xv;
    float y = 0.f;
    const float4* b4 = (const float4*)&Bls[t * NN];
    const float4* c4 = (const float4*)&Cls[t * NN];
#pragma unroll
    for (int j = 0; j < 4; j++) {
      float4 b = b4[j];
      float4 cc = c4[j];
      h[4 * j + 0] = __expf(dt * A[4 * j + 0]) * h[4 * j + 0] + u * b.x;
      h[4 * j + 1] = __expf(dt * A[4 * j + 1]) * h[4 * j + 1] + u * b.y;
      h[4 * j + 2] = __expf(dt * A[4 * j + 2]) * h[4 * j + 2] + u * b.z;
      h[4 * j + 3] = __expf(dt * A[4 * j + 3]) * h[4 * j + 3] + u * b.w;
      y += h[4 * j + 0] * cc.x + h[4 * j + 1] * cc.y
         + h[4 * j + 2] * cc.z + h[4 * j + 3] * cc.w;
    }
    yp[t * DD] = y + Dv * xv;
  }
}

// ---------------- K6a: gather 4 dirs + out_norm LN + silu(z) -----------------
__global__ __launch_bounds__(256) void k_combine(const float* __restrict__ ys,
                                                 const float* __restrict__ z,
                                                 const float* __restrict__ ong,
                                                 const float* __restrict__ onb,
                                                 float* __restrict__ ya) {
  __shared__ float yt[64 * 201];
  int bx = blockIdx.x; int bb = bx / 36; int l0 = (bx % 36) * 64;
  int tid = threadIdx.x;
  for (int i = tid; i < 64 * DD; i += 256) {
    int p = i / DD, d = i - p * DD;
    int l = l0 + p; int h = l / WW, w = l - h * WW;
    int t1 = w * HH + h;
    float v = ys[(((size_t)bb * KK + 0) * LL + l) * DD + d]
            + ys[(((size_t)bb * KK + 1) * LL + t1) * DD + d]
            + ys[(((size_t)bb * KK + 2) * LL + (LL - 1 - l)) * DD + d]
            + ys[(((size_t)bb * KK + 3) * LL + (LL - 1 - t1)) * DD + d];
    yt[p * 201 + d] = v;
  }
  __syncthreads();
  int p = tid >> 2, q = tid & 3;
  int l = l0 + p;
  float s = 0.f, ss = 0.f;
  for (int d = q * 48; d < q * 48 + 48; d++) { float v = yt[p * 201 + d]; s += v; ss += v * v; }
  s += __shfl_xor(s, 1, 64); s += __shfl_xor(s, 2, 64);
  ss += __shfl_xor(ss, 1, 64); ss += __shfl_xor(ss, 2, 64);
  float m = s / DD, var = ss / DD - m * m;
  float rr = rsqrtf(var + EPSF);
  const float* zp = z + (bb * LL + l) * DD;
  for (int d = q * 48; d < q * 48 + 48; d++) {
    float v = (yt[p * 201 + d] - m) * rr * ong[d] + onb[d];
    float zv = zp[d];
    yt[p * 201 + d] = v * zv / (1.f + __expf(-zv));
  }
  __syncthreads();
  for (int i = tid; i < 64 * DD; i += 256) {
    int d = i >> 6, p2 = i & 63;
    ya[(bb * DD + d) * LL + l0 + p2] = yt[p2 * 201 + d];
  }
}

// ---------------- K6b: out_proj GEMM + residual -> xm ------------------------
__global__ __launch_bounds__(256) void k_outproj(const float* __restrict__ ya,
                                                 const float* __restrict__ wout,
                                                 const float* __restrict__ x,
                                                 float* __restrict__ xm) {
  int bx = blockIdx.x; int bb = bx / 36; int l0 = (bx % 36) * 64;
  int tx = threadIdx.x & 63, ty = threadIdx.x >> 6;
  int cc = blockIdx.y * 4 + ty;
  int l = l0 + tx;
  const float* yp = ya + bb * DD * LL + l;
  const float* wp = wout + cc * DD;
  float acc = 0.f;
#pragma unroll 8
  for (int d = 0; d < DD; d++) acc += yp[d * LL] * wp[d];
  xm[(bb * CIN + cc) * LL + l] = x[(bb * CIN + cc) * LL + l] + acc;
}

// ---------------- K7: weight transpose/concat --------------------------------
__global__ __launch_bounds__(256) void k_prepw(const float* __restrict__ w31,
                                               const float* __restrict__ w32,
                                               const float* __restrict__ w33,
                                               const float* __restrict__ w1,
                                               float* __restrict__ At1,
                                               float* __restrict__ At2,
                                               float* __restrict__ w1t) {
  int idx = blockIdx.x * 256 + threadIdx.x;
  if (idx < 331776) {
    int k = idx / 384, m = idx % 384;
    At1[idx] = (m < 192) ? w31[m * 864 + k] : w32[(m - 192) * 864 + k];
  } else if (idx < 663552) {
    int i = idx - 331776; int k = i / 192, m = i % 192;
    At2[i] = w33[m * 1728 + k];
  } else if (idx < 681984) {
    int i = idx - 663552; int k = i / 192, m = i % 192;
    w1t[i] = w1[m * 96 + k];
  }
}

// ---------------- K8: im2col (stride-2 3x3) over xm --------------------------
__global__ __launch_bounds__(256) void k_pack1(const float* __restrict__ xm,
                                               float* __restrict__ Bm1) {
  int idx4 = blockIdx.x * 256 + threadIdx.x;
  if (idx4 >= 864 * 288) return;
  int k = idx4 / 288; int n = (idx4 % 288) * 4;
  int ci = k / 9, r9 = k % 9, kh = r9 / 3, kw = r9 % 3;
  int bb = n / OHW, rem = n % OHW, oh = rem / OW, ow0 = rem % OW;
  int ih = 2 * oh + kh - 1;
  float4 v = {0.f, 0.f, 0.f, 0.f};
  if (ih >= 0 && ih < HH) {
    const float* base = xm + (bb * CIN + ci) * LL + ih * WW;
    int iw0 = 2 * ow0 + kw - 1;
    v.x = (iw0 >= 0) ? base[iw0] : 0.f;
    v.y = base[iw0 + 2];
    v.z = base[iw0 + 4];
    v.w = base[iw0 + 6];
  }
  *(float4*)&Bm1[k * NPX + n] = v;
}

// ---------------- K9: im2col (stride-1 3x3) over t3 --------------------------
__global__ __launch_bounds__(256) void k_pack2(const float* __restrict__ t3,
                                               float* __restrict__ Bm2) {
  int idx4 = blockIdx.x * 256 + threadIdx.x;
  if (idx4 >= 1728 * 288) return;
  int k = idx4 / 288; int n = (idx4 % 288) * 4;
  int ci = k / 9, r9 = k % 9, kh = r9 / 3, kw = r9 % 3;
  int bb = n / OHW, rem = n % OHW, oh = rem / OW, ow0 = rem % OW;
  int ih = oh + kh - 1;
  float4 v = {0.f, 0.f, 0.f, 0.f};
  if (ih >= 0 && ih < OH) {
    const float* base = t3 + (bb * COUT + ci) * OHW + ih * OW;
    int iw0 = ow0 + kw - 1;
    v.x = (iw0 >= 0) ? base[iw0] : 0.f;
    v.y = base[iw0 + 1];
    v.z = base[iw0 + 2];
    v.w = (iw0 + 3 < OW) ? base[iw0 + 3] : 0.f;
  }
  *(float4*)&Bm2[k * NPX + n] = v;
}

// ---------------- K10: tiled GEMM, 64x64 block tile, 4x4 micro, split-K ------
template<int MT, int KCHUNK, int BROWMUL, int BROWADD, int EPI>
__global__ __launch_bounds__(256) void k_gemm(const float* __restrict__ At,
                                              const float* __restrict__ Bm,
                                              float* __restrict__ Cout,
                                              const float* __restrict__ bias,
                                              const float* __restrict__ bn_g,
                                              const float* __restrict__ bn_b,
                                              const float* __restrict__ bn_m,
                                              const float* __restrict__ bn_v,
                                              const float* __restrict__ prelu_a,
                                              int bnoff) {
  __shared__ float As[16][64];
  __shared__ float Bs[16][64];
  int n0 = blockIdx.x * 64;
  int m0 = blockIdx.y * 64;
  int kz = blockIdx.z;
  int k0 = kz * KCHUNK;
  int tid = threadIdx.x;
  int lr = tid >> 4;
  int lc = (tid & 15) * 4;
  int tm = tid >> 4;
  int tn = tid & 15;
  float acc[4][4] = {};
  for (int ks = 0; ks < KCHUNK; ks += 16) {
    int kg = k0 + ks + lr;
    *(float4*)&As[lr][lc] = *(const float4*)&At[kg * MT + m0 + lc];
    *(float4*)&Bs[lr][lc] = *(const float4*)&Bm[(kg * BROWMUL + BROWADD) * NPX + n0 + lc];
    __syncthreads();
#pragma unroll
    for (int kk = 0; kk < 16; kk++) {
      float4 a = *(float4*)&As[kk][tm * 4];
      float4 b = *(float4*)&Bs[kk][tn * 4];
      acc[0][0] += a.x * b.x; acc[0][1] += a.x * b.y; acc[0][2] += a.x * b.z; acc[0][3] += a.x * b.w;
      acc[1][0] += a.y * b.x; acc[1][1] += a.y * b.y; acc[1][2] += a.y * b.z; acc[1][3] += a.y * b.w;
      acc[2][0] += a.z * b.x; acc[2][1] += a.z * b.y; acc[2][2] += a.z * b.z; acc[2][3] += a.z * b.w;
      acc[3][0] += a.w * b.x; acc[3][1] += a.w * b.y; acc[3][2] += a.w * b.z; acc[3][3] += a.w * b.w;
    }
    __syncthreads();
  }
  if (EPI == 0) {
    float* cp = Cout + ((size_t)kz * MT + m0) * NPX + n0;
#pragma unroll
    for (int i = 0; i < 4; i++) {
      float4 v = {acc[i][0], acc[i][1], acc[i][2], acc[i][3]};
      *(float4*)&cp[(tm * 4 + i) * NPX + tn * 4] = v;
    }
  } else {
    int n = n0 + tn * 4;
    int bb = n / OHW, o = n % OHW;
    float aslope = prelu_a[0];
#pragma unroll
    for (int i = 0; i < 4; i++) {
      int co = m0 + tm * 4 + i;
      int cc = bnoff + co;
      float scale = rsqrtf(bn_v[cc] + EPSF) * bn_g[cc];
      float shift = bn_b[cc] - bn_m[cc] * scale;
      float bv = bias[co];
      float4 v;
      v.x = (acc[i][0] + bv) * scale + shift;
      v.y = (acc[i][1] + bv) * scale + shift;
      v.z = (acc[i][2] + bv) * scale + shift;
      v.w = (acc[i][3] + bv) * scale + shift;
      v.x = v.x > 0.f ? v.x : aslope * v.x;
      v.y = v.y > 0.f ? v.y : aslope * v.y;
      v.z = v.z > 0.f ? v.z : aslope * v.z;
      v.w = v.w > 0.f ? v.w : aslope * v.w;
      *(float4*)&Cout[((size_t)bb * 576 + cc) * OHW + o] = v;
    }
  }
}

// ---------------- K11: reduce split-K (w31 -> out x2 w/ BN; w32 -> t3) -------
__global__ __launch_bounds__(256) void k_reduce1(const float* __restrict__ Cp1,
                                                 const float* __restrict__ b31,
                                                 const float* __restrict__ b32,
                                                 const float* __restrict__ bn_g,
                                                 const float* __restrict__ bn_b,
                                                 const float* __restrict__ bn_m,
                                                 const float* __restrict__ bn_v,
                                                 const float* __restrict__ prelu_a,
                                                 float* __restrict__ out,
                                                 float* __restrict__ t3) {
  int idx = blockIdx.x * 256 + threadIdx.x;
  if (idx >= 384 * NPX) return;
  int m = idx / NPX, n = idx % NPX;
  float s = 0.f;
#pragma unroll
  for (int c = 0; c < 6; c++) s += Cp1[(size_t)c * 384 * NPX + idx];
  int bb = n / OHW, o = n % OHW;
  if (m < 192) {
    s += b31[m];
    int cc = 192 + m;
    float scale = rsqrtf(bn_v[cc] + EPSF) * bn_g[cc];
    float v = s * scale + (bn_b[cc] - bn_m[cc] * scale);
    float a = prelu_a[0];
    out[((size_t)bb * 576 + cc) * OHW + o] = v > 0.f ? v : a * v;
  } else {
    s += b32[m - 192];
    t3[((size_t)bb * COUT + (m - 192)) * OHW + o] = s;
  }
}

// ---------------- K12: reduce split-K for w33 -> out x3 w/ BN ----------------
__global__ __launch_bounds__(256) void k_reduce2(const float* __restrict__ Cp2,
                                                 const float* __restrict__ b33,
                                                 const float* __restrict__ bn_g,
                                                 const float* __restrict__ bn_b,
                                                 const float* __restrict__ bn_m,
                                                 const float* __restrict__ bn_v,
                                                 const float* __restrict__ prelu_a,
                                                 float* __restrict__ out) {
  int idx = blockIdx.x * 256 + threadIdx.x;
  if (idx >= 192 * NPX) return;
  int m = idx / NPX, n = idx % NPX;
  float s = b33[m];
#pragma unroll
  for (int c = 0; c < 9; c++) s += Cp2[(size_t)c * 192 * NPX + idx];
  int bb = n / OHW, o = n % OHW;
  int cc = 384 + m;
  float scale = rsqrtf(bn_v[cc] + EPSF) * bn_g[cc];
  float v = s * scale + (bn_b[cc] - bn_m[cc] * scale);
  float a = prelu_a[0];
  out[((size_t)bb * 576 + cc) * OHW + o] = v > 0.f ? v : a * v;
}

extern "C" void kernel_launch(void* const* d_in, const int* in_sizes, int n_in,
                              void* d_out, int out_size, void* d_ws, size_t ws_size,
                              hipStream_t stream) {
  const float* x        = (const float*)d_in[0];
  const float* ln_g     = (const float*)d_in[1];
  const float* ln_b     = (const float*)d_in[2];
  const float* in_proj_w= (const float*)d_in[3];
  const float* dwconv_w = (const float*)d_in[4];
  const float* dwconv_b = (const float*)d_in[5];
  const float* x_proj_w = (const float*)d_in[6];
  const float* dt_w     = (const float*)d_in[7];
  const float* dt_b     = (const float*)d_in[8];
  const float* A_logs   = (const float*)d_in[9];
  const float* Ds       = (const float*)d_in[10];
  const float* out_norm_g = (const float*)d_in[11];
  const float* out_norm_b = (const float*)d_in[12];
  const float* out_proj_w = (const float*)d_in[13];
  const float* w1  = (const float*)d_in[14];
  const float* b1  = (const float*)d_in[15];
  const float* w31 = (const float*)d_in[16];
  const float* b31 = (const float*)d_in[17];
  const float* w32 = (const float*)d_in[18];
  const float* b32 = (const float*)d_in[19];
  const float* w33 = (const float*)d_in[20];
  const float* b33 = (const float*)d_in[21];
  const float* bn_g = (const float*)d_in[22];
  const float* bn_b = (const float*)d_in[23];
  const float* bn_m = (const float*)d_in[24];
  const float* bn_v = (const float*)d_in[25];
  const float* prelu_a = (const float*)d_in[26];

  float* ws = (float*)d_ws;
  float* ya    = ws;                    // 884736 (live k_combine..k_outproj)
  float* Hinit = ws;                    // 786432 (live scan2..scan3; dead before ya written)
  float* xin   = ws + 884736;           // 884736 ; later xm/t3
  float* xm    = xin;                   // 442368
  float* t3    = xin + 442368;          // 221184
  float* z     = ws + 1769472;          // 884736
  float* xs    = ws + 2654208;          // 3538944
  float* delta = ws + 6193152;          // 3538944
  float* ys    = ws + 9732096;          // 3538944 (P/S union: dead before scan3 writes)
  float* Pbuf  = ys;                    // 786432
  float* Sbuf  = ys + 786432;           // 786432
  float* Bsb   = ws + 13271040;         // 294912
  float* Csb   = ws + 13565952;         // 294912
  float* Wg    = ws + 14450688;         // 36864
  float* sWg   = ws + 14487552;         // 384
  float* sWb   = ws + 14487936;         // 384
  float* stats = ws + 14488320;         // 9216
  // conv-stage pool reuses dead scan pool
  float* At1 = ws + 1769472;            // 331776
  float* At2 = ws + 2101248;            // 331776
  float* w1t = ws + 2433024;            // 18432
  float* Bm1 = ws + 2451456;            // 995328
  float* Bm2 = ws + 3446784;            // 1990656
  float* Cp1 = ws + 5437440;            // 2654208
  float* Cp2 = ws + 8091648;            // 1990656
  float* out = (float*)d_out;

  k_prep<<<73, 256, 0, stream>>>(x, ln_g, ln_b, in_proj_w, stats, Wg, sWg, sWb);
  k_inproj<<<dim3(72, 96), 256, 0, stream>>>(x, stats, Wg, sWg, sWb, xin, z);
  k_dwconv<<<144, 256, 0, stream>>>(xin, dwconv_w, dwconv_b, xs);
  k_xproj<<<288, 256, 0, stream>>>(xs, x_proj_w, dt_w, dt_b, Bsb, Csb, delta);
  k_scan1<<<256, 192, 0, stream>>>(delta, xs, Bsb, A_logs, Pbuf, Sbuf);
  k_scan2<<<96, 256, 0, stream>>>(Pbuf, Sbuf, Hinit);
  k_scan3<<<256, 192, 0, stream>>>(delta, xs, Bsb, Csb, A_logs, Ds, Hinit, ys);
  k_combine<<<72, 256, 0, stream>>>(ys, z, out_norm_g, out_norm_b, ya);
  k_prepw<<<2665, 256, 0, stream>>>(w31, w32, w33, w1, At1, At2, w1t);
  k_outproj<<<dim3(72, 24), 256, 0, stream>>>(ya, out_proj_w, x, xm);
  k_pack1<<<972, 256, 0, stream>>>(xm, Bm1);
  k_gemm<384, 144, 1, 0, 0><<<dim3(18, 6, 6), 256, 0, stream>>>(
      At1, Bm1, Cp1, nullptr, nullptr, nullptr, nullptr, nullptr, nullptr, 0);
  k_gemm<192, 96, 9, 4, 1><<<dim3(18, 3, 1), 256, 0, stream>>>(
      w1t, Bm1, out, b1, bn_g, bn_b, bn_m, bn_v, prelu_a, 0);
  k_reduce1<<<1728, 256, 0, stream>>>(Cp1, b31, b32, bn_g, bn_b, bn_m, bn_v,
                                      prelu_a, out, t3);
  k_pack2<<<1944, 256, 0, stream>>>(t3, Bm2);
  k_gemm<192, 192, 1, 0, 0><<<dim3(18, 3, 9), 256, 0, stream>>>(
      At2, Bm2, Cp2, nullptr, nullptr, nullptr, nullptr, nullptr, nullptr, 0);
  k_reduce2<<<864, 256, 0, stream>>>(Cp2, b33, bn_g, bn_b, bn_m, bn_v, prelu_a, out);
}

// Round 5
// 275.554 us; speedup vs baseline: 4.4402x; 1.2534x over previous
//
#include <hip/hip_runtime.h>
#include <math.h>

#define BB_ 2
#define HH 48
#define WW 48
#define LL 2304
#define CIN 96
#define DD 192
#define KK 4
#define NN 16
#define RR 6
#define NCH 32
#define LC 72
#define COUT 192
#define OH 24
#define OW 24
#define OHW 576
#define NPX 1152
#define NTOT 4608
#define EPSF 1e-5f

// ---------------- K1: LN stats + folded weight prep + At3 (xpw^T) ------------
__global__ __launch_bounds__(256) void k_prep(const float* __restrict__ x,
                                              const float* __restrict__ g,
                                              const float* __restrict__ b,
                                              const float* __restrict__ inw,
                                              const float* __restrict__ xpw,
                                              float* __restrict__ stats,
                                              float* __restrict__ WgT,
                                              float* __restrict__ sWg,
                                              float* __restrict__ sWb,
                                              float* __restrict__ At3) {
  int bx = blockIdx.x;
  if (bx < 72) {
    int bb = bx / 36; int l0 = (bx % 36) * 64;
    int p = threadIdx.x >> 2, q = threadIdx.x & 3;
    int l = l0 + p;
    const float* xp = x + bb * CIN * LL + l;
    float s = 0.f, ss = 0.f;
    for (int c = q; c < CIN; c += 4) { float v = xp[c * LL]; s += v; ss += v * v; }
    s += __shfl_xor(s, 1, 64); s += __shfl_xor(s, 2, 64);
    ss += __shfl_xor(ss, 1, 64); ss += __shfl_xor(ss, 2, 64);
    if (q == 0) {
      float m = s / CIN; float var = ss / CIN - m * m;
      stats[(bb * LL + l) * 2 + 0] = m;
      stats[(bb * LL + l) * 2 + 1] = rsqrtf(var + EPSF);
    }
  } else if (bx == 72) {
    for (int e = threadIdx.x; e < 2 * DD; e += 256) {
      float swg = 0.f, swb = 0.f;
      for (int c = 0; c < CIN; c++) {
        float w = inw[e * CIN + c];
        float wg = w * g[c];
        WgT[c * 384 + e] = wg;
        swg += wg; swb += w * b[c];
      }
      sWg[e] = swg; sWb[e] = swb;
    }
  } else {
    int idx = (bx - 73) * 256 + threadIdx.x;   // 0..36863 : At3[d*192+m]
    if (idx < 192 * 192) {
      int m = idx % 192;
      int d = idx / 192;
      At3[idx] = (m < 152) ? xpw[m * 192 + d] : 0.f;
    }
  }
}

// ---------------- K3: depthwise 3x3 + silu -> xs t-major ×4 + xsl l-major ----
__global__ __launch_bounds__(256) void k_dwconv(const float* __restrict__ xin,
                                                const float* __restrict__ wdw,
                                                const float* __restrict__ bdw,
                                                float* __restrict__ xs,
                                                float* __restrict__ xsl) {
  __shared__ float vt[32 * 194];
  int bid = blockIdx.x;
  int bb = bid / 72; int l0 = (bid % 72) * 32;
  for (int i = threadIdx.x; i < 32 * 192; i += 256) {
    int lj = i & 31, d = i >> 5;
    int l = l0 + lj;
    int h = l / WW, w = l % WW;
    const float* xp = xin + (bb * DD + d) * LL;
    const float* wq = wdw + d * 9;
    float acc = bdw[d];
#pragma unroll
    for (int kh = 0; kh < 3; kh++) {
      int ih = h + kh - 1; if (ih < 0 || ih >= HH) continue;
#pragma unroll
      for (int kw = 0; kw < 3; kw++) {
        int iw = w + kw - 1; if (iw < 0 || iw >= WW) continue;
        acc += xp[ih * WW + iw] * wq[kh * 3 + kw];
      }
    }
    vt[lj * 194 + d] = acc / (1.f + __expf(-acc));
  }
  __syncthreads();
  for (int j = threadIdx.x; j < 32 * 192; j += 256) {
    int d = j % 192, lj = j / 192;
    int l = l0 + lj;
    int h = l / WW, w = l % WW;
    int lt = w * HH + h;
    float v = vt[lj * 194 + d];
    xs[(((size_t)bb * KK + 0) * LL + l) * DD + d] = v;
    xs[(((size_t)bb * KK + 1) * LL + lt) * DD + d] = v;
    xs[(((size_t)bb * KK + 2) * LL + (LL - 1 - l)) * DD + d] = v;
    xs[(((size_t)bb * KK + 3) * LL + (LL - 1 - lt)) * DD + d] = v;
  }
  for (int j = threadIdx.x; j < 32 * 192; j += 256) {
    int d = j >> 5, lj = j & 31;
    xsl[(size_t)d * NTOT + bb * LL + l0 + lj] = vt[lj * 194 + d];
  }
}

// ---------------- K-dtsplit: dts -> delta (softplus) + Bsb/Csb, permuted -----
__global__ __launch_bounds__(256) void k_dtsplit(const float* __restrict__ C1,
                                                 const float* __restrict__ dtw,
                                                 const float* __restrict__ dtb,
                                                 float* __restrict__ Bsb,
                                                 float* __restrict__ Csb,
                                                 float* __restrict__ delta) {
  __shared__ float lds[38 * 33];
  int bid = blockIdx.x;                  // bk*72 + tile
  int tile = bid % 72; int bk = bid / 72; int bb = bk >> 2; int k = bk & 3;
  int l0 = tile * 32;
  int tid = threadIdx.x;
  for (int i = tid; i < 38 * 32; i += 256) {
    int r = i >> 5, lj = i & 31;
    lds[r * 33 + lj] = C1[(size_t)(k * 38 + r) * NTOT + bb * LL + l0 + lj];
  }
  __syncthreads();
  for (int i = tid; i < 32 * 16; i += 256) {
    int lj = i >> 4, n = i & 15;
    int l = l0 + lj; int h = l / WW, w = l % WW; int lt = w * HH + h;
    int pos = (k == 0) ? l : (k == 1) ? lt : (k == 2) ? (LL - 1 - l) : (LL - 1 - lt);
    size_t base = ((size_t)bk * LL + pos) * NN + n;
    Bsb[base] = lds[(6 + n) * 33 + lj];
    Csb[base] = lds[(22 + n) * 33 + lj];
  }
  for (int i = tid; i < 32 * 192; i += 256) {
    int lj = i / 192, d = i - lj * 192;
    int l = l0 + lj; int h = l / WW, w = l % WW; int lt = w * HH + h;
    int pos = (k == 0) ? l : (k == 1) ? lt : (k == 2) ? (LL - 1 - l) : (LL - 1 - lt);
    const float* wd = dtw + (k * DD + d) * RR;
    float acc = dtb[k * DD + d];
#pragma unroll
    for (int r = 0; r < RR; r++) acc += wd[r] * lds[r * 33 + lj];
    float sp = acc > 20.f ? acc : log1pf(__expf(acc));
    delta[((size_t)bk * LL + pos) * DD + d] = sp;
  }
}

// ---------------- K5a: chunked scan pass 1 — lane-owns-d, h[16] in VGPR ------
__global__ __launch_bounds__(192) void k_scan1(const float* __restrict__ delta,
                                               const float* __restrict__ xs,
                                               const float* __restrict__ Bsb,
                                               const float* __restrict__ A_logs,
                                               float* __restrict__ Pbuf,
                                               float* __restrict__ Sbuf) {
  __shared__ float Bls[LC * NN];
  int bid = blockIdx.x;
  int c = bid & (NCH - 1); int bk = bid >> 5; int k = bk & 3;
  int t0 = c * LC;
  int d = threadIdx.x;
  const float* bp = Bsb + ((size_t)bk * LL + t0) * NN;
  for (int i = d; i < LC * NN; i += 192) Bls[i] = bp[i];
  float A[NN];
  {
    const float4* ap = (const float4*)(A_logs + (k * DD + d) * NN);
#pragma unroll
    for (int j = 0; j < 4; j++) {
      float4 a4 = ap[j];
      A[4 * j + 0] = -__expf(a4.x); A[4 * j + 1] = -__expf(a4.y);
      A[4 * j + 2] = -__expf(a4.z); A[4 * j + 3] = -__expf(a4.w);
    }
  }
  float h[NN];
#pragma unroll
  for (int n = 0; n < NN; n++) h[n] = 0.f;
  float sd = 0.f;
  __syncthreads();
  const float* dp = delta + ((size_t)bk * LL + t0) * DD + d;
  const float* xp = xs + ((size_t)bk * LL + t0) * DD + d;
#pragma unroll 2
  for (int t = 0; t < LC; ++t) {
    float dt = dp[t * DD];
    float xv = xp[t * DD];
    float u = dt * xv;
    sd += dt;
    const float4* b4 = (const float4*)&Bls[t * NN];
#pragma unroll
    for (int j = 0; j < 4; j++) {
      float4 b = b4[j];
      h[4 * j + 0] = __expf(dt * A[4 * j + 0]) * h[4 * j + 0] + u * b.x;
      h[4 * j + 1] = __expf(dt * A[4 * j + 1]) * h[4 * j + 1] + u * b.y;
      h[4 * j + 2] = __expf(dt * A[4 * j + 2]) * h[4 * j + 2] + u * b.z;
      h[4 * j + 3] = __expf(dt * A[4 * j + 3]) * h[4 * j + 3] + u * b.w;
    }
  }
  int chn = (bk * DD + d) * NN;
  float* pp = Pbuf + (size_t)c * 24576 + chn;
  float* sp = Sbuf + (size_t)c * 24576 + chn;
#pragma unroll
  for (int n = 0; n < NN; n++) { pp[n] = __expf(A[n] * sd); sp[n] = h[n]; }
}

// ---------------- K5b: combine chunks ----------------------------------------
__global__ __launch_bounds__(256) void k_scan2(const float* __restrict__ Pbuf,
                                               const float* __restrict__ Sbuf,
                                               float* __restrict__ Hinit) {
  int idx = blockIdx.x * 256 + threadIdx.x;
  float h = 0.f;
  for (int c = 0; c < NCH; c++) {
    Hinit[(size_t)c * 24576 + idx] = h;
    h = Pbuf[(size_t)c * 24576 + idx] * h + Sbuf[(size_t)c * 24576 + idx];
  }
}

// ---------------- K5c: replay + emit ys — lane-owns-d, no shuffles -----------
__global__ __launch_bounds__(192) void k_scan3(const float* __restrict__ delta,
                                               const float* __restrict__ xs,
                                               const float* __restrict__ Bsb,
                                               const float* __restrict__ Csb,
                                               const float* __restrict__ A_logs,
                                               const float* __restrict__ Ds,
                                               const float* __restrict__ Hinit,
                                               float* __restrict__ ys) {
  __shared__ float Bls[LC * NN];
  __shared__ float Cls[LC * NN];
  int bid = blockIdx.x;
  int c = bid & (NCH - 1); int bk = bid >> 5; int k = bk & 3;
  int t0 = c * LC;
  int d = threadIdx.x;
  const float* bp = Bsb + ((size_t)bk * LL + t0) * NN;
  const float* cp = Csb + ((size_t)bk * LL + t0) * NN;
  for (int i = d; i < LC * NN; i += 192) { Bls[i] = bp[i]; Cls[i] = cp[i]; }
  float A[NN];
  {
    const float4* ap = (const float4*)(A_logs + (k * DD + d) * NN);
#pragma unroll
    for (int j = 0; j < 4; j++) {
      float4 a4 = ap[j];
      A[4 * j + 0] = -__expf(a4.x); A[4 * j + 1] = -__expf(a4.y);
      A[4 * j + 2] = -__expf(a4.z); A[4 * j + 3] = -__expf(a4.w);
    }
  }
  float Dv = Ds[k * DD + d];
  float h[NN];
  {
    const float4* hp = (const float4*)(Hinit + (size_t)c * 24576 + (bk * DD + d) * NN);
#pragma unroll
    for (int j = 0; j < 4; j++) {
      float4 h4 = hp[j];
      h[4 * j + 0] = h4.x; h[4 * j + 1] = h4.y;
      h[4 * j + 2] = h4.z; h[4 * j + 3] = h4.w;
    }
  }
  __syncthreads();
  const float* dp = delta + ((size_t)bk * LL + t0) * DD + d;
  const float* xp = xs + ((size_t)bk * LL + t0) * DD + d;
  float* yp = ys + ((size_t)bk * LL + t0) * DD + d;
#pragma unroll 2
  for (int t = 0; t < LC; ++t) {
    float dt = dp[t * DD];
    float xv = xp[t * DD];
    float u = dt * xv;
    float y = 0.f;
    const float4* b4 = (const float4*)&Bls[t * NN];
    const float4* c4 = (const float4*)&Cls[t * NN];
#pragma unroll
    for (int j = 0; j < 4; j++) {
      float4 b = b4[j];
      float4 cc = c4[j];
      h[4 * j + 0] = __expf(dt * A[4 * j + 0]) * h[4 * j + 0] + u * b.x;
      h[4 * j + 1] = __expf(dt * A[4 * j + 1]) * h[4 * j + 1] + u * b.y;
      h[4 * j + 2] = __expf(dt * A[4 * j + 2]) * h[4 * j + 2] + u * b.z;
      h[4 * j + 3] = __expf(dt * A[4 * j + 3]) * h[4 * j + 3] + u * b.w;
      y += h[4 * j + 0] * cc.x + h[4 * j + 1] * cc.y
         + h[4 * j + 2] * cc.z + h[4 * j + 3] * cc.w;
    }
    yp[t * DD] = y + Dv * xv;
  }
}

// ---------------- K6a: gather 4 dirs + out_norm LN + silu(z) -----------------
__global__ __launch_bounds__(256) void k_combine(const float* __restrict__ ys,
                                                 const float* __restrict__ z,
                                                 const float* __restrict__ ong,
                                                 const float* __restrict__ onb,
                                                 float* __restrict__ ya) {
  __shared__ float yt[64 * 201];
  int bx = blockIdx.x; int bb = bx / 36; int l0 = (bx % 36) * 64;
  int tid = threadIdx.x;
  for (int i = tid; i < 64 * DD; i += 256) {
    int p = i / DD, d = i - p * DD;
    int l = l0 + p; int h = l / WW, w = l - h * WW;
    int t1 = w * HH + h;
    float v = ys[(((size_t)bb * KK + 0) * LL + l) * DD + d]
            + ys[(((size_t)bb * KK + 1) * LL + t1) * DD + d]
            + ys[(((size_t)bb * KK + 2) * LL + (LL - 1 - l)) * DD + d]
            + ys[(((size_t)bb * KK + 3) * LL + (LL - 1 - t1)) * DD + d];
    yt[p * 201 + d] = v;
  }
  __syncthreads();
  int p = tid >> 2, q = tid & 3;
  int l = l0 + p;
  float s = 0.f, ss = 0.f;
  for (int d = q * 48; d < q * 48 + 48; d++) { float v = yt[p * 201 + d]; s += v; ss += v * v; }
  s += __shfl_xor(s, 1, 64); s += __shfl_xor(s, 2, 64);
  ss += __shfl_xor(ss, 1, 64); ss += __shfl_xor(ss, 2, 64);
  float m = s / DD, var = ss / DD - m * m;
  float rr = rsqrtf(var + EPSF);
  const float* zp = z + (bb * LL + l) * DD;
  for (int d = q * 48; d < q * 48 + 48; d++) {
    float v = (yt[p * 201 + d] - m) * rr * ong[d] + onb[d];
    float zv = zp[d];
    yt[p * 201 + d] = v * zv / (1.f + __expf(-zv));
  }
  __syncthreads();
  for (int i = tid; i < 64 * DD; i += 256) {
    int d = i >> 6, p2 = i & 63;
    ya[(bb * DD + d) * LL + l0 + p2] = yt[p2 * 201 + d];
  }
}

// ---------------- K7: weight transpose/concat --------------------------------
__global__ __launch_bounds__(256) void k_prepw(const float* __restrict__ w31,
                                               const float* __restrict__ w32,
                                               const float* __restrict__ w33,
                                               const float* __restrict__ w1,
                                               const float* __restrict__ wout,
                                               float* __restrict__ At1,
                                               float* __restrict__ At2,
                                               float* __restrict__ w1t,
                                               float* __restrict__ woutT) {
  int idx = blockIdx.x * 256 + threadIdx.x;
  if (idx < 331776) {
    int k = idx / 384, m = idx % 384;
    At1[idx] = (m < 192) ? w31[m * 864 + k] : w32[(m - 192) * 864 + k];
  } else if (idx < 663552) {
    int i = idx - 331776; int k = i / 192, m = i % 192;
    At2[i] = w33[m * 1728 + k];
  } else if (idx < 681984) {
    int i = idx - 663552; int k = i / 192, m = i % 192;
    w1t[i] = w1[m * 96 + k];
  } else if (idx < 706560) {
    int i = idx - 681984; int d = i / 128, e = i % 128;
    woutT[i] = (e < 96) ? wout[e * 192 + d] : 0.f;
  }
}

// ---------------- K8: im2col (stride-2 3x3) over xm --------------------------
__global__ __launch_bounds__(256) void k_pack1(const float* __restrict__ xm,
                                               float* __restrict__ Bm1) {
  int idx4 = blockIdx.x * 256 + threadIdx.x;
  if (idx4 >= 864 * 288) return;
  int k = idx4 / 288; int n = (idx4 % 288) * 4;
  int ci = k / 9, r9 = k % 9, kh = r9 / 3, kw = r9 % 3;
  int bb = n / OHW, rem = n % OHW, oh = rem / OW, ow0 = rem % OW;
  int ih = 2 * oh + kh - 1;
  float4 v = {0.f, 0.f, 0.f, 0.f};
  if (ih >= 0 && ih < HH) {
    const float* base = xm + (bb * CIN + ci) * LL + ih * WW;
    int iw0 = 2 * ow0 + kw - 1;
    v.x = (iw0 >= 0) ? base[iw0] : 0.f;
    v.y = base[iw0 + 2];
    v.z = base[iw0 + 4];
    v.w = base[iw0 + 6];
  }
  *(float4*)&Bm1[k * NPX + n] = v;
}

// ---------------- K9: im2col (stride-1 3x3) over t3 --------------------------
__global__ __launch_bounds__(256) void k_pack2(const float* __restrict__ t3,
                                               float* __restrict__ Bm2) {
  int idx4 = blockIdx.x * 256 + threadIdx.x;
  if (idx4 >= 1728 * 288) return;
  int k = idx4 / 288; int n = (idx4 % 288) * 4;
  int ci = k / 9, r9 = k % 9, kh = r9 / 3, kw = r9 % 3;
  int bb = n / OHW, rem = n % OHW, oh = rem / OW, ow0 = rem % OW;
  int ih = oh + kh - 1;
  float4 v = {0.f, 0.f, 0.f, 0.f};
  if (ih >= 0 && ih < OH) {
    const float* base = t3 + (bb * COUT + ci) * OHW + ih * OW;
    int iw0 = ow0 + kw - 1;
    v.x = (iw0 >= 0) ? base[iw0] : 0.f;
    v.y = base[iw0 + 1];
    v.z = base[iw0 + 2];
    v.w = (iw0 + 3 < OW) ? base[iw0 + 3] : 0.f;
  }
  *(float4*)&Bm2[k * NPX + n] = v;
}

// ---------------- K10: tiled GEMM (64x64, 4x4 micro, split-K, NB stride) -----
template<int MT, int KCHUNK, int BROWMUL, int BROWADD, int NB, int EPI>
__global__ __launch_bounds__(256) void k_gemm(const float* __restrict__ At,
                                              const float* __restrict__ Bm,
                                              float* __restrict__ Cout,
                                              const float* __restrict__ bias,
                                              const float* __restrict__ bn_g,
                                              const float* __restrict__ bn_b,
                                              const float* __restrict__ bn_m,
                                              const float* __restrict__ bn_v,
                                              const float* __restrict__ prelu_a,
                                              int bnoff) {
  __shared__ float As[16][64];
  __shared__ float Bs[16][64];
  int n0 = blockIdx.x * 64;
  int m0 = blockIdx.y * 64;
  int kz = blockIdx.z;
  int k0 = kz * KCHUNK;
  int tid = threadIdx.x;
  int lr = tid >> 4;
  int lc = (tid & 15) * 4;
  int tm = tid >> 4;
  int tn = tid & 15;
  float acc[4][4] = {};
  for (int ks = 0; ks < KCHUNK; ks += 16) {
    int kg = k0 + ks + lr;
    *(float4*)&As[lr][lc] = *(const float4*)&At[kg * MT + m0 + lc];
    *(float4*)&Bs[lr][lc] = *(const float4*)&Bm[(size_t)(kg * BROWMUL + BROWADD) * NB + n0 + lc];
    __syncthreads();
#pragma unroll
    for (int kk = 0; kk < 16; kk++) {
      float4 a = *(float4*)&As[kk][tm * 4];
      float4 b = *(float4*)&Bs[kk][tn * 4];
      acc[0][0] += a.x * b.x; acc[0][1] += a.x * b.y; acc[0][2] += a.x * b.z; acc[0][3] += a.x * b.w;
      acc[1][0] += a.y * b.x; acc[1][1] += a.y * b.y; acc[1][2] += a.y * b.z; acc[1][3] += a.y * b.w;
      acc[2][0] += a.z * b.x; acc[2][1] += a.z * b.y; acc[2][2] += a.z * b.z; acc[2][3] += a.z * b.w;
      acc[3][0] += a.w * b.x; acc[3][1] += a.w * b.y; acc[3][2] += a.w * b.z; acc[3][3] += a.w * b.w;
    }
    __syncthreads();
  }
  if (EPI == 0) {
    float* cp = Cout + ((size_t)kz * MT + m0) * NB + n0;
#pragma unroll
    for (int i = 0; i < 4; i++) {
      float4 v = {acc[i][0], acc[i][1], acc[i][2], acc[i][3]};
      *(float4*)&cp[(size_t)(tm * 4 + i) * NB + tn * 4] = v;
    }
  } else {
    int n = n0 + tn * 4;
    int bb = n / OHW, o = n % OHW;
    float aslope = prelu_a[0];
#pragma unroll
    for (int i = 0; i < 4; i++) {
      int co = m0 + tm * 4 + i;
      int cc = bnoff + co;
      float scale = rsqrtf(bn_v[cc] + EPSF) * bn_g[cc];
      float shift = bn_b[cc] - bn_m[cc] * scale;
      float bv = bias[co];
      float4 v;
      v.x = (acc[i][0] + bv) * scale + shift;
      v.y = (acc[i][1] + bv) * scale + shift;
      v.z = (acc[i][2] + bv) * scale + shift;
      v.w = (acc[i][3] + bv) * scale + shift;
      v.x = v.x > 0.f ? v.x : aslope * v.x;
      v.y = v.y > 0.f ? v.y : aslope * v.y;
      v.z = v.z > 0.f ? v.z : aslope * v.z;
      v.w = v.w > 0.f ? v.w : aslope * v.w;
      *(float4*)&Cout[((size_t)bb * 576 + cc) * OHW + o] = v;
    }
  }
}

// ---------------- K10F: per-batch GEMM with fused epilogues ------------------
// EPI 2: in_proj + LN-fold -> xin rows <192, z rows >=192
// EPI 3: out_proj + residual -> xm (rows <96 valid)
template<int MT, int KD, int EPI>
__global__ __launch_bounds__(256) void k_gemmF(const float* __restrict__ At,
                                               const float* __restrict__ Bm,
                                               int ldb, int boffB,
                                               float* __restrict__ C0,
                                               int ldc, int boffC,
                                               const float* __restrict__ a0,
                                               const float* __restrict__ a1,
                                               const float* __restrict__ a2,
                                               float* __restrict__ a3) {
  __shared__ float As[16][64];
  __shared__ float Bs[16][64];
  int n0 = blockIdx.x * 64;
  int m0 = blockIdx.y * 64;
  int bb = blockIdx.z;
  const float* B = Bm + (size_t)bb * boffB;
  int tid = threadIdx.x;
  int lr = tid >> 4;
  int lc = (tid & 15) * 4;
  int tm = tid >> 4;
  int tn = tid & 15;
  float acc[4][4] = {};
  for (int ks = 0; ks < KD; ks += 16) {
    *(float4*)&As[lr][lc] = *(const float4*)&At[(ks + lr) * MT + m0 + lc];
    *(float4*)&Bs[lr][lc] = *(const float4*)&B[(size_t)(ks + lr) * ldb + n0 + lc];
    __syncthreads();
#pragma unroll
    for (int kk = 0; kk < 16; kk++) {
      float4 a = *(float4*)&As[kk][tm * 4];
      float4 b = *(float4*)&Bs[kk][tn * 4];
      acc[0][0] += a.x * b.x; acc[0][1] += a.x * b.y; acc[0][2] += a.x * b.z; acc[0][3] += a.x * b.w;
      acc[1][0] += a.y * b.x; acc[1][1] += a.y * b.y; acc[1][2] += a.y * b.z; acc[1][3] += a.y * b.w;
      acc[2][0] += a.z * b.x; acc[2][1] += a.z * b.y; acc[2][2] += a.z * b.z; acc[2][3] += a.z * b.w;
      acc[3][0] += a.w * b.x; acc[3][1] += a.w * b.y; acc[3][2] += a.w * b.z; acc[3][3] += a.w * b.w;
    }
    __syncthreads();
  }
  int n = n0 + tn * 4;
  if (EPI == 2) {
    float m_[4], r_[4];
#pragma unroll
    for (int j = 0; j < 4; j++) {
      m_[j] = a0[((size_t)bb * LL + n + j) * 2];
      r_[j] = a0[((size_t)bb * LL + n + j) * 2 + 1];
    }
#pragma unroll
    for (int i = 0; i < 4; i++) {
      int e = m0 + tm * 4 + i;
      float swg = a1[e], swb = a2[e];
      float v0 = r_[0] * (acc[i][0] - m_[0] * swg) + swb;
      float v1 = r_[1] * (acc[i][1] - m_[1] * swg) + swb;
      float v2 = r_[2] * (acc[i][2] - m_[2] * swg) + swb;
      float v3 = r_[3] * (acc[i][3] - m_[3] * swg) + swb;
      if (e < DD) {
        float4 v = {v0, v1, v2, v3};
        *(float4*)&C0[(size_t)bb * boffC + (size_t)e * ldc + n] = v;
      } else {
        a3[((size_t)bb * LL + n + 0) * DD + (e - DD)] = v0;
        a3[((size_t)bb * LL + n + 1) * DD + (e - DD)] = v1;
        a3[((size_t)bb * LL + n + 2) * DD + (e - DD)] = v2;
        a3[((size_t)bb * LL + n + 3) * DD + (e - DD)] = v3;
      }
    }
  } else {
#pragma unroll
    for (int i = 0; i < 4; i++) {
      int e = m0 + tm * 4 + i;
      if (e < CIN) {
        size_t off = (size_t)bb * boffC + (size_t)e * ldc + n;
        float4 xr = *(const float4*)&a0[off];
        float4 v = {acc[i][0] + xr.x, acc[i][1] + xr.y, acc[i][2] + xr.z, acc[i][3] + xr.w};
        *(float4*)&C0[off] = v;
      }
    }
  }
}

// ---------------- K11: reduce split-K (w31 -> out x2 w/ BN; w32 -> t3) -------
__global__ __launch_bounds__(256) void k_reduce1(const float* __restrict__ Cp1,
                                                 const float* __restrict__ b31,
                                                 const float* __restrict__ b32,
                                                 const float* __restrict__ bn_g,
                                                 const float* __restrict__ bn_b,
                                                 const float* __restrict__ bn_m,
                                                 const float* __restrict__ bn_v,
                                                 const float* __restrict__ prelu_a,
                                                 float* __restrict__ out,
                                                 float* __restrict__ t3) {
  int idx = blockIdx.x * 256 + threadIdx.x;
  if (idx >= 384 * NPX) return;
  int m = idx / NPX, n = idx % NPX;
  float s = 0.f;
#pragma unroll
  for (int c = 0; c < 6; c++) s += Cp1[(size_t)c * 384 * NPX + idx];
  int bb = n / OHW, o = n % OHW;
  if (m < 192) {
    s += b31[m];
    int cc = 192 + m;
    float scale = rsqrtf(bn_v[cc] + EPSF) * bn_g[cc];
    float v = s * scale + (bn_b[cc] - bn_m[cc] * scale);
    float a = prelu_a[0];
    out[((size_t)bb * 576 + cc) * OHW + o] = v > 0.f ? v : a * v;
  } else {
    s += b32[m - 192];
    t3[((size_t)bb * COUT + (m - 192)) * OHW + o] = s;
  }
}

// ---------------- K12: reduce split-K for w33 -> out x3 w/ BN ----------------
__global__ __launch_bounds__(256) void k_reduce2(const float* __restrict__ Cp2,
                                                 const float* __restrict__ b33,
                                                 const float* __restrict__ bn_g,
                                                 const float* __restrict__ bn_b,
                                                 const float* __restrict__ bn_m,
                                                 const float* __restrict__ bn_v,
                                                 const float* __restrict__ prelu_a,
                                                 float* __restrict__ out) {
  int idx = blockIdx.x * 256 + threadIdx.x;
  if (idx >= 192 * NPX) return;
  int m = idx / NPX, n = idx % NPX;
  float s = b33[m];
#pragma unroll
  for (int c = 0; c < 9; c++) s += Cp2[(size_t)c * 192 * NPX + idx];
  int bb = n / OHW, o = n % OHW;
  int cc = 384 + m;
  float scale = rsqrtf(bn_v[cc] + EPSF) * bn_g[cc];
  float v = s * scale + (bn_b[cc] - bn_m[cc] * scale);
  float a = prelu_a[0];
  out[((size_t)bb * 576 + cc) * OHW + o] = v > 0.f ? v : a * v;
}

extern "C" void kernel_launch(void* const* d_in, const int* in_sizes, int n_in,
                              void* d_out, int out_size, void* d_ws, size_t ws_size,
                              hipStream_t stream) {
  const float* x        = (const float*)d_in[0];
  const float* ln_g     = (const float*)d_in[1];
  const float* ln_b     = (const float*)d_in[2];
  const float* in_proj_w= (const float*)d_in[3];
  const float* dwconv_w = (const float*)d_in[4];
  const float* dwconv_b = (const float*)d_in[5];
  const float* x_proj_w = (const float*)d_in[6];
  const float* dt_w     = (const float*)d_in[7];
  const float* dt_b     = (const float*)d_in[8];
  const float* A_logs   = (const float*)d_in[9];
  const float* Ds       = (const float*)d_in[10];
  const float* out_norm_g = (const float*)d_in[11];
  const float* out_norm_b = (const float*)d_in[12];
  const float* out_proj_w = (const float*)d_in[13];
  const float* w1  = (const float*)d_in[14];
  const float* b1  = (const float*)d_in[15];
  const float* w31 = (const float*)d_in[16];
  const float* b31 = (const float*)d_in[17];
  const float* w32 = (const float*)d_in[18];
  const float* b32 = (const float*)d_in[19];
  const float* w33 = (const float*)d_in[20];
  const float* b33 = (const float*)d_in[21];
  const float* bn_g = (const float*)d_in[22];
  const float* bn_b = (const float*)d_in[23];
  const float* bn_m = (const float*)d_in[24];
  const float* bn_v = (const float*)d_in[25];
  const float* prelu_a = (const float*)d_in[26];

  float* ws = (float*)d_ws;
  // region 0: C1 (gemm1->dtsplit) / Hinit (scan2->scan3) / ya (combine->outproj)
  float* C1    = ws;                    // 884736
  float* Hinit = ws;                    // 786432
  float* ya    = ws;                    // 884736
  // region 1: xin (inproj->dwconv); later xm + t3
  float* xin   = ws + 884736;           // 884736
  float* xm    = xin;                   // 442368
  float* t3    = xin + 442368;          // 221184
  // region 2: z (inproj->combine); later conv weight/pack pool
  float* z     = ws + 1769472;          // 884736
  // region 3: xs (dwconv->scan3)
  float* xs    = ws + 2654208;          // 3538944
  // region 4: xsl (dwconv->gemm1), then delta (dtsplit->scan3)
  float* xsl   = ws + 6193152;          // 884736
  float* delta = ws + 6193152;          // 3538944
  // region 5: ys (scan3->combine); Pbuf/Sbuf union (scan1->scan2)
  float* ys    = ws + 9732096;          // 3538944
  float* Pbuf  = ys;                    // 786432
  float* Sbuf  = ys + 786432;           // 786432
  // region 6: At3 (prep->gemm1), then Bsb/Csb (dtsplit->scan3)
  float* At3   = ws + 13271040;         // 36864
  float* Bsb   = ws + 13271040;         // 294912
  float* Csb   = ws + 13565952;         // 294912
  // region 7: small persistents
  float* WgT   = ws + 14450688;         // 36864
  float* sWg   = ws + 14487552;         // 384
  float* sWb   = ws + 14487936;         // 384
  float* stats = ws + 14488320;         // 9216
  // conv pool (in dead region 2+, after combine)
  float* At1   = ws + 1769472;          // 331776
  float* At2   = ws + 2101248;          // 331776
  float* w1t   = ws + 2433024;          // 18432
  float* woutT = ws + 2451456;          // 24576
  float* Bm1   = ws + 2476032;          // 995328
  float* Bm2   = ws + 3471360;          // 1990656
  float* Cp1   = ws + 5462016;          // 2654208
  float* Cp2   = ws + 8116224;          // 1990656
  float* out = (float*)d_out;

  k_prep<<<217, 256, 0, stream>>>(x, ln_g, ln_b, in_proj_w, x_proj_w,
                                  stats, WgT, sWg, sWb, At3);
  // in_proj GEMM + LN fold: M=384, K=96, per-batch
  k_gemmF<384, 96, 2><<<dim3(36, 6, 2), 256, 0, stream>>>(
      WgT, x, LL, CIN * LL, xin, LL, DD * LL, stats, sWg, sWb, z);
  k_dwconv<<<144, 256, 0, stream>>>(xin, dwconv_w, dwconv_b, xs, xsl);
  // x_proj (all 4 dirs fused): C1[192][4608] = At3^T . xsl
  k_gemm<192, 192, 1, 0, NTOT, 0><<<dim3(72, 3, 1), 256, 0, stream>>>(
      At3, xsl, C1, nullptr, nullptr, nullptr, nullptr, nullptr, nullptr, 0);
  k_dtsplit<<<576, 256, 0, stream>>>(C1, dt_w, dt_b, Bsb, Csb, delta);
  k_scan1<<<256, 192, 0, stream>>>(delta, xs, Bsb, A_logs, Pbuf, Sbuf);
  k_scan2<<<96, 256, 0, stream>>>(Pbuf, Sbuf, Hinit);
  k_scan3<<<256, 192, 0, stream>>>(delta, xs, Bsb, Csb, A_logs, Ds, Hinit, ys);
  k_combine<<<72, 256, 0, stream>>>(ys, z, out_norm_g, out_norm_b, ya);
  k_prepw<<<2760, 256, 0, stream>>>(w31, w32, w33, w1, out_proj_w,
                                    At1, At2, w1t, woutT);
  // out_proj GEMM + residual: M=128(pad of 96), K=192, per-batch
  k_gemmF<128, 192, 3><<<dim3(36, 2, 2), 256, 0, stream>>>(
      woutT, ya, LL, DD * LL, xm, LL, CIN * LL, x, nullptr, nullptr, nullptr);
  k_pack1<<<972, 256, 0, stream>>>(xm, Bm1);
  k_gemm<384, 144, 1, 0, NPX, 0><<<dim3(18, 6, 6), 256, 0, stream>>>(
      At1, Bm1, Cp1, nullptr, nullptr, nullptr, nullptr, nullptr, nullptr, 0);
  k_gemm<192, 96, 9, 4, NPX, 1><<<dim3(18, 3, 1), 256, 0, stream>>>(
      w1t, Bm1, out, b1, bn_g, bn_b, bn_m, bn_v, prelu_a, 0);
  k_reduce1<<<1728, 256, 0, stream>>>(Cp1, b31, b32, bn_g, bn_b, bn_m, bn_v,
                                      prelu_a, out, t3);
  k_pack2<<<1944, 256, 0, stream>>>(t3, Bm2);
  k_gemm<192, 192, 1, 0, NPX, 0><<<dim3(18, 3, 9), 256, 0, stream>>>(
      At2, Bm2, Cp2, nullptr, nullptr, nullptr, nullptr, nullptr, nullptr, 0);
  k_reduce2<<<864, 256, 0, stream>>>(Cp2, b33, bn_g, bn_b, bn_m, bn_v, prelu_a, out);
}

// Round 6
// 226.877 us; speedup vs baseline: 5.3929x; 1.2146x over previous
//
#include <hip/hip_runtime.h>
#include <math.h>

#define BB_ 2
#define HH 48
#define WW 48
#define LL 2304
#define CIN 96
#define DD 192
#define KK 4
#define NN 16
#define RR 6
#define NCH 64
#define LC 36
#define COUT 192
#define OH 24
#define OW 24
#define OHW 576
#define NPX 1152
#define NTOT 4608
#define EPSF 1e-5f

// ---------------- K1: LN stats + folded weight prep + At3 (xpw^T) ------------
__global__ __launch_bounds__(256) void k_prep(const float* __restrict__ x,
                                              const float* __restrict__ g,
                                              const float* __restrict__ b,
                                              const float* __restrict__ inw,
                                              const float* __restrict__ xpw,
                                              float* __restrict__ stats,
                                              float* __restrict__ WgT,
                                              float* __restrict__ sWg,
                                              float* __restrict__ sWb,
                                              float* __restrict__ At3) {
  int bx = blockIdx.x;
  if (bx < 72) {
    int bb = bx / 36; int l0 = (bx % 36) * 64;
    int p = threadIdx.x >> 2, q = threadIdx.x & 3;
    int l = l0 + p;
    const float* xp = x + bb * CIN * LL + l;
    float s = 0.f, ss = 0.f;
    for (int c = q; c < CIN; c += 4) { float v = xp[c * LL]; s += v; ss += v * v; }
    s += __shfl_xor(s, 1, 64); s += __shfl_xor(s, 2, 64);
    ss += __shfl_xor(ss, 1, 64); ss += __shfl_xor(ss, 2, 64);
    if (q == 0) {
      float m = s / CIN; float var = ss / CIN - m * m;
      stats[(bb * LL + l) * 2 + 0] = m;
      stats[(bb * LL + l) * 2 + 1] = rsqrtf(var + EPSF);
    }
  } else if (bx == 72) {
    for (int e = threadIdx.x; e < 2 * DD; e += 256) {
      float swg = 0.f, swb = 0.f;
      for (int c = 0; c < CIN; c++) {
        float w = inw[e * CIN + c];
        float wg = w * g[c];
        WgT[c * 384 + e] = wg;
        swg += wg; swb += w * b[c];
      }
      sWg[e] = swg; sWb[e] = swb;
    }
  } else {
    int idx = (bx - 73) * 256 + threadIdx.x;   // 0..36863 : At3[d*192+m]
    if (idx < 192 * 192) {
      int m = idx % 192;
      int d = idx / 192;
      At3[idx] = (m < 152) ? xpw[m * 192 + d] : 0.f;
    }
  }
}

// ---------------- K3: depthwise 3x3 + silu -> xs t-major ×4 + xsl l-major ----
// block = (bb, dgroup of 48, 32-pixel tile) -> grid 576, 9 waves/CU
__global__ __launch_bounds__(256) void k_dwconv(const float* __restrict__ xin,
                                                const float* __restrict__ wdw,
                                                const float* __restrict__ bdw,
                                                float* __restrict__ xs,
                                                float* __restrict__ xsl) {
  __shared__ float vt[32 * 50];
  int bid = blockIdx.x;                 // bb*288 + dg*72 + tile
  int bb = bid / 288; int r = bid % 288; int dg = r / 72; int tile = r % 72;
  int l0 = tile * 32;
  int d0 = dg * 48;
  for (int i = threadIdx.x; i < 32 * 48; i += 256) {
    int lj = i & 31, dl = i >> 5;
    int d = d0 + dl;
    int l = l0 + lj;
    int h = l / WW, w = l % WW;
    const float* xp = xin + (bb * DD + d) * LL;
    const float* wq = wdw + d * 9;
    float acc = bdw[d];
#pragma unroll
    for (int kh = 0; kh < 3; kh++) {
      int ih = h + kh - 1; if (ih < 0 || ih >= HH) continue;
#pragma unroll
      for (int kw = 0; kw < 3; kw++) {
        int iw = w + kw - 1; if (iw < 0 || iw >= WW) continue;
        acc += xp[ih * WW + iw] * wq[kh * 3 + kw];
      }
    }
    float v = acc / (1.f + __expf(-acc));
    vt[lj * 50 + dl] = v;
    xsl[(size_t)d * NTOT + bb * LL + l] = v;
  }
  __syncthreads();
  for (int j = threadIdx.x; j < 32 * 48; j += 256) {
    int lj = j / 48, dl = j - lj * 48;
    int d = d0 + dl;
    int l = l0 + lj;
    int h = l / WW, w = l % WW;
    int lt = w * HH + h;
    float v = vt[lj * 50 + dl];
    xs[(((size_t)bb * KK + 0) * LL + l) * DD + d] = v;
    xs[(((size_t)bb * KK + 1) * LL + lt) * DD + d] = v;
    xs[(((size_t)bb * KK + 2) * LL + (LL - 1 - l)) * DD + d] = v;
    xs[(((size_t)bb * KK + 3) * LL + (LL - 1 - lt)) * DD + d] = v;
  }
}

// ---------------- K-dtsplit: dts -> delta (softplus) + Bsb/Csb, permuted -----
__global__ __launch_bounds__(256) void k_dtsplit(const float* __restrict__ C1,
                                                 const float* __restrict__ dtw,
                                                 const float* __restrict__ dtb,
                                                 float* __restrict__ Bsb,
                                                 float* __restrict__ Csb,
                                                 float* __restrict__ delta) {
  __shared__ float lds[38 * 33];
  int bid = blockIdx.x;                  // bk*72 + tile
  int tile = bid % 72; int bk = bid / 72; int bb = bk >> 2; int k = bk & 3;
  int l0 = tile * 32;
  int tid = threadIdx.x;
  for (int i = tid; i < 38 * 32; i += 256) {
    int r = i >> 5, lj = i & 31;
    lds[r * 33 + lj] = C1[(size_t)(k * 38 + r) * NTOT + bb * LL + l0 + lj];
  }
  __syncthreads();
  for (int i = tid; i < 32 * 16; i += 256) {
    int lj = i >> 4, n = i & 15;
    int l = l0 + lj; int h = l / WW, w = l % WW; int lt = w * HH + h;
    int pos = (k == 0) ? l : (k == 1) ? lt : (k == 2) ? (LL - 1 - l) : (LL - 1 - lt);
    size_t base = ((size_t)bk * LL + pos) * NN + n;
    Bsb[base] = lds[(6 + n) * 33 + lj];
    Csb[base] = lds[(22 + n) * 33 + lj];
  }
  for (int i = tid; i < 32 * 192; i += 256) {
    int lj = i / 192, d = i - lj * 192;
    int l = l0 + lj; int h = l / WW, w = l % WW; int lt = w * HH + h;
    int pos = (k == 0) ? l : (k == 1) ? lt : (k == 2) ? (LL - 1 - l) : (LL - 1 - lt);
    const float* wd = dtw + (k * DD + d) * RR;
    float acc = dtb[k * DD + d];
#pragma unroll
    for (int r = 0; r < RR; r++) acc += wd[r] * lds[r * 33 + lj];
    float sp = acc > 20.f ? acc : log1pf(__expf(acc));
    delta[((size_t)bk * LL + pos) * DD + d] = sp;
  }
}

// ---------------- K5a: chunked scan pass 1 — lane-owns-d, h[16] in VGPR ------
__global__ __launch_bounds__(192) void k_scan1(const float* __restrict__ delta,
                                               const float* __restrict__ xs,
                                               const float* __restrict__ Bsb,
                                               const float* __restrict__ A_logs,
                                               float* __restrict__ Pbuf,
                                               float* __restrict__ Sbuf) {
  __shared__ float Bls[LC * NN];
  int bid = blockIdx.x;
  int c = bid & (NCH - 1); int bk = bid >> 6; int k = bk & 3;
  int t0 = c * LC;
  int d = threadIdx.x;
  const float* bp = Bsb + ((size_t)bk * LL + t0) * NN;
  for (int i = d; i < LC * NN; i += 192) Bls[i] = bp[i];
  float A[NN];
  {
    const float4* ap = (const float4*)(A_logs + (k * DD + d) * NN);
#pragma unroll
    for (int j = 0; j < 4; j++) {
      float4 a4 = ap[j];
      A[4 * j + 0] = -__expf(a4.x); A[4 * j + 1] = -__expf(a4.y);
      A[4 * j + 2] = -__expf(a4.z); A[4 * j + 3] = -__expf(a4.w);
    }
  }
  float h[NN];
#pragma unroll
  for (int n = 0; n < NN; n++) h[n] = 0.f;
  float sd = 0.f;
  __syncthreads();
  const float* dp = delta + ((size_t)bk * LL + t0) * DD + d;
  const float* xp = xs + ((size_t)bk * LL + t0) * DD + d;
#pragma unroll 2
  for (int t = 0; t < LC; ++t) {
    float dt = dp[t * DD];
    float xv = xp[t * DD];
    float u = dt * xv;
    sd += dt;
    const float4* b4 = (const float4*)&Bls[t * NN];
#pragma unroll
    for (int j = 0; j < 4; j++) {
      float4 b = b4[j];
      h[4 * j + 0] = __expf(dt * A[4 * j + 0]) * h[4 * j + 0] + u * b.x;
      h[4 * j + 1] = __expf(dt * A[4 * j + 1]) * h[4 * j + 1] + u * b.y;
      h[4 * j + 2] = __expf(dt * A[4 * j + 2]) * h[4 * j + 2] + u * b.z;
      h[4 * j + 3] = __expf(dt * A[4 * j + 3]) * h[4 * j + 3] + u * b.w;
    }
  }
  int chn = (bk * DD + d) * NN;
  float* pp = Pbuf + (size_t)c * 24576 + chn;
  float* sp = Sbuf + (size_t)c * 24576 + chn;
#pragma unroll
  for (int n = 0; n < NN; n++) { pp[n] = __expf(A[n] * sd); sp[n] = h[n]; }
}

// ---------------- K5b: combine chunks ----------------------------------------
__global__ __launch_bounds__(256) void k_scan2(const float* __restrict__ Pbuf,
                                               const float* __restrict__ Sbuf,
                                               float* __restrict__ Hinit) {
  int idx = blockIdx.x * 256 + threadIdx.x;
  float h = 0.f;
  for (int c = 0; c < NCH; c++) {
    Hinit[(size_t)c * 24576 + idx] = h;
    h = Pbuf[(size_t)c * 24576 + idx] * h + Sbuf[(size_t)c * 24576 + idx];
  }
}

// ---------------- K5c: replay + emit ys — lane-owns-d, no shuffles -----------
__global__ __launch_bounds__(192) void k_scan3(const float* __restrict__ delta,
                                               const float* __restrict__ xs,
                                               const float* __restrict__ Bsb,
                                               const float* __restrict__ Csb,
                                               const float* __restrict__ A_logs,
                                               const float* __restrict__ Ds,
                                               const float* __restrict__ Hinit,
                                               float* __restrict__ ys) {
  __shared__ float Bls[LC * NN];
  __shared__ float Cls[LC * NN];
  int bid = blockIdx.x;
  int c = bid & (NCH - 1); int bk = bid >> 6; int k = bk & 3;
  int t0 = c * LC;
  int d = threadIdx.x;
  const float* bp = Bsb + ((size_t)bk * LL + t0) * NN;
  const float* cp = Csb + ((size_t)bk * LL + t0) * NN;
  for (int i = d; i < LC * NN; i += 192) { Bls[i] = bp[i]; Cls[i] = cp[i]; }
  float A[NN];
  {
    const float4* ap = (const float4*)(A_logs + (k * DD + d) * NN);
#pragma unroll
    for (int j = 0; j < 4; j++) {
      float4 a4 = ap[j];
      A[4 * j + 0] = -__expf(a4.x); A[4 * j + 1] = -__expf(a4.y);
      A[4 * j + 2] = -__expf(a4.z); A[4 * j + 3] = -__expf(a4.w);
    }
  }
  float Dv = Ds[k * DD + d];
  float h[NN];
  {
    const float4* hp = (const float4*)(Hinit + (size_t)c * 24576 + (bk * DD + d) * NN);
#pragma unroll
    for (int j = 0; j < 4; j++) {
      float4 h4 = hp[j];
      h[4 * j + 0] = h4.x; h[4 * j + 1] = h4.y;
      h[4 * j + 2] = h4.z; h[4 * j + 3] = h4.w;
    }
  }
  __syncthreads();
  const float* dp = delta + ((size_t)bk * LL + t0) * DD + d;
  const float* xp = xs + ((size_t)bk * LL + t0) * DD + d;
  float* yp = ys + ((size_t)bk * LL + t0) * DD + d;
#pragma unroll 2
  for (int t = 0; t < LC; ++t) {
    float dt = dp[t * DD];
    float xv = xp[t * DD];
    float u = dt * xv;
    float y = 0.f;
    const float4* b4 = (const float4*)&Bls[t * NN];
    const float4* c4 = (const float4*)&Cls[t * NN];
#pragma unroll
    for (int j = 0; j < 4; j++) {
      float4 b = b4[j];
      float4 cc = c4[j];
      h[4 * j + 0] = __expf(dt * A[4 * j + 0]) * h[4 * j + 0] + u * b.x;
      h[4 * j + 1] = __expf(dt * A[4 * j + 1]) * h[4 * j + 1] + u * b.y;
      h[4 * j + 2] = __expf(dt * A[4 * j + 2]) * h[4 * j + 2] + u * b.z;
      h[4 * j + 3] = __expf(dt * A[4 * j + 3]) * h[4 * j + 3] + u * b.w;
      y += h[4 * j + 0] * cc.x + h[4 * j + 1] * cc.y
         + h[4 * j + 2] * cc.z + h[4 * j + 3] * cc.w;
    }
    yp[t * DD] = y + Dv * xv;
  }
}

// ---------------- K6a: gather 4 dirs + out_norm LN + silu(z) -----------------
__global__ __launch_bounds__(256) void k_combine(const float* __restrict__ ys,
                                                 const float* __restrict__ z,
                                                 const float* __restrict__ ong,
                                                 const float* __restrict__ onb,
                                                 float* __restrict__ ya) {
  __shared__ float yt[64 * 201];
  int bx = blockIdx.x; int bb = bx / 36; int l0 = (bx % 36) * 64;
  int tid = threadIdx.x;
  for (int i = tid; i < 64 * DD; i += 256) {
    int p = i / DD, d = i - p * DD;
    int l = l0 + p; int h = l / WW, w = l - h * WW;
    int t1 = w * HH + h;
    float v = ys[(((size_t)bb * KK + 0) * LL + l) * DD + d]
            + ys[(((size_t)bb * KK + 1) * LL + t1) * DD + d]
            + ys[(((size_t)bb * KK + 2) * LL + (LL - 1 - l)) * DD + d]
            + ys[(((size_t)bb * KK + 3) * LL + (LL - 1 - t1)) * DD + d];
    yt[p * 201 + d] = v;
  }
  __syncthreads();
  int p = tid >> 2, q = tid & 3;
  int l = l0 + p;
  float s = 0.f, ss = 0.f;
  for (int d = q * 48; d < q * 48 + 48; d++) { float v = yt[p * 201 + d]; s += v; ss += v * v; }
  s += __shfl_xor(s, 1, 64); s += __shfl_xor(s, 2, 64);
  ss += __shfl_xor(ss, 1, 64); ss += __shfl_xor(ss, 2, 64);
  float m = s / DD, var = ss / DD - m * m;
  float rr = rsqrtf(var + EPSF);
  const float* zp = z + (bb * LL + l) * DD;
  for (int d = q * 48; d < q * 48 + 48; d++) {
    float v = (yt[p * 201 + d] - m) * rr * ong[d] + onb[d];
    float zv = zp[d];
    yt[p * 201 + d] = v * zv / (1.f + __expf(-zv));
  }
  __syncthreads();
  for (int i = tid; i < 64 * DD; i += 256) {
    int d = i >> 6, p2 = i & 63;
    ya[(bb * DD + d) * LL + l0 + p2] = yt[p2 * 201 + d];
  }
}

// ---------------- K7: weight transpose/concat --------------------------------
__global__ __launch_bounds__(256) void k_prepw(const float* __restrict__ w31,
                                               const float* __restrict__ w32,
                                               const float* __restrict__ w33,
                                               const float* __restrict__ w1,
                                               const float* __restrict__ wout,
                                               float* __restrict__ At1,
                                               float* __restrict__ At2,
                                               float* __restrict__ w1t,
                                               float* __restrict__ woutT) {
  int idx = blockIdx.x * 256 + threadIdx.x;
  if (idx < 331776) {
    int k = idx / 384, m = idx % 384;
    At1[idx] = (m < 192) ? w31[m * 864 + k] : w32[(m - 192) * 864 + k];
  } else if (idx < 663552) {
    int i = idx - 331776; int k = i / 192, m = i % 192;
    At2[i] = w33[m * 1728 + k];
  } else if (idx < 681984) {
    int i = idx - 663552; int k = i / 192, m = i % 192;
    w1t[i] = w1[m * 96 + k];
  } else if (idx < 706560) {
    int i = idx - 681984; int d = i / 128, e = i % 128;
    woutT[i] = (e < 96) ? wout[e * 192 + d] : 0.f;
  }
}

// ---------------- K8: im2col (stride-2 3x3) over xm --------------------------
__global__ __launch_bounds__(256) void k_pack1(const float* __restrict__ xm,
                                               float* __restrict__ Bm1) {
  int idx4 = blockIdx.x * 256 + threadIdx.x;
  if (idx4 >= 864 * 288) return;
  int k = idx4 / 288; int n = (idx4 % 288) * 4;
  int ci = k / 9, r9 = k % 9, kh = r9 / 3, kw = r9 % 3;
  int bb = n / OHW, rem = n % OHW, oh = rem / OW, ow0 = rem % OW;
  int ih = 2 * oh + kh - 1;
  float4 v = {0.f, 0.f, 0.f, 0.f};
  if (ih >= 0 && ih < HH) {
    const float* base = xm + (bb * CIN + ci) * LL + ih * WW;
    int iw0 = 2 * ow0 + kw - 1;
    v.x = (iw0 >= 0) ? base[iw0] : 0.f;
    v.y = base[iw0 + 2];
    v.z = base[iw0 + 4];
    v.w = base[iw0 + 6];
  }
  *(float4*)&Bm1[k * NPX + n] = v;
}

// ---------------- K9: im2col (stride-1 3x3) over t3 --------------------------
__global__ __launch_bounds__(256) void k_pack2(const float* __restrict__ t3,
                                               float* __restrict__ Bm2) {
  int idx4 = blockIdx.x * 256 + threadIdx.x;
  if (idx4 >= 1728 * 288) return;
  int k = idx4 / 288; int n = (idx4 % 288) * 4;
  int ci = k / 9, r9 = k % 9, kh = r9 / 3, kw = r9 % 3;
  int bb = n / OHW, rem = n % OHW, oh = rem / OW, ow0 = rem % OW;
  int ih = oh + kh - 1;
  float4 v = {0.f, 0.f, 0.f, 0.f};
  if (ih >= 0 && ih < OH) {
    const float* base = t3 + (bb * COUT + ci) * OHW + ih * OW;
    int iw0 = ow0 + kw - 1;
    v.x = (iw0 >= 0) ? base[iw0] : 0.f;
    v.y = base[iw0 + 1];
    v.z = base[iw0 + 2];
    v.w = (iw0 + 3 < OW) ? base[iw0 + 3] : 0.f;
  }
  *(float4*)&Bm2[k * NPX + n] = v;
}

// ---------------- K10: tiled GEMM (64x64, 4x4 micro, split-K, NB stride) -----
template<int MT, int KCHUNK, int BROWMUL, int BROWADD, int NB, int EPI>
__global__ __launch_bounds__(256) void k_gemm(const float* __restrict__ At,
                                              const float* __restrict__ Bm,
                                              float* __restrict__ Cout,
                                              const float* __restrict__ bias,
                                              const float* __restrict__ bn_g,
                                              const float* __restrict__ bn_b,
                                              const float* __restrict__ bn_m,
                                              const float* __restrict__ bn_v,
                                              const float* __restrict__ prelu_a,
                                              int bnoff) {
  __shared__ float As[16][64];
  __shared__ float Bs[16][64];
  int n0 = blockIdx.x * 64;
  int m0 = blockIdx.y * 64;
  int kz = blockIdx.z;
  int k0 = kz * KCHUNK;
  int tid = threadIdx.x;
  int lr = tid >> 4;
  int lc = (tid & 15) * 4;
  int tm = tid >> 4;
  int tn = tid & 15;
  float acc[4][4] = {};
  for (int ks = 0; ks < KCHUNK; ks += 16) {
    int kg = k0 + ks + lr;
    *(float4*)&As[lr][lc] = *(const float4*)&At[kg * MT + m0 + lc];
    *(float4*)&Bs[lr][lc] = *(const float4*)&Bm[(size_t)(kg * BROWMUL + BROWADD) * NB + n0 + lc];
    __syncthreads();
#pragma unroll
    for (int kk = 0; kk < 16; kk++) {
      float4 a = *(float4*)&As[kk][tm * 4];
      float4 b = *(float4*)&Bs[kk][tn * 4];
      acc[0][0] += a.x * b.x; acc[0][1] += a.x * b.y; acc[0][2] += a.x * b.z; acc[0][3] += a.x * b.w;
      acc[1][0] += a.y * b.x; acc[1][1] += a.y * b.y; acc[1][2] += a.y * b.z; acc[1][3] += a.y * b.w;
      acc[2][0] += a.z * b.x; acc[2][1] += a.z * b.y; acc[2][2] += a.z * b.z; acc[2][3] += a.z * b.w;
      acc[3][0] += a.w * b.x; acc[3][1] += a.w * b.y; acc[3][2] += a.w * b.z; acc[3][3] += a.w * b.w;
    }
    __syncthreads();
  }
  if (EPI == 0) {
    float* cp = Cout + ((size_t)kz * MT + m0) * NB + n0;
#pragma unroll
    for (int i = 0; i < 4; i++) {
      float4 v = {acc[i][0], acc[i][1], acc[i][2], acc[i][3]};
      *(float4*)&cp[(size_t)(tm * 4 + i) * NB + tn * 4] = v;
    }
  } else {
    int n = n0 + tn * 4;
    int bb = n / OHW, o = n % OHW;
    float aslope = prelu_a[0];
#pragma unroll
    for (int i = 0; i < 4; i++) {
      int co = m0 + tm * 4 + i;
      int cc = bnoff + co;
      float scale = rsqrtf(bn_v[cc] + EPSF) * bn_g[cc];
      float shift = bn_b[cc] - bn_m[cc] * scale;
      float bv = bias[co];
      float4 v;
      v.x = (acc[i][0] + bv) * scale + shift;
      v.y = (acc[i][1] + bv) * scale + shift;
      v.z = (acc[i][2] + bv) * scale + shift;
      v.w = (acc[i][3] + bv) * scale + shift;
      v.x = v.x > 0.f ? v.x : aslope * v.x;
      v.y = v.y > 0.f ? v.y : aslope * v.y;
      v.z = v.z > 0.f ? v.z : aslope * v.z;
      v.w = v.w > 0.f ? v.w : aslope * v.w;
      *(float4*)&Cout[((size_t)bb * 576 + cc) * OHW + o] = v;
    }
  }
}

// ---------------- K10F: per-batch GEMM with fused epilogues ------------------
template<int MT, int KD, int EPI>
__global__ __launch_bounds__(256) void k_gemmF(const float* __restrict__ At,
                                               const float* __restrict__ Bm,
                                               int ldb, int boffB,
                                               float* __restrict__ C0,
                                               int ldc, int boffC,
                                               const float* __restrict__ a0,
                                               const float* __restrict__ a1,
                                               const float* __restrict__ a2,
                                               float* __restrict__ a3) {
  __shared__ float As[16][64];
  __shared__ float Bs[16][64];
  int n0 = blockIdx.x * 64;
  int m0 = blockIdx.y * 64;
  int bb = blockIdx.z;
  const float* B = Bm + (size_t)bb * boffB;
  int tid = threadIdx.x;
  int lr = tid >> 4;
  int lc = (tid & 15) * 4;
  int tm = tid >> 4;
  int tn = tid & 15;
  float acc[4][4] = {};
  for (int ks = 0; ks < KD; ks += 16) {
    *(float4*)&As[lr][lc] = *(const float4*)&At[(ks + lr) * MT + m0 + lc];
    *(float4*)&Bs[lr][lc] = *(const float4*)&B[(size_t)(ks + lr) * ldb + n0 + lc];
    __syncthreads();
#pragma unroll
    for (int kk = 0; kk < 16; kk++) {
      float4 a = *(float4*)&As[kk][tm * 4];
      float4 b = *(float4*)&Bs[kk][tn * 4];
      acc[0][0] += a.x * b.x; acc[0][1] += a.x * b.y; acc[0][2] += a.x * b.z; acc[0][3] += a.x * b.w;
      acc[1][0] += a.y * b.x; acc[1][1] += a.y * b.y; acc[1][2] += a.y * b.z; acc[1][3] += a.y * b.w;
      acc[2][0] += a.z * b.x; acc[2][1] += a.z * b.y; acc[2][2] += a.z * b.z; acc[2][3] += a.z * b.w;
      acc[3][0] += a.w * b.x; acc[3][1] += a.w * b.y; acc[3][2] += a.w * b.z; acc[3][3] += a.w * b.w;
    }
    __syncthreads();
  }
  int n = n0 + tn * 4;
  if (EPI == 2) {
    float m_[4], r_[4];
#pragma unroll
    for (int j = 0; j < 4; j++) {
      m_[j] = a0[((size_t)bb * LL + n + j) * 2];
      r_[j] = a0[((size_t)bb * LL + n + j) * 2 + 1];
    }
#pragma unroll
    for (int i = 0; i < 4; i++) {
      int e = m0 + tm * 4 + i;
      float swg = a1[e], swb = a2[e];
      float v0 = r_[0] * (acc[i][0] - m_[0] * swg) + swb;
      float v1 = r_[1] * (acc[i][1] - m_[1] * swg) + swb;
      float v2 = r_[2] * (acc[i][2] - m_[2] * swg) + swb;
      float v3 = r_[3] * (acc[i][3] - m_[3] * swg) + swb;
      if (e < DD) {
        float4 v = {v0, v1, v2, v3};
        *(float4*)&C0[(size_t)bb * boffC + (size_t)e * ldc + n] = v;
      } else {
        a3[((size_t)bb * LL + n + 0) * DD + (e - DD)] = v0;
        a3[((size_t)bb * LL + n + 1) * DD + (e - DD)] = v1;
        a3[((size_t)bb * LL + n + 2) * DD + (e - DD)] = v2;
        a3[((size_t)bb * LL + n + 3) * DD + (e - DD)] = v3;
      }
    }
  } else {
#pragma unroll
    for (int i = 0; i < 4; i++) {
      int e = m0 + tm * 4 + i;
      if (e < CIN) {
        size_t off = (size_t)bb * boffC + (size_t)e * ldc + n;
        float4 xr = *(const float4*)&a0[off];
        float4 v = {acc[i][0] + xr.x, acc[i][1] + xr.y, acc[i][2] + xr.z, acc[i][3] + xr.w};
        *(float4*)&C0[off] = v;
      }
    }
  }
}

// ---------------- K11: reduce split-K (w31 -> out x2 w/ BN; w32 -> t3) -------
__global__ __launch_bounds__(256) void k_reduce1(const float* __restrict__ Cp1,
                                                 const float* __restrict__ b31,
                                                 const float* __restrict__ b32,
                                                 const float* __restrict__ bn_g,
                                                 const float* __restrict__ bn_b,
                                                 const float* __restrict__ bn_m,
                                                 const float* __restrict__ bn_v,
                                                 const float* __restrict__ prelu_a,
                                                 float* __restrict__ out,
                                                 float* __restrict__ t3) {
  int idx = blockIdx.x * 256 + threadIdx.x;
  if (idx >= 384 * NPX) return;
  int m = idx / NPX, n = idx % NPX;
  float s = 0.f;
#pragma unroll
  for (int c = 0; c < 6; c++) s += Cp1[(size_t)c * 384 * NPX + idx];
  int bb = n / OHW, o = n % OHW;
  if (m < 192) {
    s += b31[m];
    int cc = 192 + m;
    float scale = rsqrtf(bn_v[cc] + EPSF) * bn_g[cc];
    float v = s * scale + (bn_b[cc] - bn_m[cc] * scale);
    float a = prelu_a[0];
    out[((size_t)bb * 576 + cc) * OHW + o] = v > 0.f ? v : a * v;
  } else {
    s += b32[m - 192];
    t3[((size_t)bb * COUT + (m - 192)) * OHW + o] = s;
  }
}

// ---------------- K12: reduce split-K for w33 -> out x3 w/ BN ----------------
__global__ __launch_bounds__(256) void k_reduce2(const float* __restrict__ Cp2,
                                                 const float* __restrict__ b33,
                                                 const float* __restrict__ bn_g,
                                                 const float* __restrict__ bn_b,
                                                 const float* __restrict__ bn_m,
                                                 const float* __restrict__ bn_v,
                                                 const float* __restrict__ prelu_a,
                                                 float* __restrict__ out) {
  int idx = blockIdx.x * 256 + threadIdx.x;
  if (idx >= 192 * NPX) return;
  int m = idx / NPX, n = idx % NPX;
  float s = b33[m];
#pragma unroll
  for (int c = 0; c < 9; c++) s += Cp2[(size_t)c * 192 * NPX + idx];
  int bb = n / OHW, o = n % OHW;
  int cc = 384 + m;
  float scale = rsqrtf(bn_v[cc] + EPSF) * bn_g[cc];
  float v = s * scale + (bn_b[cc] - bn_m[cc] * scale);
  float a = prelu_a[0];
  out[((size_t)bb * 576 + cc) * OHW + o] = v > 0.f ? v : a * v;
}

extern "C" void kernel_launch(void* const* d_in, const int* in_sizes, int n_in,
                              void* d_out, int out_size, void* d_ws, size_t ws_size,
                              hipStream_t stream) {
  const float* x        = (const float*)d_in[0];
  const float* ln_g     = (const float*)d_in[1];
  const float* ln_b     = (const float*)d_in[2];
  const float* in_proj_w= (const float*)d_in[3];
  const float* dwconv_w = (const float*)d_in[4];
  const float* dwconv_b = (const float*)d_in[5];
  const float* x_proj_w = (const float*)d_in[6];
  const float* dt_w     = (const float*)d_in[7];
  const float* dt_b     = (const float*)d_in[8];
  const float* A_logs   = (const float*)d_in[9];
  const float* Ds       = (const float*)d_in[10];
  const float* out_norm_g = (const float*)d_in[11];
  const float* out_norm_b = (const float*)d_in[12];
  const float* out_proj_w = (const float*)d_in[13];
  const float* w1  = (const float*)d_in[14];
  const float* b1  = (const float*)d_in[15];
  const float* w31 = (const float*)d_in[16];
  const float* b31 = (const float*)d_in[17];
  const float* w32 = (const float*)d_in[18];
  const float* b32 = (const float*)d_in[19];
  const float* w33 = (const float*)d_in[20];
  const float* b33 = (const float*)d_in[21];
  const float* bn_g = (const float*)d_in[22];
  const float* bn_b = (const float*)d_in[23];
  const float* bn_m = (const float*)d_in[24];
  const float* bn_v = (const float*)d_in[25];
  const float* prelu_a = (const float*)d_in[26];

  float* ws = (float*)d_ws;
  // region 0+1 head: C1 (gemm1->dtsplit) / Hinit (scan2->scan3, 1572864 spans
  //   into dead xin) / ya (combine->outproj)
  float* C1    = ws;                    // 884736
  float* Hinit = ws;                    // 1572864 (xin dead after dwconv)
  float* ya    = ws;                    // 884736
  // region 1: xin (inproj->dwconv); later xm + t3
  float* xin   = ws + 884736;           // 884736
  float* xm    = xin;                   // 442368
  float* t3    = xin + 442368;          // 221184
  // region 2: z (inproj->combine); later conv weight/pack pool
  float* z     = ws + 1769472;          // 884736
  // region 3: xs (dwconv->scan3)
  float* xs    = ws + 2654208;          // 3538944
  // region 4: xsl (dwconv->gemm1), then delta (dtsplit->scan3)
  float* xsl   = ws + 6193152;          // 884736
  float* delta = ws + 6193152;          // 3538944
  // region 5: ys (scan3->combine); Pbuf/Sbuf union (scan1->scan2)
  float* ys    = ws + 9732096;          // 3538944
  float* Pbuf  = ys;                    // 1572864
  float* Sbuf  = ys + 1572864;          // 1572864
  // region 6: At3 (prep->gemm1), then Bsb/Csb (dtsplit->scan3)
  float* At3   = ws + 13271040;         // 36864
  float* Bsb   = ws + 13271040;         // 294912
  float* Csb   = ws + 13565952;         // 294912
  // region 7: small persistents
  float* WgT   = ws + 14450688;         // 36864
  float* sWg   = ws + 14487552;         // 384
  float* sWb   = ws + 14487936;         // 384
  float* stats = ws + 14488320;         // 9216
  // conv pool (in dead region 2+, after combine)
  float* At1   = ws + 1769472;          // 331776
  float* At2   = ws + 2101248;          // 331776
  float* w1t   = ws + 2433024;          // 18432
  float* woutT = ws + 2451456;          // 24576
  float* Bm1   = ws + 2476032;          // 995328
  float* Bm2   = ws + 3471360;          // 1990656
  float* Cp1   = ws + 5462016;          // 2654208
  float* Cp2   = ws + 8116224;          // 1990656
  float* out = (float*)d_out;

  k_prep<<<217, 256, 0, stream>>>(x, ln_g, ln_b, in_proj_w, x_proj_w,
                                  stats, WgT, sWg, sWb, At3);
  k_gemmF<384, 96, 2><<<dim3(36, 6, 2), 256, 0, stream>>>(
      WgT, x, LL, CIN * LL, xin, LL, DD * LL, stats, sWg, sWb, z);
  k_dwconv<<<576, 256, 0, stream>>>(xin, dwconv_w, dwconv_b, xs, xsl);
  k_gemm<192, 192, 1, 0, NTOT, 0><<<dim3(72, 3, 1), 256, 0, stream>>>(
      At3, xsl, C1, nullptr, nullptr, nullptr, nullptr, nullptr, nullptr, 0);
  k_dtsplit<<<576, 256, 0, stream>>>(C1, dt_w, dt_b, Bsb, Csb, delta);
  k_scan1<<<512, 192, 0, stream>>>(delta, xs, Bsb, A_logs, Pbuf, Sbuf);
  k_scan2<<<96, 256, 0, stream>>>(Pbuf, Sbuf, Hinit);
  k_scan3<<<512, 192, 0, stream>>>(delta, xs, Bsb, Csb, A_logs, Ds, Hinit, ys);
  k_combine<<<72, 256, 0, stream>>>(ys, z, out_norm_g, out_norm_b, ya);
  k_prepw<<<2760, 256, 0, stream>>>(w31, w32, w33, w1, out_proj_w,
                                    At1, At2, w1t, woutT);
  k_gemmF<128, 192, 3><<<dim3(36, 2, 2), 256, 0, stream>>>(
      woutT, ya, LL, DD * LL, xm, LL, CIN * LL, x, nullptr, nullptr, nullptr);
  k_pack1<<<972, 256, 0, stream>>>(xm, Bm1);
  k_gemm<384, 144, 1, 0, NPX, 0><<<dim3(18, 6, 6), 256, 0, stream>>>(
      At1, Bm1, Cp1, nullptr, nullptr, nullptr, nullptr, nullptr, nullptr, 0);
  k_gemm<192, 96, 9, 4, NPX, 1><<<dim3(18, 3, 1), 256, 0, stream>>>(
      w1t, Bm1, out, b1, bn_g, bn_b, bn_m, bn_v, prelu_a, 0);
  k_reduce1<<<1728, 256, 0, stream>>>(Cp1, b31, b32, bn_g, bn_b, bn_m, bn_v,
                                      prelu_a, out, t3);
  k_pack2<<<1944, 256, 0, stream>>>(t3, Bm2);
  k_gemm<192, 192, 1, 0, NPX, 0><<<dim3(18, 3, 9), 256, 0, stream>>>(
      At2, Bm2, Cp2, nullptr, nullptr, nullptr, nullptr, nullptr, nullptr, 0);
  k_reduce2<<<864, 256, 0, stream>>>(Cp2, b33, bn_g, bn_b, bn_m, bn_v, prelu_a, out);
}

// Round 7
// 205.869 us; speedup vs baseline: 5.9432x; 1.1020x over previous
//
#include <hip/hip_runtime.h>
#include <math.h>

#define BB_ 2
#define HH 48
#define WW 48
#define LL 2304
#define CIN 96
#define DD 192
#define KK 4
#define NN 16
#define RR 6
#define NCH 64
#define LC 36
#define COUT 192
#define OH 24
#define OW 24
#define OHW 576
#define NPX 1152
#define NTOT 4608
#define EPSF 1e-5f

// ---------------- K1: all prep: LN stats, WgT/sWg/sWb, At3, At1(+w1), At2, woutT
__global__ __launch_bounds__(256) void k_prep(const float* __restrict__ x,
                                              const float* __restrict__ g,
                                              const float* __restrict__ b,
                                              const float* __restrict__ inw,
                                              const float* __restrict__ xpw,
                                              const float* __restrict__ w31,
                                              const float* __restrict__ w32,
                                              const float* __restrict__ w33,
                                              const float* __restrict__ w1,
                                              const float* __restrict__ wout,
                                              float* __restrict__ stats,
                                              float* __restrict__ WgT,
                                              float* __restrict__ sWg,
                                              float* __restrict__ sWb,
                                              float* __restrict__ At3,
                                              float* __restrict__ At1,
                                              float* __restrict__ At2,
                                              float* __restrict__ woutT) {
  int bx = blockIdx.x;
  int tid = threadIdx.x;
  if (bx < 72) {
    int bb = bx / 36; int l0 = (bx % 36) * 64;
    int p = tid >> 2, q = tid & 3;
    int l = l0 + p;
    const float* xp = x + bb * CIN * LL + l;
    float s = 0.f, ss = 0.f;
    for (int c = q; c < CIN; c += 4) { float v = xp[c * LL]; s += v; ss += v * v; }
    s += __shfl_xor(s, 1, 64); s += __shfl_xor(s, 2, 64);
    ss += __shfl_xor(ss, 1, 64); ss += __shfl_xor(ss, 2, 64);
    if (q == 0) {
      float m = s / CIN; float var = ss / CIN - m * m;
      stats[(bb * LL + l) * 2 + 0] = m;
      stats[(bb * LL + l) * 2 + 1] = rsqrtf(var + EPSF);
    }
  } else if (bx == 72) {
    for (int e = tid; e < 2 * DD; e += 256) {
      float swg = 0.f, swb = 0.f;
      for (int c = 0; c < CIN; c++) {
        float w = inw[e * CIN + c];
        float wg = w * g[c];
        WgT[c * 384 + e] = wg;
        swg += wg; swb += w * b[c];
      }
      sWg[e] = swg; sWb[e] = swb;
    }
  } else if (bx < 217) {
    int idx = (bx - 73) * 256 + tid;
    if (idx < 192 * 192) {
      int m = idx % 192, d = idx / 192;
      At3[idx] = (m < 152) ? xpw[m * 192 + d] : 0.f;
    }
  } else if (bx < 2161) {
    int i = (bx - 217) * 256 + tid;
    if (i < 864 * 576) {
      int k = i / 576, m = i % 576;
      float v;
      if (m < 192) v = w31[m * 864 + k];
      else if (m < 384) v = w32[(m - 192) * 864 + k];
      else v = (k % 9 == 4) ? w1[(m - 384) * 96 + k / 9] : 0.f;
      At1[i] = v;
    }
  } else if (bx < 3457) {
    int i = (bx - 2161) * 256 + tid;
    if (i < 1728 * 192) {
      int k = i / 192, m = i % 192;
      At2[i] = w33[m * 1728 + k];
    }
  } else {
    int i = (bx - 3457) * 256 + tid;
    if (i < 192 * 128) {
      int d = i / 128, e = i % 128;
      woutT[i] = (e < 96) ? wout[e * 192 + d] : 0.f;
    }
  }
}

// ---------------- K3: depthwise 3x3 + silu -> xs t-major ×4 + xsl l-major ----
__global__ __launch_bounds__(256) void k_dwconv(const float* __restrict__ xin,
                                                const float* __restrict__ wdw,
                                                const float* __restrict__ bdw,
                                                float* __restrict__ xs,
                                                float* __restrict__ xsl) {
  __shared__ float vt[32 * 50];
  int bid = blockIdx.x;                 // bb*288 + dg*72 + tile
  int bb = bid / 288; int r = bid % 288; int dg = r / 72; int tile = r % 72;
  int l0 = tile * 32;
  int d0 = dg * 48;
  for (int i = threadIdx.x; i < 32 * 48; i += 256) {
    int lj = i & 31, dl = i >> 5;
    int d = d0 + dl;
    int l = l0 + lj;
    int h = l / WW, w = l % WW;
    const float* xp = xin + (bb * DD + d) * LL;
    const float* wq = wdw + d * 9;
    float acc = bdw[d];
#pragma unroll
    for (int kh = 0; kh < 3; kh++) {
      int ih = h + kh - 1; if (ih < 0 || ih >= HH) continue;
#pragma unroll
      for (int kw = 0; kw < 3; kw++) {
        int iw = w + kw - 1; if (iw < 0 || iw >= WW) continue;
        acc += xp[ih * WW + iw] * wq[kh * 3 + kw];
      }
    }
    float v = acc / (1.f + __expf(-acc));
    vt[lj * 50 + dl] = v;
    xsl[(size_t)d * NTOT + bb * LL + l] = v;
  }
  __syncthreads();
  for (int j = threadIdx.x; j < 32 * 48; j += 256) {
    int lj = j / 48, dl = j - lj * 48;
    int d = d0 + dl;
    int l = l0 + lj;
    int h = l / WW, w = l % WW;
    int lt = w * HH + h;
    float v = vt[lj * 50 + dl];
    xs[(((size_t)bb * KK + 0) * LL + l) * DD + d] = v;
    xs[(((size_t)bb * KK + 1) * LL + lt) * DD + d] = v;
    xs[(((size_t)bb * KK + 2) * LL + (LL - 1 - l)) * DD + d] = v;
    xs[(((size_t)bb * KK + 3) * LL + (LL - 1 - lt)) * DD + d] = v;
  }
}

// ---------------- K-dtsplit: C1 -> delta (softplus) + Bsb/Csb, permuted ------
__global__ __launch_bounds__(256) void k_dtsplit(const float* __restrict__ C1,
                                                 const float* __restrict__ dtw,
                                                 const float* __restrict__ dtb,
                                                 float* __restrict__ Bsb,
                                                 float* __restrict__ Csb,
                                                 float* __restrict__ delta) {
  __shared__ float lds[38 * 33];
  int bid = blockIdx.x;                  // bk*72 + tile
  int tile = bid % 72; int bk = bid / 72; int bb = bk >> 2; int k = bk & 3;
  int l0 = tile * 32;
  int tid = threadIdx.x;
  for (int i = tid; i < 38 * 32; i += 256) {
    int r = i >> 5, lj = i & 31;
    lds[r * 33 + lj] = C1[(size_t)(k * 38 + r) * NTOT + bb * LL + l0 + lj];
  }
  __syncthreads();
  for (int i = tid; i < 32 * 16; i += 256) {
    int lj = i >> 4, n = i & 15;
    int l = l0 + lj; int h = l / WW, w = l % WW; int lt = w * HH + h;
    int pos = (k == 0) ? l : (k == 1) ? lt : (k == 2) ? (LL - 1 - l) : (LL - 1 - lt);
    size_t base = ((size_t)bk * LL + pos) * NN + n;
    Bsb[base] = lds[(6 + n) * 33 + lj];
    Csb[base] = lds[(22 + n) * 33 + lj];
  }
  for (int i = tid; i < 32 * 192; i += 256) {
    int lj = i / 192, d = i - lj * 192;
    int l = l0 + lj; int h = l / WW, w = l % WW; int lt = w * HH + h;
    int pos = (k == 0) ? l : (k == 1) ? lt : (k == 2) ? (LL - 1 - l) : (LL - 1 - lt);
    const float* wd = dtw + (k * DD + d) * RR;
    float acc = dtb[k * DD + d];
#pragma unroll
    for (int r = 0; r < RR; r++) acc += wd[r] * lds[r * 33 + lj];
    float sp = acc > 20.f ? acc : log1pf(__expf(acc));
    delta[((size_t)bk * LL + pos) * DD + d] = sp;
  }
}

// ---------------- K5a: chunked scan pass 1 — lane-owns-d, h[16] in VGPR ------
__global__ __launch_bounds__(192) void k_scan1(const float* __restrict__ delta,
                                               const float* __restrict__ xs,
                                               const float* __restrict__ Bsb,
                                               const float* __restrict__ A_logs,
                                               float* __restrict__ Pbuf,
                                               float* __restrict__ Sbuf) {
  __shared__ float Bls[LC * NN];
  int bid = blockIdx.x;
  int c = bid & (NCH - 1); int bk = bid >> 6; int k = bk & 3;
  int t0 = c * LC;
  int d = threadIdx.x;
  const float* bp = Bsb + ((size_t)bk * LL + t0) * NN;
  for (int i = d; i < LC * NN; i += 192) Bls[i] = bp[i];
  float A[NN];
  {
    const float4* ap = (const float4*)(A_logs + (k * DD + d) * NN);
#pragma unroll
    for (int j = 0; j < 4; j++) {
      float4 a4 = ap[j];
      A[4 * j + 0] = -__expf(a4.x); A[4 * j + 1] = -__expf(a4.y);
      A[4 * j + 2] = -__expf(a4.z); A[4 * j + 3] = -__expf(a4.w);
    }
  }
  bool seq = true;
#pragma unroll
  for (int n = 0; n < NN; n++) seq = seq && (fabsf(A[n] + (float)(n + 1)) < 1e-3f);
  float h[NN];
#pragma unroll
  for (int n = 0; n < NN; n++) h[n] = 0.f;
  float sd = 0.f;
  __syncthreads();
  const float* dp = delta + ((size_t)bk * LL + t0) * DD + d;
  const float* xp = xs + ((size_t)bk * LL + t0) * DD + d;
#pragma unroll 2
  for (int t = 0; t < LC; ++t) {
    float dt = dp[t * DD];
    float xv = xp[t * DD];
    float u = dt * xv;
    sd += dt;
    float dA[NN];
    if (seq) {
      float q = __expf(-dt);
      dA[0] = q;
#pragma unroll
      for (int n = 1; n < NN; n++) dA[n] = dA[n - 1] * q;
    } else {
#pragma unroll
      for (int n = 0; n < NN; n++) dA[n] = __expf(dt * A[n]);
    }
    const float4* b4 = (const float4*)&Bls[t * NN];
#pragma unroll
    for (int j = 0; j < 4; j++) {
      float4 bv = b4[j];
      h[4 * j + 0] = dA[4 * j + 0] * h[4 * j + 0] + u * bv.x;
      h[4 * j + 1] = dA[4 * j + 1] * h[4 * j + 1] + u * bv.y;
      h[4 * j + 2] = dA[4 * j + 2] * h[4 * j + 2] + u * bv.z;
      h[4 * j + 3] = dA[4 * j + 3] * h[4 * j + 3] + u * bv.w;
    }
  }
  int chn = (bk * DD + d) * NN;
  float* pp = Pbuf + (size_t)c * 24576 + chn;
  float* sp = Sbuf + (size_t)c * 24576 + chn;
#pragma unroll
  for (int n = 0; n < NN; n++) { pp[n] = __expf(A[n] * sd); sp[n] = h[n]; }
}

// ---------------- K5b: combine chunks ----------------------------------------
__global__ __launch_bounds__(256) void k_scan2(const float* __restrict__ Pbuf,
                                               const float* __restrict__ Sbuf,
                                               float* __restrict__ Hinit) {
  int idx = blockIdx.x * 256 + threadIdx.x;
  float h = 0.f;
  for (int c = 0; c < NCH; c++) {
    Hinit[(size_t)c * 24576 + idx] = h;
    h = Pbuf[(size_t)c * 24576 + idx] * h + Sbuf[(size_t)c * 24576 + idx];
  }
}

// ---------------- K5c: replay + emit ys — lane-owns-d, no shuffles -----------
__global__ __launch_bounds__(192) void k_scan3(const float* __restrict__ delta,
                                               const float* __restrict__ xs,
                                               const float* __restrict__ Bsb,
                                               const float* __restrict__ Csb,
                                               const float* __restrict__ A_logs,
                                               const float* __restrict__ Ds,
                                               const float* __restrict__ Hinit,
                                               float* __restrict__ ys) {
  __shared__ float Bls[LC * NN];
  __shared__ float Cls[LC * NN];
  int bid = blockIdx.x;
  int c = bid & (NCH - 1); int bk = bid >> 6; int k = bk & 3;
  int t0 = c * LC;
  int d = threadIdx.x;
  const float* bp = Bsb + ((size_t)bk * LL + t0) * NN;
  const float* cp = Csb + ((size_t)bk * LL + t0) * NN;
  for (int i = d; i < LC * NN; i += 192) { Bls[i] = bp[i]; Cls[i] = cp[i]; }
  float A[NN];
  {
    const float4* ap = (const float4*)(A_logs + (k * DD + d) * NN);
#pragma unroll
    for (int j = 0; j < 4; j++) {
      float4 a4 = ap[j];
      A[4 * j + 0] = -__expf(a4.x); A[4 * j + 1] = -__expf(a4.y);
      A[4 * j + 2] = -__expf(a4.z); A[4 * j + 3] = -__expf(a4.w);
    }
  }
  bool seq = true;
#pragma unroll
  for (int n = 0; n < NN; n++) seq = seq && (fabsf(A[n] + (float)(n + 1)) < 1e-3f);
  float Dv = Ds[k * DD + d];
  float h[NN];
  {
    const float4* hp = (const float4*)(Hinit + (size_t)c * 24576 + (bk * DD + d) * NN);
#pragma unroll
    for (int j = 0; j < 4; j++) {
      float4 h4 = hp[j];
      h[4 * j + 0] = h4.x; h[4 * j + 1] = h4.y;
      h[4 * j + 2] = h4.z; h[4 * j + 3] = h4.w;
    }
  }
  __syncthreads();
  const float* dp = delta + ((size_t)bk * LL + t0) * DD + d;
  const float* xp = xs + ((size_t)bk * LL + t0) * DD + d;
  float* yp = ys + ((size_t)bk * LL + t0) * DD + d;
#pragma unroll 2
  for (int t = 0; t < LC; ++t) {
    float dt = dp[t * DD];
    float xv = xp[t * DD];
    float u = dt * xv;
    float y = 0.f;
    float dA[NN];
    if (seq) {
      float q = __expf(-dt);
      dA[0] = q;
#pragma unroll
      for (int n = 1; n < NN; n++) dA[n] = dA[n - 1] * q;
    } else {
#pragma unroll
      for (int n = 0; n < NN; n++) dA[n] = __expf(dt * A[n]);
    }
    const float4* b4 = (const float4*)&Bls[t * NN];
    const float4* c4 = (const float4*)&Cls[t * NN];
#pragma unroll
    for (int j = 0; j < 4; j++) {
      float4 bv = b4[j];
      float4 cc = c4[j];
      h[4 * j + 0] = dA[4 * j + 0] * h[4 * j + 0] + u * bv.x;
      h[4 * j + 1] = dA[4 * j + 1] * h[4 * j + 1] + u * bv.y;
      h[4 * j + 2] = dA[4 * j + 2] * h[4 * j + 2] + u * bv.z;
      h[4 * j + 3] = dA[4 * j + 3] * h[4 * j + 3] + u * bv.w;
      y += h[4 * j + 0] * cc.x + h[4 * j + 1] * cc.y
         + h[4 * j + 2] * cc.z + h[4 * j + 3] * cc.w;
    }
    yp[t * DD] = y + Dv * xv;
  }
}

// ---------------- K6a: gather 4 dirs + out_norm LN + silu(z) (144 blocks) ----
__global__ __launch_bounds__(256) void k_combine(const float* __restrict__ ys,
                                                 const float* __restrict__ z,
                                                 const float* __restrict__ ong,
                                                 const float* __restrict__ onb,
                                                 float* __restrict__ ya) {
  __shared__ float yt[32 * 193];
  int bx = blockIdx.x; int bb = bx / 72; int l0 = (bx % 72) * 32;
  int tid = threadIdx.x;
  for (int i = tid; i < 32 * DD; i += 256) {
    int p = i / DD, d = i - p * DD;
    int l = l0 + p; int h = l / WW, w = l - h * WW;
    int t1 = w * HH + h;
    float v = ys[(((size_t)bb * KK + 0) * LL + l) * DD + d]
            + ys[(((size_t)bb * KK + 1) * LL + t1) * DD + d]
            + ys[(((size_t)bb * KK + 2) * LL + (LL - 1 - l)) * DD + d]
            + ys[(((size_t)bb * KK + 3) * LL + (LL - 1 - t1)) * DD + d];
    yt[p * 193 + d] = v;
  }
  __syncthreads();
  int p = tid >> 3, q = tid & 7;
  int l = l0 + p;
  float s = 0.f, ss = 0.f;
  for (int d = q * 24; d < q * 24 + 24; d++) { float v = yt[p * 193 + d]; s += v; ss += v * v; }
  s += __shfl_xor(s, 1, 64); s += __shfl_xor(s, 2, 64); s += __shfl_xor(s, 4, 64);
  ss += __shfl_xor(ss, 1, 64); ss += __shfl_xor(ss, 2, 64); ss += __shfl_xor(ss, 4, 64);
  float m = s / DD, var = ss / DD - m * m;
  float rr = rsqrtf(var + EPSF);
  const float* zp = z + (bb * LL + l) * DD;
  for (int d = q * 24; d < q * 24 + 24; d++) {
    float v = (yt[p * 193 + d] - m) * rr * ong[d] + onb[d];
    float zv = zp[d];
    yt[p * 193 + d] = v * zv / (1.f + __expf(-zv));
  }
  __syncthreads();
  for (int i = tid; i < 32 * DD; i += 256) {
    int d = i >> 5, p2 = i & 31;
    ya[(bb * DD + d) * LL + l0 + p2] = yt[p2 * 193 + d];
  }
}

// ---------------- K8: im2col (stride-2 3x3) over xm --------------------------
__global__ __launch_bounds__(256) void k_pack1(const float* __restrict__ xm,
                                               float* __restrict__ Bm1) {
  int idx4 = blockIdx.x * 256 + threadIdx.x;
  if (idx4 >= 864 * 288) return;
  int k = idx4 / 288; int n = (idx4 % 288) * 4;
  int ci = k / 9, r9 = k % 9, kh = r9 / 3, kw = r9 % 3;
  int bb = n / OHW, rem = n % OHW, oh = rem / OW, ow0 = rem % OW;
  int ih = 2 * oh + kh - 1;
  float4 v = {0.f, 0.f, 0.f, 0.f};
  if (ih >= 0 && ih < HH) {
    const float* base = xm + (bb * CIN + ci) * LL + ih * WW;
    int iw0 = 2 * ow0 + kw - 1;
    v.x = (iw0 >= 0) ? base[iw0] : 0.f;
    v.y = base[iw0 + 2];
    v.z = base[iw0 + 4];
    v.w = base[iw0 + 6];
  }
  *(float4*)&Bm1[k * NPX + n] = v;
}

// ---------------- K9: im2col (stride-1 3x3) over t3 --------------------------
__global__ __launch_bounds__(256) void k_pack2(const float* __restrict__ t3,
                                               float* __restrict__ Bm2) {
  int idx4 = blockIdx.x * 256 + threadIdx.x;
  if (idx4 >= 1728 * 288) return;
  int k = idx4 / 288; int n = (idx4 % 288) * 4;
  int ci = k / 9, r9 = k % 9, kh = r9 / 3, kw = r9 % 3;
  int bb = n / OHW, rem = n % OHW, oh = rem / OW, ow0 = rem % OW;
  int ih = oh + kh - 1;
  float4 v = {0.f, 0.f, 0.f, 0.f};
  if (ih >= 0 && ih < OH) {
    const float* base = t3 + (bb * COUT + ci) * OHW + ih * OW;
    int iw0 = ow0 + kw - 1;
    v.x = (iw0 >= 0) ? base[iw0] : 0.f;
    v.y = base[iw0 + 1];
    v.z = base[iw0 + 2];
    v.w = (iw0 + 3 < OW) ? base[iw0 + 3] : 0.f;
  }
  *(float4*)&Bm2[k * NPX + n] = v;
}

// ---------------- K10: tiled GEMM (64x64, 4x4 micro, split-K) ----------------
template<int MT, int KCHUNK, int NB>
__global__ __launch_bounds__(256) void k_gemm(const float* __restrict__ At,
                                              const float* __restrict__ Bm,
                                              float* __restrict__ Cout) {
  __shared__ float As[16][64];
  __shared__ float Bs[16][64];
  int n0 = blockIdx.x * 64;
  int m0 = blockIdx.y * 64;
  int kz = blockIdx.z;
  int k0 = kz * KCHUNK;
  int tid = threadIdx.x;
  int lr = tid >> 4;
  int lc = (tid & 15) * 4;
  int tm = tid >> 4;
  int tn = tid & 15;
  float acc[4][4] = {};
  for (int ks = 0; ks < KCHUNK; ks += 16) {
    int kg = k0 + ks + lr;
    *(float4*)&As[lr][lc] = *(const float4*)&At[kg * MT + m0 + lc];
    *(float4*)&Bs[lr][lc] = *(const float4*)&Bm[(size_t)kg * NB + n0 + lc];
    __syncthreads();
#pragma unroll
    for (int kk = 0; kk < 16; kk++) {
      float4 a = *(float4*)&As[kk][tm * 4];
      float4 b = *(float4*)&Bs[kk][tn * 4];
      acc[0][0] += a.x * b.x; acc[0][1] += a.x * b.y; acc[0][2] += a.x * b.z; acc[0][3] += a.x * b.w;
      acc[1][0] += a.y * b.x; acc[1][1] += a.y * b.y; acc[1][2] += a.y * b.z; acc[1][3] += a.y * b.w;
      acc[2][0] += a.z * b.x; acc[2][1] += a.z * b.y; acc[2][2] += a.z * b.z; acc[2][3] += a.z * b.w;
      acc[3][0] += a.w * b.x; acc[3][1] += a.w * b.y; acc[3][2] += a.w * b.z; acc[3][3] += a.w * b.w;
    }
    __syncthreads();
  }
  float* cp = Cout + ((size_t)kz * MT + m0) * NB + n0;
#pragma unroll
  for (int i = 0; i < 4; i++) {
    float4 v = {acc[i][0], acc[i][1], acc[i][2], acc[i][3]};
    *(float4*)&cp[(size_t)(tm * 4 + i) * NB + tn * 4] = v;
  }
}

// ---------------- K10F: per-batch GEMM with fused epilogues ------------------
// EPI 2: in_proj + LN-fold -> xin rows <192, z rows >=192
// EPI 3: out_proj + residual -> xm (rows <96 valid)
template<int MT, int KD, int EPI>
__global__ __launch_bounds__(256) void k_gemmF(const float* __restrict__ At,
                                               const float* __restrict__ Bm,
                                               int ldb, int boffB,
                                               float* __restrict__ C0,
                                               int ldc, int boffC,
                                               const float* __restrict__ a0,
                                               const float* __restrict__ a1,
                                               const float* __restrict__ a2,
                                               float* __restrict__ a3) {
  __shared__ float As[16][64];
  __shared__ float Bs[16][64];
  int n0 = blockIdx.x * 64;
  int m0 = blockIdx.y * 64;
  int bb = blockIdx.z;
  const float* B = Bm + (size_t)bb * boffB;
  int tid = threadIdx.x;
  int lr = tid >> 4;
  int lc = (tid & 15) * 4;
  int tm = tid >> 4;
  int tn = tid & 15;
  float acc[4][4] = {};
  for (int ks = 0; ks < KD; ks += 16) {
    *(float4*)&As[lr][lc] = *(const float4*)&At[(ks + lr) * MT + m0 + lc];
    *(float4*)&Bs[lr][lc] = *(const float4*)&B[(size_t)(ks + lr) * ldb + n0 + lc];
    __syncthreads();
#pragma unroll
    for (int kk = 0; kk < 16; kk++) {
      float4 a = *(float4*)&As[kk][tm * 4];
      float4 b = *(float4*)&Bs[kk][tn * 4];
      acc[0][0] += a.x * b.x; acc[0][1] += a.x * b.y; acc[0][2] += a.x * b.z; acc[0][3] += a.x * b.w;
      acc[1][0] += a.y * b.x; acc[1][1] += a.y * b.y; acc[1][2] += a.y * b.z; acc[1][3] += a.y * b.w;
      acc[2][0] += a.z * b.x; acc[2][1] += a.z * b.y; acc[2][2] += a.z * b.z; acc[2][3] += a.z * b.w;
      acc[3][0] += a.w * b.x; acc[3][1] += a.w * b.y; acc[3][2] += a.w * b.z; acc[3][3] += a.w * b.w;
    }
    __syncthreads();
  }
  int n = n0 + tn * 4;
  if (EPI == 2) {
    float m_[4], r_[4];
#pragma unroll
    for (int j = 0; j < 4; j++) {
      m_[j] = a0[((size_t)bb * LL + n + j) * 2];
      r_[j] = a0[((size_t)bb * LL + n + j) * 2 + 1];
    }
#pragma unroll
    for (int i = 0; i < 4; i++) {
      int e = m0 + tm * 4 + i;
      float swg = a1[e], swb = a2[e];
      float v0 = r_[0] * (acc[i][0] - m_[0] * swg) + swb;
      float v1 = r_[1] * (acc[i][1] - m_[1] * swg) + swb;
      float v2 = r_[2] * (acc[i][2] - m_[2] * swg) + swb;
      float v3 = r_[3] * (acc[i][3] - m_[3] * swg) + swb;
      if (e < DD) {
        float4 v = {v0, v1, v2, v3};
        *(float4*)&C0[(size_t)bb * boffC + (size_t)e * ldc + n] = v;
      } else {
        a3[((size_t)bb * LL + n + 0) * DD + (e - DD)] = v0;
        a3[((size_t)bb * LL + n + 1) * DD + (e - DD)] = v1;
        a3[((size_t)bb * LL + n + 2) * DD + (e - DD)] = v2;
        a3[((size_t)bb * LL + n + 3) * DD + (e - DD)] = v3;
      }
    }
  } else {
#pragma unroll
    for (int i = 0; i < 4; i++) {
      int e = m0 + tm * 4 + i;
      if (e < CIN) {
        size_t off = (size_t)bb * boffC + (size_t)e * ldc + n;
        float4 xr = *(const float4*)&a0[off];
        float4 v = {acc[i][0] + xr.x, acc[i][1] + xr.y, acc[i][2] + xr.z, acc[i][3] + xr.w};
        *(float4*)&C0[off] = v;
      }
    }
  }
}

// ---------------- K11: reduce split-K: x2-BN / t3 / x1-BN --------------------
__global__ __launch_bounds__(256) void k_reduce1(const float* __restrict__ Cp1,
                                                 const float* __restrict__ b1,
                                                 const float* __restrict__ b31,
                                                 const float* __restrict__ b32,
                                                 const float* __restrict__ bn_g,
                                                 const float* __restrict__ bn_b,
                                                 const float* __restrict__ bn_m,
                                                 const float* __restrict__ bn_v,
                                                 const float* __restrict__ prelu_a,
                                                 float* __restrict__ out,
                                                 float* __restrict__ t3) {
  int idx = blockIdx.x * 256 + threadIdx.x;
  if (idx >= 576 * NPX) return;
  int m = idx / NPX, n = idx % NPX;
  float s = 0.f;
#pragma unroll
  for (int c = 0; c < 6; c++) s += Cp1[(size_t)c * 576 * NPX + idx];
  int bb = n / OHW, o = n % OHW;
  if (m < 192) {
    s += b31[m];
    int cc = 192 + m;
    float scale = rsqrtf(bn_v[cc] + EPSF) * bn_g[cc];
    float v = s * scale + (bn_b[cc] - bn_m[cc] * scale);
    float a = prelu_a[0];
    out[((size_t)bb * 576 + cc) * OHW + o] = v > 0.f ? v : a * v;
  } else if (m < 384) {
    s += b32[m - 192];
    t3[((size_t)bb * COUT + (m - 192)) * OHW + o] = s;
  } else {
    s += b1[m - 384];
    int cc = m - 384;
    float scale = rsqrtf(bn_v[cc] + EPSF) * bn_g[cc];
    float v = s * scale + (bn_b[cc] - bn_m[cc] * scale);
    float a = prelu_a[0];
    out[((size_t)bb * 576 + cc) * OHW + o] = v > 0.f ? v : a * v;
  }
}

// ---------------- K12: reduce split-K for w33 -> out x3 w/ BN ----------------
__global__ __launch_bounds__(256) void k_reduce2(const float* __restrict__ Cp2,
                                                 const float* __restrict__ b33,
                                                 const float* __restrict__ bn_g,
                                                 const float* __restrict__ bn_b,
                                                 const float* __restrict__ bn_m,
                                                 const float* __restrict__ bn_v,
                                                 const float* __restrict__ prelu_a,
                                                 float* __restrict__ out) {
  int idx = blockIdx.x * 256 + threadIdx.x;
  if (idx >= 192 * NPX) return;
  int m = idx / NPX, n = idx % NPX;
  float s = b33[m];
#pragma unroll
  for (int c = 0; c < 9; c++) s += Cp2[(size_t)c * 192 * NPX + idx];
  int bb = n / OHW, o = n % OHW;
  int cc = 384 + m;
  float scale = rsqrtf(bn_v[cc] + EPSF) * bn_g[cc];
  float v = s * scale + (bn_b[cc] - bn_m[cc] * scale);
  float a = prelu_a[0];
  out[((size_t)bb * 576 + cc) * OHW + o] = v > 0.f ? v : a * v;
}

extern "C" void kernel_launch(void* const* d_in, const int* in_sizes, int n_in,
                              void* d_out, int out_size, void* d_ws, size_t ws_size,
                              hipStream_t stream) {
  const float* x        = (const float*)d_in[0];
  const float* ln_g     = (const float*)d_in[1];
  const float* ln_b     = (const float*)d_in[2];
  const float* in_proj_w= (const float*)d_in[3];
  const float* dwconv_w = (const float*)d_in[4];
  const float* dwconv_b = (const float*)d_in[5];
  const float* x_proj_w = (const float*)d_in[6];
  const float* dt_w     = (const float*)d_in[7];
  const float* dt_b     = (const float*)d_in[8];
  const float* A_logs   = (const float*)d_in[9];
  const float* Ds       = (const float*)d_in[10];
  const float* out_norm_g = (const float*)d_in[11];
  const float* out_norm_b = (const float*)d_in[12];
  const float* out_proj_w = (const float*)d_in[13];
  const float* w1  = (const float*)d_in[14];
  const float* b1  = (const float*)d_in[15];
  const float* w31 = (const float*)d_in[16];
  const float* b31 = (const float*)d_in[17];
  const float* w32 = (const float*)d_in[18];
  const float* b32 = (const float*)d_in[19];
  const float* w33 = (const float*)d_in[20];
  const float* b33 = (const float*)d_in[21];
  const float* bn_g = (const float*)d_in[22];
  const float* bn_b = (const float*)d_in[23];
  const float* bn_m = (const float*)d_in[24];
  const float* bn_v = (const float*)d_in[25];
  const float* prelu_a = (const float*)d_in[26];

  // flat, non-aliased workspace layout (ws >= 268 MB; we use ~151 MB)
  float* ws = (float*)d_ws;
  float* stats = ws + 0;          //   9216
  float* WgT   = ws + 16384;      //  36864
  float* sWg   = ws + 65536;      //    384
  float* sWb   = ws + 66048;      //    384
  float* At3   = ws + 98304;      //  36864
  float* At1   = ws + 147456;     // 497664 (864 x 576, w1 folded at center tap)
  float* At2   = ws + 655360;     // 331776
  float* woutT = ws + 1048576;    //  24576
  float* xin   = ws + 2097152;    // 884736
  float* z     = ws + 3145728;    // 884736
  float* xs    = ws + 4194304;    // 3538944
  float* xsl   = ws + 8388608;    // 884736
  float* C1    = ws + 9437184;    // 884736
  float* delta = ws + 10485760;   // 3538944
  float* Bsb   = ws + 14155776;   // 294912
  float* Csb   = ws + 14680064;   // 294912
  float* Pbuf  = ws + 15728640;   // 1572864
  float* Sbuf  = ws + 17301504;   // 1572864
  float* Hinit = ws + 18874368;   // 1572864
  float* ys    = ws + 20971520;   // 3538944
  float* ya    = ws + 25165824;   // 884736
  float* xm    = ws + 26214400;   // 442368
  float* t3    = ws + 27262976;   // 221184
  float* Bm1   = ws + 28311552;   // 995328
  float* Bm2   = ws + 29360128;   // 1990656
  float* Cp1   = ws + 31457280;   // 3981312 (6 x 576 x 1152)
  float* Cp2   = ws + 35651584;   // 1990656
  float* out = (float*)d_out;

  k_prep<<<3553, 256, 0, stream>>>(x, ln_g, ln_b, in_proj_w, x_proj_w,
                                   w31, w32, w33, w1, out_proj_w,
                                   stats, WgT, sWg, sWb, At3, At1, At2, woutT);
  k_gemmF<384, 96, 2><<<dim3(36, 6, 2), 256, 0, stream>>>(
      WgT, x, LL, CIN * LL, xin, LL, DD * LL, stats, sWg, sWb, z);
  k_dwconv<<<576, 256, 0, stream>>>(xin, dwconv_w, dwconv_b, xs, xsl);
  k_gemm<192, 192, NTOT><<<dim3(72, 3, 1), 256, 0, stream>>>(At3, xsl, C1);
  k_dtsplit<<<576, 256, 0, stream>>>(C1, dt_w, dt_b, Bsb, Csb, delta);
  k_scan1<<<512, 192, 0, stream>>>(delta, xs, Bsb, A_logs, Pbuf, Sbuf);
  k_scan2<<<96, 256, 0, stream>>>(Pbuf, Sbuf, Hinit);
  k_scan3<<<512, 192, 0, stream>>>(delta, xs, Bsb, Csb, A_logs, Ds, Hinit, ys);
  k_combine<<<144, 256, 0, stream>>>(ys, z, out_norm_g, out_norm_b, ya);
  k_gemmF<128, 192, 3><<<dim3(36, 2, 2), 256, 0, stream>>>(
      woutT, ya, LL, DD * LL, xm, LL, CIN * LL, x, nullptr, nullptr, nullptr);
  k_pack1<<<972, 256, 0, stream>>>(xm, Bm1);
  k_gemm<576, 144, NPX><<<dim3(18, 9, 6), 256, 0, stream>>>(At1, Bm1, Cp1);
  k_reduce1<<<2592, 256, 0, stream>>>(Cp1, b1, b31, b32, bn_g, bn_b, bn_m, bn_v,
                                      prelu_a, out, t3);
  k_pack2<<<1944, 256, 0, stream>>>(t3, Bm2);
  k_gemm<192, 192, NPX><<<dim3(18, 3, 9), 256, 0, stream>>>(At2, Bm2, Cp2);
  k_reduce2<<<864, 256, 0, stream>>>(Cp2, b33, bn_g, bn_b, bn_m, bn_v, prelu_a, out);
}

// Round 8
// 204.616 us; speedup vs baseline: 5.9796x; 1.0061x over previous
//
#include <hip/hip_runtime.h>
#include <math.h>

#define BB_ 2
#define HH 48
#define WW 48
#define LL 2304
#define CIN 96
#define DD 192
#define KK 4
#define NN 16
#define RR 6
#define NCH 64
#define LC 36
#define COUT 192
#define OH 24
#define OW 24
#define OHW 576
#define NPX 1152
#define NTOT 4608
#define EPSF 1e-5f

// ---------------- K1: all prep: LN stats, WgT, At3, At1 (tiled), At2, woutT --
__global__ __launch_bounds__(256) void k_prep(const float* __restrict__ x,
                                              const float* __restrict__ g,
                                              const float* __restrict__ b,
                                              const float* __restrict__ inw,
                                              const float* __restrict__ xpw,
                                              const float* __restrict__ w31,
                                              const float* __restrict__ w32,
                                              const float* __restrict__ w33,
                                              const float* __restrict__ w1,
                                              const float* __restrict__ wout,
                                              float* __restrict__ stats,
                                              float* __restrict__ WgT,
                                              float* __restrict__ sWg,
                                              float* __restrict__ sWb,
                                              float* __restrict__ At3,
                                              float* __restrict__ At1,
                                              float* __restrict__ At2,
                                              float* __restrict__ woutT) {
  __shared__ float tile[32][33];
  int bx = blockIdx.x;
  int tid = threadIdx.x;
  if (bx < 72) {
    int bb = bx / 36; int l0 = (bx % 36) * 64;
    int p = tid >> 2, q = tid & 3;
    int l = l0 + p;
    const float* xp = x + bb * CIN * LL + l;
    float s = 0.f, ss = 0.f;
    for (int c = q; c < CIN; c += 4) { float v = xp[c * LL]; s += v; ss += v * v; }
    s += __shfl_xor(s, 1, 64); s += __shfl_xor(s, 2, 64);
    ss += __shfl_xor(ss, 1, 64); ss += __shfl_xor(ss, 2, 64);
    if (q == 0) {
      float m = s / CIN; float var = ss / CIN - m * m;
      stats[(bb * LL + l) * 2 + 0] = m;
      stats[(bb * LL + l) * 2 + 1] = rsqrtf(var + EPSF);
    }
  } else if (bx == 72) {
    for (int e = tid; e < 2 * DD; e += 256) {
      float swg = 0.f, swb = 0.f;
      for (int c = 0; c < CIN; c++) {
        float w = inw[e * CIN + c];
        float wg = w * g[c];
        WgT[c * 384 + e] = wg;
        swg += wg; swb += w * b[c];
      }
      sWg[e] = swg; sWb[e] = swb;
    }
  } else if (bx < 218) {
    int idx = (bx - 73) * 256 + tid;
    if (idx < 192 * 192) {
      int m = idx % 192, d = idx / 192;
      At3[idx] = (m < 152) ? xpw[m * 192 + d] : 0.f;
    }
  } else if (bx < 542) {
    // w31 / w32 -> At1 cols [0,192)/(192,384), 32x32 LDS transpose tiles
    int tt = bx - 218;
    const float* srcw = (tt < 162) ? w31 : w32;
    int mofs = (tt < 162) ? 0 : 192;
    if (tt >= 162) tt -= 162;
    int kt = tt / 6, mt = tt % 6;
    int r = tid >> 5, c = tid & 31;
    for (int rr = r; rr < 32; rr += 8)
      tile[rr][c] = srcw[(mt * 32 + rr) * 864 + kt * 32 + c];
    __syncthreads();
    for (int rr = r; rr < 32; rr += 8)
      At1[(kt * 32 + rr) * 576 + mofs + mt * 32 + c] = tile[c][rr];
  } else if (bx < 1190) {
    // w1 folded at center tap into At1 cols [384,576)
    int i = (bx - 542) * 256 + tid;
    if (i < 864 * 192) {
      int k = i / 192, m = i % 192;
      At1[k * 576 + 384 + m] = (k % 9 == 4) ? w1[m * 96 + k / 9] : 0.f;
    }
  } else if (bx < 1514) {
    // w33 -> At2, 32x32 tiles
    int tt = bx - 1190;
    int kt = tt / 6, mt = tt % 6;
    int r = tid >> 5, c = tid & 31;
    for (int rr = r; rr < 32; rr += 8)
      tile[rr][c] = w33[(mt * 32 + rr) * 1728 + kt * 32 + c];
    __syncthreads();
    for (int rr = r; rr < 32; rr += 8)
      At2[(kt * 32 + rr) * 192 + mt * 32 + c] = tile[c][rr];
  } else {
    int i = (bx - 1514) * 256 + tid;
    if (i < 192 * 128) {
      int d = i / 128, e = i % 128;
      woutT[i] = (e < 96) ? wout[e * 192 + d] : 0.f;
    }
  }
}

// ---------------- K3: depthwise 3x3 + silu -> xs (2 layouts) + xsl l-major ---
__global__ __launch_bounds__(256) void k_dwconv(const float* __restrict__ xin,
                                                const float* __restrict__ wdw,
                                                const float* __restrict__ bdw,
                                                float* __restrict__ xs,
                                                float* __restrict__ xsl) {
  __shared__ float vt[32 * 50];
  int bid = blockIdx.x;                 // bb*288 + dg*72 + tile
  int bb = bid / 288; int r = bid % 288; int dg = r / 72; int tile = r % 72;
  int l0 = tile * 32;
  int d0 = dg * 48;
  for (int i = threadIdx.x; i < 32 * 48; i += 256) {
    int lj = i & 31, dl = i >> 5;
    int d = d0 + dl;
    int l = l0 + lj;
    int h = l / WW, w = l % WW;
    const float* xp = xin + (bb * DD + d) * LL;
    const float* wq = wdw + d * 9;
    float acc = bdw[d];
#pragma unroll
    for (int kh = 0; kh < 3; kh++) {
      int ih = h + kh - 1; if (ih < 0 || ih >= HH) continue;
#pragma unroll
      for (int kw = 0; kw < 3; kw++) {
        int iw = w + kw - 1; if (iw < 0 || iw >= WW) continue;
        acc += xp[ih * WW + iw] * wq[kh * 3 + kw];
      }
    }
    float v = acc / (1.f + __expf(-acc));
    vt[lj * 50 + dl] = v;
    xsl[(size_t)d * NTOT + bb * LL + l] = v;
  }
  __syncthreads();
  for (int j = threadIdx.x; j < 32 * 48; j += 256) {
    int lj = j / 48, dl = j - lj * 48;
    int d = d0 + dl;
    int l = l0 + lj;
    int h = l / WW, w = l % WW;
    int lt = w * HH + h;
    float v = vt[lj * 50 + dl];
    xs[((size_t)(bb * 2 + 0) * LL + l) * DD + d] = v;
    xs[((size_t)(bb * 2 + 1) * LL + lt) * DD + d] = v;
  }
}

// ---------------- K-dtsplit: C1 -> delta (softplus) + Bsb/Csb, permuted ------
__global__ __launch_bounds__(256) void k_dtsplit(const float* __restrict__ C1,
                                                 const float* __restrict__ dtw,
                                                 const float* __restrict__ dtb,
                                                 float* __restrict__ Bsb,
                                                 float* __restrict__ Csb,
                                                 float* __restrict__ delta) {
  __shared__ float lds[38 * 33];
  int bid = blockIdx.x;                  // bk*72 + tile
  int tile = bid % 72; int bk = bid / 72; int bb = bk >> 2; int k = bk & 3;
  int l0 = tile * 32;
  int tid = threadIdx.x;
  for (int i = tid; i < 38 * 32; i += 256) {
    int r = i >> 5, lj = i & 31;
    lds[r * 33 + lj] = C1[(size_t)(k * 38 + r) * NTOT + bb * LL + l0 + lj];
  }
  __syncthreads();
  for (int i = tid; i < 32 * 16; i += 256) {
    int lj = i >> 4, n = i & 15;
    int l = l0 + lj; int h = l / WW, w = l % WW; int lt = w * HH + h;
    int pos = (k == 0) ? l : (k == 1) ? lt : (k == 2) ? (LL - 1 - l) : (LL - 1 - lt);
    size_t base = ((size_t)bk * LL + pos) * NN + n;
    Bsb[base] = lds[(6 + n) * 33 + lj];
    Csb[base] = lds[(22 + n) * 33 + lj];
  }
  for (int i = tid; i < 32 * 192; i += 256) {
    int lj = i / 192, d = i - lj * 192;
    int l = l0 + lj; int h = l / WW, w = l % WW; int lt = w * HH + h;
    int pos = (k == 0) ? l : (k == 1) ? lt : (k == 2) ? (LL - 1 - l) : (LL - 1 - lt);
    const float* wd = dtw + (k * DD + d) * RR;
    float acc = dtb[k * DD + d];
#pragma unroll
    for (int r = 0; r < RR; r++) acc += wd[r] * lds[r * 33 + lj];
    float sp = acc > 20.f ? acc : log1pf(__expf(acc));
    delta[((size_t)bk * LL + pos) * DD + d] = sp;
  }
}

// ---------------- K5a: chunked scan pass 1 — lane-owns-d, h[16] in VGPR ------
__global__ __launch_bounds__(192) void k_scan1(const float* __restrict__ delta,
                                               const float* __restrict__ xs,
                                               const float* __restrict__ Bsb,
                                               const float* __restrict__ A_logs,
                                               float* __restrict__ Pbuf,
                                               float* __restrict__ Sbuf) {
  __shared__ float Bls[LC * NN];
  int bid = blockIdx.x;
  int c = bid & (NCH - 1); int bk = bid >> 6; int k = bk & 3; int bb = bk >> 2;
  int t0 = c * LC;
  int d = threadIdx.x;
  const float* bp = Bsb + ((size_t)bk * LL + t0) * NN;
  for (int i = d; i < LC * NN; i += 192) Bls[i] = bp[i];
  float A[NN];
  {
    const float4* ap = (const float4*)(A_logs + (k * DD + d) * NN);
#pragma unroll
    for (int j = 0; j < 4; j++) {
      float4 a4 = ap[j];
      A[4 * j + 0] = -__expf(a4.x); A[4 * j + 1] = -__expf(a4.y);
      A[4 * j + 2] = -__expf(a4.z); A[4 * j + 3] = -__expf(a4.w);
    }
  }
  bool seq = true;
#pragma unroll
  for (int n = 0; n < NN; n++) seq = seq && (fabsf(A[n] + (float)(n + 1)) < 1e-3f);
  float h[NN];
#pragma unroll
  for (int n = 0; n < NN; n++) h[n] = 0.f;
  float sd = 0.f;
  __syncthreads();
  const float* dp = delta + ((size_t)bk * LL + t0) * DD + d;
  const float* xpb = xs + ((size_t)(bb * 2 + (k & 1)) * LL) * DD + d;
  const float* xp; int xstep;
  if (k < 2) { xp = xpb + (size_t)t0 * DD; xstep = DD; }
  else       { xp = xpb + (size_t)(LL - 1 - t0) * DD; xstep = -DD; }
#pragma unroll 2
  for (int t = 0; t < LC; ++t) {
    float dt = dp[t * DD];
    float xv = xp[t * xstep];
    float u = dt * xv;
    sd += dt;
    float dA[NN];
    if (seq) {
      float q = __expf(-dt);
      dA[0] = q;
#pragma unroll
      for (int n = 1; n < NN; n++) dA[n] = dA[n - 1] * q;
    } else {
#pragma unroll
      for (int n = 0; n < NN; n++) dA[n] = __expf(dt * A[n]);
    }
    const float4* b4 = (const float4*)&Bls[t * NN];
#pragma unroll
    for (int j = 0; j < 4; j++) {
      float4 bv = b4[j];
      h[4 * j + 0] = dA[4 * j + 0] * h[4 * j + 0] + u * bv.x;
      h[4 * j + 1] = dA[4 * j + 1] * h[4 * j + 1] + u * bv.y;
      h[4 * j + 2] = dA[4 * j + 2] * h[4 * j + 2] + u * bv.z;
      h[4 * j + 3] = dA[4 * j + 3] * h[4 * j + 3] + u * bv.w;
    }
  }
  int chn = (bk * DD + d) * NN;
  float* pp = Pbuf + (size_t)c * 24576 + chn;
  float* sp = Sbuf + (size_t)c * 24576 + chn;
#pragma unroll
  for (int n = 0; n < NN; n++) { pp[n] = __expf(A[n] * sd); sp[n] = h[n]; }
}

// ---------------- K5b: combine chunks ----------------------------------------
__global__ __launch_bounds__(256) void k_scan2(const float* __restrict__ Pbuf,
                                               const float* __restrict__ Sbuf,
                                               float* __restrict__ Hinit) {
  int idx = blockIdx.x * 256 + threadIdx.x;
  float h = 0.f;
  for (int c = 0; c < NCH; c++) {
    Hinit[(size_t)c * 24576 + idx] = h;
    h = Pbuf[(size_t)c * 24576 + idx] * h + Sbuf[(size_t)c * 24576 + idx];
  }
}

// ---------------- K5c: replay + emit ys — lane-owns-d, no shuffles -----------
__global__ __launch_bounds__(192) void k_scan3(const float* __restrict__ delta,
                                               const float* __restrict__ xs,
                                               const float* __restrict__ Bsb,
                                               const float* __restrict__ Csb,
                                               const float* __restrict__ A_logs,
                                               const float* __restrict__ Ds,
                                               const float* __restrict__ Hinit,
                                               float* __restrict__ ys) {
  __shared__ float Bls[LC * NN];
  __shared__ float Cls[LC * NN];
  int bid = blockIdx.x;
  int c = bid & (NCH - 1); int bk = bid >> 6; int k = bk & 3; int bb = bk >> 2;
  int t0 = c * LC;
  int d = threadIdx.x;
  const float* bp = Bsb + ((size_t)bk * LL + t0) * NN;
  const float* cp = Csb + ((size_t)bk * LL + t0) * NN;
  for (int i = d; i < LC * NN; i += 192) { Bls[i] = bp[i]; Cls[i] = cp[i]; }
  float A[NN];
  {
    const float4* ap = (const float4*)(A_logs + (k * DD + d) * NN);
#pragma unroll
    for (int j = 0; j < 4; j++) {
      float4 a4 = ap[j];
      A[4 * j + 0] = -__expf(a4.x); A[4 * j + 1] = -__expf(a4.y);
      A[4 * j + 2] = -__expf(a4.z); A[4 * j + 3] = -__expf(a4.w);
    }
  }
  bool seq = true;
#pragma unroll
  for (int n = 0; n < NN; n++) seq = seq && (fabsf(A[n] + (float)(n + 1)) < 1e-3f);
  float Dv = Ds[k * DD + d];
  float h[NN];
  {
    const float4* hp = (const float4*)(Hinit + (size_t)c * 24576 + (bk * DD + d) * NN);
#pragma unroll
    for (int j = 0; j < 4; j++) {
      float4 h4 = hp[j];
      h[4 * j + 0] = h4.x; h[4 * j + 1] = h4.y;
      h[4 * j + 2] = h4.z; h[4 * j + 3] = h4.w;
    }
  }
  __syncthreads();
  const float* dp = delta + ((size_t)bk * LL + t0) * DD + d;
  const float* xpb = xs + ((size_t)(bb * 2 + (k & 1)) * LL) * DD + d;
  const float* xp; int xstep;
  if (k < 2) { xp = xpb + (size_t)t0 * DD; xstep = DD; }
  else       { xp = xpb + (size_t)(LL - 1 - t0) * DD; xstep = -DD; }
  float* yp = ys + ((size_t)bk * LL + t0) * DD + d;
#pragma unroll 2
  for (int t = 0; t < LC; ++t) {
    float dt = dp[t * DD];
    float xv = xp[t * xstep];
    float u = dt * xv;
    float y = 0.f;
    float dA[NN];
    if (seq) {
      float q = __expf(-dt);
      dA[0] = q;
#pragma unroll
      for (int n = 1; n < NN; n++) dA[n] = dA[n - 1] * q;
    } else {
#pragma unroll
      for (int n = 0; n < NN; n++) dA[n] = __expf(dt * A[n]);
    }
    const float4* b4 = (const float4*)&Bls[t * NN];
    const float4* c4 = (const float4*)&Cls[t * NN];
#pragma unroll
    for (int j = 0; j < 4; j++) {
      float4 bv = b4[j];
      float4 cc = c4[j];
      h[4 * j + 0] = dA[4 * j + 0] * h[4 * j + 0] + u * bv.x;
      h[4 * j + 1] = dA[4 * j + 1] * h[4 * j + 1] + u * bv.y;
      h[4 * j + 2] = dA[4 * j + 2] * h[4 * j + 2] + u * bv.z;
      h[4 * j + 3] = dA[4 * j + 3] * h[4 * j + 3] + u * bv.w;
      y += h[4 * j + 0] * cc.x + h[4 * j + 1] * cc.y
         + h[4 * j + 2] * cc.z + h[4 * j + 3] * cc.w;
    }
    yp[t * DD] = y + Dv * xv;
  }
}

// ---------------- K6a: gather 4 dirs + out_norm LN + silu(z) -----------------
__global__ __launch_bounds__(256) void k_combine(const float* __restrict__ ys,
                                                 const float* __restrict__ z,
                                                 const float* __restrict__ ong,
                                                 const float* __restrict__ onb,
                                                 float* __restrict__ ya) {
  __shared__ float yt[32 * 193];
  int bx = blockIdx.x; int bb = bx / 72; int l0 = (bx % 72) * 32;
  int tid = threadIdx.x;
  for (int i = tid; i < 32 * DD; i += 256) {
    int p = i / DD, d = i - p * DD;
    int l = l0 + p; int h = l / WW, w = l - h * WW;
    int t1 = w * HH + h;
    float v = ys[(((size_t)bb * KK + 0) * LL + l) * DD + d]
            + ys[(((size_t)bb * KK + 1) * LL + t1) * DD + d]
            + ys[(((size_t)bb * KK + 2) * LL + (LL - 1 - l)) * DD + d]
            + ys[(((size_t)bb * KK + 3) * LL + (LL - 1 - t1)) * DD + d];
    yt[p * 193 + d] = v;
  }
  __syncthreads();
  int p = tid >> 3, q = tid & 7;
  int l = l0 + p;
  float s = 0.f, ss = 0.f;
  for (int d = q * 24; d < q * 24 + 24; d++) { float v = yt[p * 193 + d]; s += v; ss += v * v; }
  s += __shfl_xor(s, 1, 64); s += __shfl_xor(s, 2, 64); s += __shfl_xor(s, 4, 64);
  ss += __shfl_xor(ss, 1, 64); ss += __shfl_xor(ss, 2, 64); ss += __shfl_xor(ss, 4, 64);
  float m = s / DD, var = ss / DD - m * m;
  float rr = rsqrtf(var + EPSF);
  const float* zp = z + (bb * LL + l) * DD;
  for (int d = q * 24; d < q * 24 + 24; d++) {
    float v = (yt[p * 193 + d] - m) * rr * ong[d] + onb[d];
    float zv = zp[d];
    yt[p * 193 + d] = v * zv / (1.f + __expf(-zv));
  }
  __syncthreads();
  for (int i = tid; i < 32 * DD; i += 256) {
    int d = i >> 5, p2 = i & 31;
    ya[(bb * DD + d) * LL + l0 + p2] = yt[p2 * 193 + d];
  }
}

// ---------------- K10: plain tiled GEMM (for x_proj; linear B) ---------------
template<int MT, int KCHUNK, int NB>
__global__ __launch_bounds__(256) void k_gemm(const float* __restrict__ At,
                                              const float* __restrict__ Bm,
                                              float* __restrict__ Cout) {
  __shared__ float As[16][64];
  __shared__ float Bs[16][64];
  int n0 = blockIdx.x * 64;
  int m0 = blockIdx.y * 64;
  int kz = blockIdx.z;
  int k0 = kz * KCHUNK;
  int tid = threadIdx.x;
  int lr = tid >> 4;
  int lc = (tid & 15) * 4;
  int tm = tid >> 4;
  int tn = tid & 15;
  float acc[4][4] = {};
  for (int ks = 0; ks < KCHUNK; ks += 16) {
    int kg = k0 + ks + lr;
    *(float4*)&As[lr][lc] = *(const float4*)&At[kg * MT + m0 + lc];
    *(float4*)&Bs[lr][lc] = *(const float4*)&Bm[(size_t)kg * NB + n0 + lc];
    __syncthreads();
#pragma unroll
    for (int kk = 0; kk < 16; kk++) {
      float4 a = *(float4*)&As[kk][tm * 4];
      float4 b = *(float4*)&Bs[kk][tn * 4];
      acc[0][0] += a.x * b.x; acc[0][1] += a.x * b.y; acc[0][2] += a.x * b.z; acc[0][3] += a.x * b.w;
      acc[1][0] += a.y * b.x; acc[1][1] += a.y * b.y; acc[1][2] += a.y * b.z; acc[1][3] += a.y * b.w;
      acc[2][0] += a.z * b.x; acc[2][1] += a.z * b.y; acc[2][2] += a.z * b.z; acc[2][3] += a.z * b.w;
      acc[3][0] += a.w * b.x; acc[3][1] += a.w * b.y; acc[3][2] += a.w * b.z; acc[3][3] += a.w * b.w;
    }
    __syncthreads();
  }
  float* cp = Cout + ((size_t)kz * MT + m0) * NB + n0;
#pragma unroll
  for (int i = 0; i < 4; i++) {
    float4 v = {acc[i][0], acc[i][1], acc[i][2], acc[i][3]};
    *(float4*)&cp[(size_t)(tm * 4 + i) * NB + tn * 4] = v;
  }
}

// ---------------- K10c: conv GEMM with fused im2col B-gather -----------------
// SRC is (BB, CI, IH, IH); B row k = ci*9+kh*3+kw; col n = bb*576+oh*24+ow
template<int MT, int KCHUNK, int CI, int IH, int STRIDE>
__global__ __launch_bounds__(256) void k_cgemm(const float* __restrict__ At,
                                               const float* __restrict__ SRC,
                                               float* __restrict__ Cout) {
  __shared__ float As[16][64];
  __shared__ float Bs[16][64];
  int n0 = blockIdx.x * 64;
  int m0 = blockIdx.y * 64;
  int kz = blockIdx.z;
  int k0 = kz * KCHUNK;
  int tid = threadIdx.x;
  int lr = tid >> 4;
  int lc = (tid & 15) * 4;
  int tm = tid >> 4;
  int tn = tid & 15;
  // column geometry (constant over ks)
  int n = n0 + lc;
  int bb = n / OHW;
  int rem = n - bb * OHW;
  int oh = rem / OW, ow0 = rem - oh * OW;
  float acc[4][4] = {};
  for (int ks = 0; ks < KCHUNK; ks += 16) {
    int kg = k0 + ks + lr;
    int ci = kg / 9, r9 = kg - ci * 9;
    int kh = r9 / 3, kw = r9 - kh * 3;
    int ih = STRIDE * oh + kh - 1;
    const float* src = SRC + ((size_t)(bb * CI + ci)) * (IH * IH) + ih * IH;
    float bvv[4];
#pragma unroll
    for (int j = 0; j < 4; j++) {
      int iw = STRIDE * (ow0 + j) + kw - 1;
      bvv[j] = (ih >= 0 && ih < IH && iw >= 0 && iw < IH) ? src[iw] : 0.f;
    }
    float4 bv = {bvv[0], bvv[1], bvv[2], bvv[3]};
    *(float4*)&Bs[lr][lc] = bv;
    *(float4*)&As[lr][lc] = *(const float4*)&At[kg * MT + m0 + lc];
    __syncthreads();
#pragma unroll
    for (int kk = 0; kk < 16; kk++) {
      float4 a = *(float4*)&As[kk][tm * 4];
      float4 b = *(float4*)&Bs[kk][tn * 4];
      acc[0][0] += a.x * b.x; acc[0][1] += a.x * b.y; acc[0][2] += a.x * b.z; acc[0][3] += a.x * b.w;
      acc[1][0] += a.y * b.x; acc[1][1] += a.y * b.y; acc[1][2] += a.y * b.z; acc[1][3] += a.y * b.w;
      acc[2][0] += a.z * b.x; acc[2][1] += a.z * b.y; acc[2][2] += a.z * b.z; acc[2][3] += a.z * b.w;
      acc[3][0] += a.w * b.x; acc[3][1] += a.w * b.y; acc[3][2] += a.w * b.z; acc[3][3] += a.w * b.w;
    }
    __syncthreads();
  }
  float* cp = Cout + ((size_t)kz * MT + m0) * NPX + n0;
#pragma unroll
  for (int i = 0; i < 4; i++) {
    float4 v = {acc[i][0], acc[i][1], acc[i][2], acc[i][3]};
    *(float4*)&cp[(size_t)(tm * 4 + i) * NPX + tn * 4] = v;
  }
}

// ---------------- K10F: per-batch GEMM with fused epilogues ------------------
template<int MT, int KD, int EPI>
__global__ __launch_bounds__(256) void k_gemmF(const float* __restrict__ At,
                                               const float* __restrict__ Bm,
                                               int ldb, int boffB,
                                               float* __restrict__ C0,
                                               int ldc, int boffC,
                                               const float* __restrict__ a0,
                                               const float* __restrict__ a1,
                                               const float* __restrict__ a2,
                                               float* __restrict__ a3) {
  __shared__ float As[16][64];
  __shared__ float Bs[16][64];
  int n0 = blockIdx.x * 64;
  int m0 = blockIdx.y * 64;
  int bb = blockIdx.z;
  const float* B = Bm + (size_t)bb * boffB;
  int tid = threadIdx.x;
  int lr = tid >> 4;
  int lc = (tid & 15) * 4;
  int tm = tid >> 4;
  int tn = tid & 15;
  float acc[4][4] = {};
  for (int ks = 0; ks < KD; ks += 16) {
    *(float4*)&As[lr][lc] = *(const float4*)&At[(ks + lr) * MT + m0 + lc];
    *(float4*)&Bs[lr][lc] = *(const float4*)&B[(size_t)(ks + lr) * ldb + n0 + lc];
    __syncthreads();
#pragma unroll
    for (int kk = 0; kk < 16; kk++) {
      float4 a = *(float4*)&As[kk][tm * 4];
      float4 b = *(float4*)&Bs[kk][tn * 4];
      acc[0][0] += a.x * b.x; acc[0][1] += a.x * b.y; acc[0][2] += a.x * b.z; acc[0][3] += a.x * b.w;
      acc[1][0] += a.y * b.x; acc[1][1] += a.y * b.y; acc[1][2] += a.y * b.z; acc[1][3] += a.y * b.w;
      acc[2][0] += a.z * b.x; acc[2][1] += a.z * b.y; acc[2][2] += a.z * b.z; acc[2][3] += a.z * b.w;
      acc[3][0] += a.w * b.x; acc[3][1] += a.w * b.y; acc[3][2] += a.w * b.z; acc[3][3] += a.w * b.w;
    }
    __syncthreads();
  }
  int n = n0 + tn * 4;
  if (EPI == 2) {
    float m_[4], r_[4];
#pragma unroll
    for (int j = 0; j < 4; j++) {
      m_[j] = a0[((size_t)bb * LL + n + j) * 2];
      r_[j] = a0[((size_t)bb * LL + n + j) * 2 + 1];
    }
#pragma unroll
    for (int i = 0; i < 4; i++) {
      int e = m0 + tm * 4 + i;
      float swg = a1[e], swb = a2[e];
      float v0 = r_[0] * (acc[i][0] - m_[0] * swg) + swb;
      float v1 = r_[1] * (acc[i][1] - m_[1] * swg) + swb;
      float v2 = r_[2] * (acc[i][2] - m_[2] * swg) + swb;
      float v3 = r_[3] * (acc[i][3] - m_[3] * swg) + swb;
      if (e < DD) {
        float4 v = {v0, v1, v2, v3};
        *(float4*)&C0[(size_t)bb * boffC + (size_t)e * ldc + n] = v;
      } else {
        a3[((size_t)bb * LL + n + 0) * DD + (e - DD)] = v0;
        a3[((size_t)bb * LL + n + 1) * DD + (e - DD)] = v1;
        a3[((size_t)bb * LL + n + 2) * DD + (e - DD)] = v2;
        a3[((size_t)bb * LL + n + 3) * DD + (e - DD)] = v3;
      }
    }
  } else {
#pragma unroll
    for (int i = 0; i < 4; i++) {
      int e = m0 + tm * 4 + i;
      if (e < CIN) {
        size_t off = (size_t)bb * boffC + (size_t)e * ldc + n;
        float4 xr = *(const float4*)&a0[off];
        float4 v = {acc[i][0] + xr.x, acc[i][1] + xr.y, acc[i][2] + xr.z, acc[i][3] + xr.w};
        *(float4*)&C0[off] = v;
      }
    }
  }
}

// ---------------- K11: reduce split-K: x2-BN / t3 / x1-BN --------------------
__global__ __launch_bounds__(256) void k_reduce1(const float* __restrict__ Cp1,
                                                 const float* __restrict__ b1,
                                                 const float* __restrict__ b31,
                                                 const float* __restrict__ b32,
                                                 const float* __restrict__ bn_g,
                                                 const float* __restrict__ bn_b,
                                                 const float* __restrict__ bn_m,
                                                 const float* __restrict__ bn_v,
                                                 const float* __restrict__ prelu_a,
                                                 float* __restrict__ out,
                                                 float* __restrict__ t3) {
  int idx = blockIdx.x * 256 + threadIdx.x;
  if (idx >= 576 * NPX) return;
  int m = idx / NPX, n = idx % NPX;
  float s = 0.f;
#pragma unroll
  for (int c = 0; c < 6; c++) s += Cp1[(size_t)c * 576 * NPX + idx];
  int bb = n / OHW, o = n % OHW;
  if (m < 192) {
    s += b31[m];
    int cc = 192 + m;
    float scale = rsqrtf(bn_v[cc] + EPSF) * bn_g[cc];
    float v = s * scale + (bn_b[cc] - bn_m[cc] * scale);
    float a = prelu_a[0];
    out[((size_t)bb * 576 + cc) * OHW + o] = v > 0.f ? v : a * v;
  } else if (m < 384) {
    s += b32[m - 192];
    t3[((size_t)bb * COUT + (m - 192)) * OHW + o] = s;
  } else {
    s += b1[m - 384];
    int cc = m - 384;
    float scale = rsqrtf(bn_v[cc] + EPSF) * bn_g[cc];
    float v = s * scale + (bn_b[cc] - bn_m[cc] * scale);
    float a = prelu_a[0];
    out[((size_t)bb * 576 + cc) * OHW + o] = v > 0.f ? v : a * v;
  }
}

// ---------------- K12: reduce split-K for w33 -> out x3 w/ BN ----------------
__global__ __launch_bounds__(256) void k_reduce2(const float* __restrict__ Cp2,
                                                 const float* __restrict__ b33,
                                                 const float* __restrict__ bn_g,
                                                 const float* __restrict__ bn_b,
                                                 const float* __restrict__ bn_m,
                                                 const float* __restrict__ bn_v,
                                                 const float* __restrict__ prelu_a,
                                                 float* __restrict__ out) {
  int idx = blockIdx.x * 256 + threadIdx.x;
  if (idx >= 192 * NPX) return;
  int m = idx / NPX, n = idx % NPX;
  float s = b33[m];
#pragma unroll
  for (int c = 0; c < 9; c++) s += Cp2[(size_t)c * 192 * NPX + idx];
  int bb = n / OHW, o = n % OHW;
  int cc = 384 + m;
  float scale = rsqrtf(bn_v[cc] + EPSF) * bn_g[cc];
  float v = s * scale + (bn_b[cc] - bn_m[cc] * scale);
  float a = prelu_a[0];
  out[((size_t)bb * 576 + cc) * OHW + o] = v > 0.f ? v : a * v;
}

extern "C" void kernel_launch(void* const* d_in, const int* in_sizes, int n_in,
                              void* d_out, int out_size, void* d_ws, size_t ws_size,
                              hipStream_t stream) {
  const float* x        = (const float*)d_in[0];
  const float* ln_g     = (const float*)d_in[1];
  const float* ln_b     = (const float*)d_in[2];
  const float* in_proj_w= (const float*)d_in[3];
  const float* dwconv_w = (const float*)d_in[4];
  const float* dwconv_b = (const float*)d_in[5];
  const float* x_proj_w = (const float*)d_in[6];
  const float* dt_w     = (const float*)d_in[7];
  const float* dt_b     = (const float*)d_in[8];
  const float* A_logs   = (const float*)d_in[9];
  const float* Ds       = (const float*)d_in[10];
  const float* out_norm_g = (const float*)d_in[11];
  const float* out_norm_b = (const float*)d_in[12];
  const float* out_proj_w = (const float*)d_in[13];
  const float* w1  = (const float*)d_in[14];
  const float* b1  = (const float*)d_in[15];
  const float* w31 = (const float*)d_in[16];
  const float* b31 = (const float*)d_in[17];
  const float* w32 = (const float*)d_in[18];
  const float* b32 = (const float*)d_in[19];
  const float* w33 = (const float*)d_in[20];
  const float* b33 = (const float*)d_in[21];
  const float* bn_g = (const float*)d_in[22];
  const float* bn_b = (const float*)d_in[23];
  const float* bn_m = (const float*)d_in[24];
  const float* bn_v = (const float*)d_in[25];
  const float* prelu_a = (const float*)d_in[26];

  float* ws = (float*)d_ws;
  float* stats = ws + 0;          //   9216
  float* WgT   = ws + 16384;      //  36864
  float* sWg   = ws + 65536;      //    384
  float* sWb   = ws + 66048;      //    384
  float* At3   = ws + 98304;      //  36864
  float* At1   = ws + 147456;     // 497664
  float* At2   = ws + 655360;     // 331776
  float* woutT = ws + 1048576;    //  24576
  float* xin   = ws + 2097152;    // 884736
  float* z     = ws + 3145728;    // 884736
  float* xs    = ws + 4194304;    // 1769472 (2 layouts x 2 batch)
  float* xsl   = ws + 8388608;    // 884736
  float* C1    = ws + 9437184;    // 884736
  float* delta = ws + 10485760;   // 3538944
  float* Bsb   = ws + 14155776;   // 294912
  float* Csb   = ws + 14680064;   // 294912
  float* Pbuf  = ws + 15728640;   // 1572864
  float* Sbuf  = ws + 17301504;   // 1572864
  float* Hinit = ws + 18874368;   // 1572864
  float* ys    = ws + 20971520;   // 3538944
  float* ya    = ws + 25165824;   // 884736
  float* xm    = ws + 26214400;   // 442368
  float* t3    = ws + 27262976;   // 221184
  float* Cp1   = ws + 31457280;   // 3981312 (6 x 576 x 1152)
  float* Cp2   = ws + 35651584;   // 1990656 (9 x 192 x 1152)
  float* out = (float*)d_out;

  k_prep<<<1610, 256, 0, stream>>>(x, ln_g, ln_b, in_proj_w, x_proj_w,
                                   w31, w32, w33, w1, out_proj_w,
                                   stats, WgT, sWg, sWb, At3, At1, At2, woutT);
  k_gemmF<384, 96, 2><<<dim3(36, 6, 2), 256, 0, stream>>>(
      WgT, x, LL, CIN * LL, xin, LL, DD * LL, stats, sWg, sWb, z);
  k_dwconv<<<576, 256, 0, stream>>>(xin, dwconv_w, dwconv_b, xs, xsl);
  k_gemm<192, 192, NTOT><<<dim3(72, 3, 1), 256, 0, stream>>>(At3, xsl, C1);
  k_dtsplit<<<576, 256, 0, stream>>>(C1, dt_w, dt_b, Bsb, Csb, delta);
  k_scan1<<<512, 192, 0, stream>>>(delta, xs, Bsb, A_logs, Pbuf, Sbuf);
  k_scan2<<<96, 256, 0, stream>>>(Pbuf, Sbuf, Hinit);
  k_scan3<<<512, 192, 0, stream>>>(delta, xs, Bsb, Csb, A_logs, Ds, Hinit, ys);
  k_combine<<<144, 256, 0, stream>>>(ys, z, out_norm_g, out_norm_b, ya);
  k_gemmF<128, 192, 3><<<dim3(36, 2, 2), 256, 0, stream>>>(
      woutT, ya, LL, DD * LL, xm, LL, CIN * LL, x, nullptr, nullptr, nullptr);
  // conv branch 1+2 (+1x1 folded): M=576, K=864, im2col fused, split-K 6
  k_cgemm<576, 144, CIN, HH, 2><<<dim3(18, 9, 6), 256, 0, stream>>>(At1, xm, Cp1);
  k_reduce1<<<2592, 256, 0, stream>>>(Cp1, b1, b31, b32, bn_g, bn_b, bn_m, bn_v,
                                      prelu_a, out, t3);
  // conv branch 3 stage b: M=192, K=1728, im2col fused, split-K 9
  k_cgemm<192, 192, COUT, OH, 1><<<dim3(18, 3, 9), 256, 0, stream>>>(At2, t3, Cp2);
  k_reduce2<<<864, 256, 0, stream>>>(Cp2, b33, bn_g, bn_b, bn_m, bn_v, prelu_a, out);
}

// Round 9
// 186.799 us; speedup vs baseline: 6.5499x; 1.0954x over previous
//
#include <hip/hip_runtime.h>
#include <math.h>

#define BB_ 2
#define HH 48
#define WW 48
#define LL 2304
#define CIN 96
#define DD 192
#define KK 4
#define NN 16
#define RR 6
#define NCH 96
#define LC 24
#define COUT 192
#define OH 24
#define OW 24
#define OHW 576
#define NPX 1152
#define NTOT 4608
#define EPSF 1e-5f

typedef __attribute__((ext_vector_type(8))) short bf16x8;
typedef __attribute__((ext_vector_type(4))) float f32x4;

__device__ __forceinline__ short f2bf(float f) {
  unsigned u = __float_as_uint(f);
  unsigned r = (u + 0x7fffu + ((u >> 16) & 1u)) >> 16;
  return (short)r;
}

// ---------------- K1: prep: LN stats, WgT, At3, bf16 weights -----------------
__global__ __launch_bounds__(256) void k_prep(const float* __restrict__ x,
                                              const float* __restrict__ g,
                                              const float* __restrict__ b,
                                              const float* __restrict__ inw,
                                              const float* __restrict__ xpw,
                                              const float* __restrict__ w31,
                                              const float* __restrict__ w32,
                                              const float* __restrict__ w33,
                                              const float* __restrict__ w1,
                                              const float* __restrict__ wout,
                                              float* __restrict__ stats,
                                              float* __restrict__ WgT,
                                              float* __restrict__ sWg,
                                              float* __restrict__ sWb,
                                              float* __restrict__ At3,
                                              short* __restrict__ At1b,
                                              short* __restrict__ At2b,
                                              short* __restrict__ woutb) {
  int bx = blockIdx.x;
  int tid = threadIdx.x;
  if (bx < 72) {
    int bb = bx / 36; int l0 = (bx % 36) * 64;
    int p = tid >> 2, q = tid & 3;
    int l = l0 + p;
    const float* xp = x + bb * CIN * LL + l;
    float s = 0.f, ss = 0.f;
    for (int c = q; c < CIN; c += 4) { float v = xp[c * LL]; s += v; ss += v * v; }
    s += __shfl_xor(s, 1, 64); s += __shfl_xor(s, 2, 64);
    ss += __shfl_xor(ss, 1, 64); ss += __shfl_xor(ss, 2, 64);
    if (q == 0) {
      float m = s / CIN; float var = ss / CIN - m * m;
      stats[(bb * LL + l) * 2 + 0] = m;
      stats[(bb * LL + l) * 2 + 1] = rsqrtf(var + EPSF);
    }
  } else if (bx == 72) {
    for (int e = tid; e < 2 * DD; e += 256) {
      float swg = 0.f, swb = 0.f;
      for (int c = 0; c < CIN; c++) {
        float w = inw[e * CIN + c];
        float wg = w * g[c];
        WgT[c * 384 + e] = wg;
        swg += wg; swb += w * b[c];
      }
      sWg[e] = swg; sWb[e] = swb;
    }
  } else if (bx < 217) {
    int idx = (bx - 73) * 256 + tid;
    if (idx < 192 * 192) {
      int m = idx % 192, d = idx / 192;
      At3[idx] = (m < 152) ? xpw[m * 192 + d] : 0.f;
    }
  } else if (bx < 2161) {
    int i = (bx - 217) * 256 + tid;
    if (i < 497664) {                     // At1b[m][k], 576 x 864
      float v;
      if (i < 165888) v = w31[i];
      else if (i < 331776) v = w32[i - 165888];
      else {
        int k = i % 864; int m = i / 864 - 384;
        v = (k % 9 == 4) ? w1[m * 96 + k / 9] : 0.f;
      }
      At1b[i] = f2bf(v);
    }
  } else if (bx < 3457) {
    int i = (bx - 2161) * 256 + tid;
    if (i < 331776) At2b[i] = f2bf(w33[i]);  // At2b[m][k], 192 x 1728
  } else {
    int i = (bx - 3457) * 256 + tid;
    if (i < 18432) woutb[i] = f2bf(wout[i]); // [e=96][d=192]
  }
}

// ---------------- K3: depthwise 3x3 + silu -> xs (2 layouts) + xsl -----------
__global__ __launch_bounds__(256) void k_dwconv(const float* __restrict__ xin,
                                                const float* __restrict__ wdw,
                                                const float* __restrict__ bdw,
                                                float* __restrict__ xs,
                                                float* __restrict__ xsl) {
  __shared__ float vt[32 * 50];
  int bid = blockIdx.x;
  int bb = bid / 288; int r = bid % 288; int dg = r / 72; int tile = r % 72;
  int l0 = tile * 32;
  int d0 = dg * 48;
  for (int i = threadIdx.x; i < 32 * 48; i += 256) {
    int lj = i & 31, dl = i >> 5;
    int d = d0 + dl;
    int l = l0 + lj;
    int h = l / WW, w = l % WW;
    const float* xp = xin + (bb * DD + d) * LL;
    const float* wq = wdw + d * 9;
    float acc = bdw[d];
#pragma unroll
    for (int kh = 0; kh < 3; kh++) {
      int ih = h + kh - 1; if (ih < 0 || ih >= HH) continue;
#pragma unroll
      for (int kw = 0; kw < 3; kw++) {
        int iw = w + kw - 1; if (iw < 0 || iw >= WW) continue;
        acc += xp[ih * WW + iw] * wq[kh * 3 + kw];
      }
    }
    float v = acc / (1.f + __expf(-acc));
    vt[lj * 50 + dl] = v;
    xsl[(size_t)d * NTOT + bb * LL + l] = v;
  }
  __syncthreads();
  for (int j = threadIdx.x; j < 32 * 48; j += 256) {
    int lj = j / 48, dl = j - lj * 48;
    int d = d0 + dl;
    int l = l0 + lj;
    int h = l / WW, w = l % WW;
    int lt = w * HH + h;
    float v = vt[lj * 50 + dl];
    xs[((size_t)(bb * 2 + 0) * LL + l) * DD + d] = v;
    xs[((size_t)(bb * 2 + 1) * LL + lt) * DD + d] = v;
  }
}

// ---------------- K-dtsplit ---------------------------------------------------
__global__ __launch_bounds__(256) void k_dtsplit(const float* __restrict__ C1,
                                                 const float* __restrict__ dtw,
                                                 const float* __restrict__ dtb,
                                                 float* __restrict__ Bsb,
                                                 float* __restrict__ Csb,
                                                 float* __restrict__ delta) {
  __shared__ float lds[38 * 33];
  int bid = blockIdx.x;
  int tile = bid % 72; int bk = bid / 72; int bb = bk >> 2; int k = bk & 3;
  int l0 = tile * 32;
  int tid = threadIdx.x;
  for (int i = tid; i < 38 * 32; i += 256) {
    int r = i >> 5, lj = i & 31;
    lds[r * 33 + lj] = C1[(size_t)(k * 38 + r) * NTOT + bb * LL + l0 + lj];
  }
  __syncthreads();
  for (int i = tid; i < 32 * 16; i += 256) {
    int lj = i >> 4, n = i & 15;
    int l = l0 + lj; int h = l / WW, w = l % WW; int lt = w * HH + h;
    int pos = (k == 0) ? l : (k == 1) ? lt : (k == 2) ? (LL - 1 - l) : (LL - 1 - lt);
    size_t base = ((size_t)bk * LL + pos) * NN + n;
    Bsb[base] = lds[(6 + n) * 33 + lj];
    Csb[base] = lds[(22 + n) * 33 + lj];
  }
  for (int i = tid; i < 32 * 192; i += 256) {
    int lj = i / 192, d = i - lj * 192;
    int l = l0 + lj; int h = l / WW, w = l % WW; int lt = w * HH + h;
    int pos = (k == 0) ? l : (k == 1) ? lt : (k == 2) ? (LL - 1 - l) : (LL - 1 - lt);
    const float* wd = dtw + (k * DD + d) * RR;
    float acc = dtb[k * DD + d];
#pragma unroll
    for (int r = 0; r < RR; r++) acc += wd[r] * lds[r * 33 + lj];
    float sp = acc > 20.f ? acc : log1pf(__expf(acc));
    delta[((size_t)bk * LL + pos) * DD + d] = sp;
  }
}

// ---------------- K5a: scan pass 1 -------------------------------------------
__global__ __launch_bounds__(192) void k_scan1(const float* __restrict__ delta,
                                               const float* __restrict__ xs,
                                               const float* __restrict__ Bsb,
                                               const float* __restrict__ A_logs,
                                               float* __restrict__ Pbuf,
                                               float* __restrict__ Sbuf) {
  __shared__ float Bls[LC * NN];
  int bid = blockIdx.x;
  int c = bid % NCH; int bk = bid / NCH; int k = bk & 3; int bb = bk >> 2;
  int t0 = c * LC;
  int d = threadIdx.x;
  const float* bp = Bsb + ((size_t)bk * LL + t0) * NN;
  for (int i = d; i < LC * NN; i += 192) Bls[i] = bp[i];
  float A[NN];
  {
    const float4* ap = (const float4*)(A_logs + (k * DD + d) * NN);
#pragma unroll
    for (int j = 0; j < 4; j++) {
      float4 a4 = ap[j];
      A[4 * j + 0] = -__expf(a4.x); A[4 * j + 1] = -__expf(a4.y);
      A[4 * j + 2] = -__expf(a4.z); A[4 * j + 3] = -__expf(a4.w);
    }
  }
  bool seq = true;
#pragma unroll
  for (int n = 0; n < NN; n++) seq = seq && (fabsf(A[n] + (float)(n + 1)) < 1e-3f);
  float h[NN];
#pragma unroll
  for (int n = 0; n < NN; n++) h[n] = 0.f;
  float sd = 0.f;
  __syncthreads();
  const float* dp = delta + ((size_t)bk * LL + t0) * DD + d;
  const float* xpb = xs + ((size_t)(bb * 2 + (k & 1)) * LL) * DD + d;
  const float* xp; int xstep;
  if (k < 2) { xp = xpb + (size_t)t0 * DD; xstep = DD; }
  else       { xp = xpb + (size_t)(LL - 1 - t0) * DD; xstep = -DD; }
#pragma unroll 2
  for (int t = 0; t < LC; ++t) {
    float dt = dp[t * DD];
    float xv = xp[t * xstep];
    float u = dt * xv;
    sd += dt;
    float dA[NN];
    if (seq) {
      float q = __expf(-dt);
      float q2 = q * q, q4 = q2 * q2, q8 = q4 * q4;
      dA[0] = q; dA[1] = q2; dA[2] = q2 * q; dA[3] = q4;
      dA[4] = q4 * q; dA[5] = q4 * q2; dA[6] = q4 * dA[2]; dA[7] = q8;
      dA[8] = q8 * q; dA[9] = q8 * q2; dA[10] = q8 * dA[2]; dA[11] = q8 * q4;
      dA[12] = q8 * dA[4]; dA[13] = q8 * dA[5]; dA[14] = q8 * dA[6]; dA[15] = q8 * q8;
    } else {
#pragma unroll
      for (int n = 0; n < NN; n++) dA[n] = __expf(dt * A[n]);
    }
    const float4* b4 = (const float4*)&Bls[t * NN];
#pragma unroll
    for (int j = 0; j < 4; j++) {
      float4 bv = b4[j];
      h[4 * j + 0] = dA[4 * j + 0] * h[4 * j + 0] + u * bv.x;
      h[4 * j + 1] = dA[4 * j + 1] * h[4 * j + 1] + u * bv.y;
      h[4 * j + 2] = dA[4 * j + 2] * h[4 * j + 2] + u * bv.z;
      h[4 * j + 3] = dA[4 * j + 3] * h[4 * j + 3] + u * bv.w;
    }
  }
  int chn = (bk * DD + d) * NN;
  float* pp = Pbuf + (size_t)c * 24576 + chn;
  float* sp = Sbuf + (size_t)c * 24576 + chn;
#pragma unroll
  for (int n = 0; n < NN; n++) { pp[n] = __expf(A[n] * sd); sp[n] = h[n]; }
}

// ---------------- K5b: combine chunks ----------------------------------------
__global__ __launch_bounds__(256) void k_scan2(const float* __restrict__ Pbuf,
                                               const float* __restrict__ Sbuf,
                                               float* __restrict__ Hinit) {
  int idx = blockIdx.x * 256 + threadIdx.x;
  float h = 0.f;
  for (int c = 0; c < NCH; c++) {
    Hinit[(size_t)c * 24576 + idx] = h;
    h = Pbuf[(size_t)c * 24576 + idx] * h + Sbuf[(size_t)c * 24576 + idx];
  }
}

// ---------------- K5c: scan pass 3 -------------------------------------------
__global__ __launch_bounds__(192) void k_scan3(const float* __restrict__ delta,
                                               const float* __restrict__ xs,
                                               const float* __restrict__ Bsb,
                                               const float* __restrict__ Csb,
                                               const float* __restrict__ A_logs,
                                               const float* __restrict__ Ds,
                                               const float* __restrict__ Hinit,
                                               float* __restrict__ ys) {
  __shared__ float Bls[LC * NN];
  __shared__ float Cls[LC * NN];
  int bid = blockIdx.x;
  int c = bid % NCH; int bk = bid / NCH; int k = bk & 3; int bb = bk >> 2;
  int t0 = c * LC;
  int d = threadIdx.x;
  const float* bp = Bsb + ((size_t)bk * LL + t0) * NN;
  const float* cp = Csb + ((size_t)bk * LL + t0) * NN;
  for (int i = d; i < LC * NN; i += 192) { Bls[i] = bp[i]; Cls[i] = cp[i]; }
  float A[NN];
  {
    const float4* ap = (const float4*)(A_logs + (k * DD + d) * NN);
#pragma unroll
    for (int j = 0; j < 4; j++) {
      float4 a4 = ap[j];
      A[4 * j + 0] = -__expf(a4.x); A[4 * j + 1] = -__expf(a4.y);
      A[4 * j + 2] = -__expf(a4.z); A[4 * j + 3] = -__expf(a4.w);
    }
  }
  bool seq = true;
#pragma unroll
  for (int n = 0; n < NN; n++) seq = seq && (fabsf(A[n] + (float)(n + 1)) < 1e-3f);
  float Dv = Ds[k * DD + d];
  float h[NN];
  {
    const float4* hp = (const float4*)(Hinit + (size_t)c * 24576 + (bk * DD + d) * NN);
#pragma unroll
    for (int j = 0; j < 4; j++) {
      float4 h4 = hp[j];
      h[4 * j + 0] = h4.x; h[4 * j + 1] = h4.y;
      h[4 * j + 2] = h4.z; h[4 * j + 3] = h4.w;
    }
  }
  __syncthreads();
  const float* dp = delta + ((size_t)bk * LL + t0) * DD + d;
  const float* xpb = xs + ((size_t)(bb * 2 + (k & 1)) * LL) * DD + d;
  const float* xp; int xstep;
  if (k < 2) { xp = xpb + (size_t)t0 * DD; xstep = DD; }
  else       { xp = xpb + (size_t)(LL - 1 - t0) * DD; xstep = -DD; }
  float* yp = ys + ((size_t)bk * LL + t0) * DD + d;
#pragma unroll 2
  for (int t = 0; t < LC; ++t) {
    float dt = dp[t * DD];
    float xv = xp[t * xstep];
    float u = dt * xv;
    float y = 0.f;
    float dA[NN];
    if (seq) {
      float q = __expf(-dt);
      float q2 = q * q, q4 = q2 * q2, q8 = q4 * q4;
      dA[0] = q; dA[1] = q2; dA[2] = q2 * q; dA[3] = q4;
      dA[4] = q4 * q; dA[5] = q4 * q2; dA[6] = q4 * dA[2]; dA[7] = q8;
      dA[8] = q8 * q; dA[9] = q8 * q2; dA[10] = q8 * dA[2]; dA[11] = q8 * q4;
      dA[12] = q8 * dA[4]; dA[13] = q8 * dA[5]; dA[14] = q8 * dA[6]; dA[15] = q8 * q8;
    } else {
#pragma unroll
      for (int n = 0; n < NN; n++) dA[n] = __expf(dt * A[n]);
    }
    const float4* b4 = (const float4*)&Bls[t * NN];
    const float4* c4 = (const float4*)&Cls[t * NN];
#pragma unroll
    for (int j = 0; j < 4; j++) {
      float4 bv = b4[j];
      float4 cc = c4[j];
      h[4 * j + 0] = dA[4 * j + 0] * h[4 * j + 0] + u * bv.x;
      h[4 * j + 1] = dA[4 * j + 1] * h[4 * j + 1] + u * bv.y;
      h[4 * j + 2] = dA[4 * j + 2] * h[4 * j + 2] + u * bv.z;
      h[4 * j + 3] = dA[4 * j + 3] * h[4 * j + 3] + u * bv.w;
      y += h[4 * j + 0] * cc.x + h[4 * j + 1] * cc.y
         + h[4 * j + 2] * cc.z + h[4 * j + 3] * cc.w;
    }
    yp[t * DD] = y + Dv * xv;
  }
}

// -------- K6: gather + out_norm LN + silu(z) + out_proj + residual -> xm -----
__global__ __launch_bounds__(256) void k_combineF(const float* __restrict__ ys,
                                                  const float* __restrict__ z,
                                                  const float* __restrict__ ong,
                                                  const float* __restrict__ onb,
                                                  const short* __restrict__ Wbf,
                                                  const float* __restrict__ x,
                                                  float* __restrict__ xm) {
  __shared__ float yt[32 * 194];
  __shared__ unsigned Wlu[96 * 98];
  int bx = blockIdx.x; int bb = bx / 72; int l0 = (bx % 72) * 32;
  int tid = threadIdx.x;
  // load out_proj weights (bf16 pairs) into padded LDS
  const unsigned* Wu = (const unsigned*)Wbf;
  for (int i = tid; i < 96 * 96; i += 256) {
    int e = i / 96, d2 = i - e * 96;
    Wlu[e * 98 + d2] = Wu[i];
  }
  for (int i = tid; i < 32 * DD; i += 256) {
    int p = i / DD, d = i - p * DD;
    int l = l0 + p; int h = l / WW, w = l - h * WW;
    int t1 = w * HH + h;
    float v = ys[(((size_t)bb * KK + 0) * LL + l) * DD + d]
            + ys[(((size_t)bb * KK + 1) * LL + t1) * DD + d]
            + ys[(((size_t)bb * KK + 2) * LL + (LL - 1 - l)) * DD + d]
            + ys[(((size_t)bb * KK + 3) * LL + (LL - 1 - t1)) * DD + d];
    yt[p * 194 + d] = v;
  }
  __syncthreads();
  int p = tid >> 3, q = tid & 7;
  int l = l0 + p;
  float s = 0.f, ss = 0.f;
  for (int d = q * 24; d < q * 24 + 24; d++) { float v = yt[p * 194 + d]; s += v; ss += v * v; }
  s += __shfl_xor(s, 1, 64); s += __shfl_xor(s, 2, 64); s += __shfl_xor(s, 4, 64);
  ss += __shfl_xor(ss, 1, 64); ss += __shfl_xor(ss, 2, 64); ss += __shfl_xor(ss, 4, 64);
  float m = s / DD, var = ss / DD - m * m;
  float rr = rsqrtf(var + EPSF);
  const float* zp = z + (bb * LL + l) * DD;
  for (int d = q * 24; d < q * 24 + 24; d++) {
    float v = (yt[p * 194 + d] - m) * rr * ong[d] + onb[d];
    float zv = zp[d];
    yt[p * 194 + d] = v * zv / (1.f + __expf(-zv));
  }
  __syncthreads();
  // out_proj: thread (p,q) computes e = q*12..+12 for pixel l
  float acc[12];
#pragma unroll
  for (int j = 0; j < 12; j++) acc[j] = 0.f;
  for (int d2 = 0; d2 < 96; d2++) {
    float2 y2 = *(float2*)&yt[p * 194 + 2 * d2];
#pragma unroll
    for (int j = 0; j < 12; j++) {
      unsigned wv = Wlu[(q * 12 + j) * 98 + d2];
      float wlo = __uint_as_float(wv << 16);
      float whi = __uint_as_float(wv & 0xffff0000u);
      acc[j] += y2.x * wlo + y2.y * whi;
    }
  }
#pragma unroll
  for (int j = 0; j < 12; j++) {
    int e = q * 12 + j;
    size_t off = ((size_t)bb * CIN + e) * LL + l;
    xm[off] = x[off] + acc[j];
  }
}

// ---------------- K10: plain fp32 tiled GEMM (x_proj) ------------------------
template<int MT, int KCHUNK, int NB>
__global__ __launch_bounds__(256) void k_gemm(const float* __restrict__ At,
                                              const float* __restrict__ Bm,
                                              float* __restrict__ Cout) {
  __shared__ float As[16][64];
  __shared__ float Bs[16][64];
  int n0 = blockIdx.x * 64;
  int m0 = blockIdx.y * 64;
  int kz = blockIdx.z;
  int k0 = kz * KCHUNK;
  int tid = threadIdx.x;
  int lr = tid >> 4;
  int lc = (tid & 15) * 4;
  int tm = tid >> 4;
  int tn = tid & 15;
  float acc[4][4] = {};
  for (int ks = 0; ks < KCHUNK; ks += 16) {
    int kg = k0 + ks + lr;
    *(float4*)&As[lr][lc] = *(const float4*)&At[kg * MT + m0 + lc];
    *(float4*)&Bs[lr][lc] = *(const float4*)&Bm[(size_t)kg * NB + n0 + lc];
    __syncthreads();
#pragma unroll
    for (int kk = 0; kk < 16; kk++) {
      float4 a = *(float4*)&As[kk][tm * 4];
      float4 b = *(float4*)&Bs[kk][tn * 4];
      acc[0][0] += a.x * b.x; acc[0][1] += a.x * b.y; acc[0][2] += a.x * b.z; acc[0][3] += a.x * b.w;
      acc[1][0] += a.y * b.x; acc[1][1] += a.y * b.y; acc[1][2] += a.y * b.z; acc[1][3] += a.y * b.w;
      acc[2][0] += a.z * b.x; acc[2][1] += a.z * b.y; acc[2][2] += a.z * b.z; acc[2][3] += a.z * b.w;
      acc[3][0] += a.w * b.x; acc[3][1] += a.w * b.y; acc[3][2] += a.w * b.z; acc[3][3] += a.w * b.w;
    }
    __syncthreads();
  }
  float* cp = Cout + ((size_t)kz * MT + m0) * NB + n0;
#pragma unroll
  for (int i = 0; i < 4; i++) {
    float4 v = {acc[i][0], acc[i][1], acc[i][2], acc[i][3]};
    *(float4*)&cp[(size_t)(tm * 4 + i) * NB + tn * 4] = v;
  }
}

// ---------------- K10m: bf16-MFMA conv GEMM with fused im2col ----------------
// A: bf16 [MT][KTOT] (m-major); SRC: fp32 (BB,CI,IH,IH); out: Cp[kz][MT][NPX]
template<int MT, int KTOT, int KCHUNK, int CI, int IH, int STRIDE>
__global__ __launch_bounds__(256) void k_cgemm_mfma(const short* __restrict__ Abf,
                                                    const float* __restrict__ SRC,
                                                    float* __restrict__ Cout) {
  __shared__ short As[64][40];
  __shared__ short Bs[64][40];
  int n0 = blockIdx.x * 64;
  int m0 = blockIdx.y * 64;
  int kz = blockIdx.z;
  int k0 = kz * KCHUNK;
  int tid = threadIdx.x;
  int lane = tid & 63;
  int wv = tid >> 6;               // wave -> m sub-row
  int row16 = lane & 15;
  int kg = lane >> 4;              // 0..3
  int sm = tid >> 2;               // staging row 0..63
  int sk8 = (tid & 3) * 8;         // staging k offset
  int n = n0 + sm;
  int bb = n / OHW; int rem = n - bb * OHW;
  int oh = rem / OW, ow = rem - oh * OW;
  f32x4 acc[4];
#pragma unroll
  for (int i = 0; i < 4; i++) acc[i] = (f32x4){0.f, 0.f, 0.f, 0.f};
  for (int ks = 0; ks < KCHUNK; ks += 32) {
    *(bf16x8*)&As[sm][sk8] =
        *(const bf16x8*)&Abf[(size_t)(m0 + sm) * KTOT + k0 + ks + sk8];
    bf16x8 bvv;
#pragma unroll
    for (int j = 0; j < 8; j++) {
      int k = k0 + ks + sk8 + j;
      int ci = k / 9; int r9 = k - ci * 9;
      int kh = r9 / 3, kw = r9 - kh * 3;
      int ih = STRIDE * oh + kh - 1;
      int iw = STRIDE * ow + kw - 1;
      float v = (ih >= 0 && ih < IH && iw >= 0 && iw < IH)
              ? SRC[((size_t)(bb * CI + ci) * IH + ih) * IH + iw] : 0.f;
      bvv[j] = f2bf(v);
    }
    *(bf16x8*)&Bs[sm][sk8] = bvv;
    __syncthreads();
    bf16x8 a = *(const bf16x8*)&As[wv * 16 + row16][kg * 8];
#pragma unroll
    for (int tn = 0; tn < 4; tn++) {
      bf16x8 b = *(const bf16x8*)&Bs[tn * 16 + row16][kg * 8];
      acc[tn] = __builtin_amdgcn_mfma_f32_16x16x32_bf16(a, b, acc[tn], 0, 0, 0);
    }
    __syncthreads();
  }
#pragma unroll
  for (int tn = 0; tn < 4; tn++) {
    int col = n0 + tn * 16 + row16;
    int rowb = m0 + wv * 16 + kg * 4;
#pragma unroll
    for (int i = 0; i < 4; i++)
      Cout[((size_t)kz * MT + rowb + i) * NPX + col] = acc[tn][i];
  }
}

// ---------------- K10F: per-batch GEMM, LN-folded in_proj epilogue -----------
template<int MT, int KD>
__global__ __launch_bounds__(256) void k_gemmF(const float* __restrict__ At,
                                               const float* __restrict__ Bm,
                                               int ldb, int boffB,
                                               float* __restrict__ C0,
                                               int ldc, int boffC,
                                               const float* __restrict__ a0,
                                               const float* __restrict__ a1,
                                               const float* __restrict__ a2,
                                               float* __restrict__ a3) {
  __shared__ float As[16][64];
  __shared__ float Bs[16][64];
  int n0 = blockIdx.x * 64;
  int m0 = blockIdx.y * 64;
  int bb = blockIdx.z;
  const float* B = Bm + (size_t)bb * boffB;
  int tid = threadIdx.x;
  int lr = tid >> 4;
  int lc = (tid & 15) * 4;
  int tm = tid >> 4;
  int tn = tid & 15;
  float acc[4][4] = {};
  for (int ks = 0; ks < KD; ks += 16) {
    *(float4*)&As[lr][lc] = *(const float4*)&At[(ks + lr) * MT + m0 + lc];
    *(float4*)&Bs[lr][lc] = *(const float4*)&B[(size_t)(ks + lr) * ldb + n0 + lc];
    __syncthreads();
#pragma unroll
    for (int kk = 0; kk < 16; kk++) {
      float4 a = *(float4*)&As[kk][tm * 4];
      float4 b = *(float4*)&Bs[kk][tn * 4];
      acc[0][0] += a.x * b.x; acc[0][1] += a.x * b.y; acc[0][2] += a.x * b.z; acc[0][3] += a.x * b.w;
      acc[1][0] += a.y * b.x; acc[1][1] += a.y * b.y; acc[1][2] += a.y * b.z; acc[1][3] += a.y * b.w;
      acc[2][0] += a.z * b.x; acc[2][1] += a.z * b.y; acc[2][2] += a.z * b.z; acc[2][3] += a.z * b.w;
      acc[3][0] += a.w * b.x; acc[3][1] += a.w * b.y; acc[3][2] += a.w * b.z; acc[3][3] += a.w * b.w;
    }
    __syncthreads();
  }
  int n = n0 + tn * 4;
  float m_[4], r_[4];
#pragma unroll
  for (int j = 0; j < 4; j++) {
    m_[j] = a0[((size_t)bb * LL + n + j) * 2];
    r_[j] = a0[((size_t)bb * LL + n + j) * 2 + 1];
  }
#pragma unroll
  for (int i = 0; i < 4; i++) {
    int e = m0 + tm * 4 + i;
    float swg = a1[e], swb = a2[e];
    float v0 = r_[0] * (acc[i][0] - m_[0] * swg) + swb;
    float v1 = r_[1] * (acc[i][1] - m_[1] * swg) + swb;
    float v2 = r_[2] * (acc[i][2] - m_[2] * swg) + swb;
    float v3 = r_[3] * (acc[i][3] - m_[3] * swg) + swb;
    if (e < DD) {
      float4 v = {v0, v1, v2, v3};
      *(float4*)&C0[(size_t)bb * boffC + (size_t)e * ldc + n] = v;
    } else {
      a3[((size_t)bb * LL + n + 0) * DD + (e - DD)] = v0;
      a3[((size_t)bb * LL + n + 1) * DD + (e - DD)] = v1;
      a3[((size_t)bb * LL + n + 2) * DD + (e - DD)] = v2;
      a3[((size_t)bb * LL + n + 3) * DD + (e - DD)] = v3;
    }
  }
}

// ---------------- K11: reduce split-K (9): x2-BN / t3 / x1-BN ----------------
__global__ __launch_bounds__(256) void k_reduce1(const float* __restrict__ Cp1,
                                                 const float* __restrict__ b1,
                                                 const float* __restrict__ b31,
                                                 const float* __restrict__ b32,
                                                 const float* __restrict__ bn_g,
                                                 const float* __restrict__ bn_b,
                                                 const float* __restrict__ bn_m,
                                                 const float* __restrict__ bn_v,
                                                 const float* __restrict__ prelu_a,
                                                 float* __restrict__ out,
                                                 float* __restrict__ t3) {
  int idx = blockIdx.x * 256 + threadIdx.x;
  if (idx >= 576 * NPX) return;
  int m = idx / NPX, n = idx % NPX;
  float s = 0.f;
#pragma unroll
  for (int c = 0; c < 9; c++) s += Cp1[(size_t)c * 576 * NPX + idx];
  int bb = n / OHW, o = n % OHW;
  if (m < 192) {
    s += b31[m];
    int cc = 192 + m;
    float scale = rsqrtf(bn_v[cc] + EPSF) * bn_g[cc];
    float v = s * scale + (bn_b[cc] - bn_m[cc] * scale);
    float a = prelu_a[0];
    out[((size_t)bb * 576 + cc) * OHW + o] = v > 0.f ? v : a * v;
  } else if (m < 384) {
    s += b32[m - 192];
    t3[((size_t)bb * COUT + (m - 192)) * OHW + o] = s;
  } else {
    s += b1[m - 384];
    int cc = m - 384;
    float scale = rsqrtf(bn_v[cc] + EPSF) * bn_g[cc];
    float v = s * scale + (bn_b[cc] - bn_m[cc] * scale);
    float a = prelu_a[0];
    out[((size_t)bb * 576 + cc) * OHW + o] = v > 0.f ? v : a * v;
  }
}

// ---------------- K12: reduce split-K (9) w33 -> out x3 w/ BN ----------------
__global__ __launch_bounds__(256) void k_reduce2(const float* __restrict__ Cp2,
                                                 const float* __restrict__ b33,
                                                 const float* __restrict__ bn_g,
                                                 const float* __restrict__ bn_b,
                                                 const float* __restrict__ bn_m,
                                                 const float* __restrict__ bn_v,
                                                 const float* __restrict__ prelu_a,
                                                 float* __restrict__ out) {
  int idx = blockIdx.x * 256 + threadIdx.x;
  if (idx >= 192 * NPX) return;
  int m = idx / NPX, n = idx % NPX;
  float s = b33[m];
#pragma unroll
  for (int c = 0; c < 9; c++) s += Cp2[(size_t)c * 192 * NPX + idx];
  int bb = n / OHW, o = n % OHW;
  int cc = 384 + m;
  float scale = rsqrtf(bn_v[cc] + EPSF) * bn_g[cc];
  float v = s * scale + (bn_b[cc] - bn_m[cc] * scale);
  float a = prelu_a[0];
  out[((size_t)bb * 576 + cc) * OHW + o] = v > 0.f ? v : a * v;
}

extern "C" void kernel_launch(void* const* d_in, const int* in_sizes, int n_in,
                              void* d_out, int out_size, void* d_ws, size_t ws_size,
                              hipStream_t stream) {
  const float* x        = (const float*)d_in[0];
  const float* ln_g     = (const float*)d_in[1];
  const float* ln_b     = (const float*)d_in[2];
  const float* in_proj_w= (const float*)d_in[3];
  const float* dwconv_w = (const float*)d_in[4];
  const float* dwconv_b = (const float*)d_in[5];
  const float* x_proj_w = (const float*)d_in[6];
  const float* dt_w     = (const float*)d_in[7];
  const float* dt_b     = (const float*)d_in[8];
  const float* A_logs   = (const float*)d_in[9];
  const float* Ds       = (const float*)d_in[10];
  const float* out_norm_g = (const float*)d_in[11];
  const float* out_norm_b = (const float*)d_in[12];
  const float* out_proj_w = (const float*)d_in[13];
  const float* w1  = (const float*)d_in[14];
  const float* b1  = (const float*)d_in[15];
  const float* w31 = (const float*)d_in[16];
  const float* b31 = (const float*)d_in[17];
  const float* w32 = (const float*)d_in[18];
  const float* b32 = (const float*)d_in[19];
  const float* w33 = (const float*)d_in[20];
  const float* b33 = (const float*)d_in[21];
  const float* bn_g = (const float*)d_in[22];
  const float* bn_b = (const float*)d_in[23];
  const float* bn_m = (const float*)d_in[24];
  const float* bn_v = (const float*)d_in[25];
  const float* prelu_a = (const float*)d_in[26];

  float* ws = (float*)d_ws;
  float* stats = ws + 0;           //   9216
  float* WgT   = ws + 16384;       //  36864
  float* sWg   = ws + 65536;       //    384
  float* sWb   = ws + 66048;       //    384
  float* At3   = ws + 98304;       //  36864
  short* At1b  = (short*)(ws + 147456);   // 497664 shorts
  short* At2b  = (short*)(ws + 397312);   // 331776 shorts
  short* woutb = (short*)(ws + 565248);   //  18432 shorts
  float* xin   = ws + 2097152;     // 884736
  float* z     = ws + 3145728;     // 884736
  float* xs    = ws + 4194304;     // 1769472
  float* xsl   = ws + 8388608;     // 884736
  float* C1    = ws + 9437184;     // 884736
  float* delta = ws + 10485760;    // 3538944
  float* Bsb   = ws + 14155776;    // 294912
  float* Csb   = ws + 14680064;    // 294912
  float* Pbuf  = ws + 15728640;    // 2359296 (96 chunks)
  float* Sbuf  = ws + 18874368;    // 2359296
  float* Hinit = ws + 22020096;    // 2359296
  float* ys    = ws + 25165824;    // 3538944
  float* xm    = ws + 29360128;    // 442368
  float* t3    = ws + 30408704;    // 221184
  float* Cp1   = ws + 31457280;    // 5971968 (9 x 576 x 1152)
  float* Cp2   = ws + 37748736;    // 1990656 (9 x 192 x 1152)
  float* out = (float*)d_out;

  k_prep<<<3529, 256, 0, stream>>>(x, ln_g, ln_b, in_proj_w, x_proj_w,
                                   w31, w32, w33, w1, out_proj_w,
                                   stats, WgT, sWg, sWb, At3, At1b, At2b, woutb);
  k_gemmF<384, 96><<<dim3(36, 6, 2), 256, 0, stream>>>(
      WgT, x, LL, CIN * LL, xin, LL, DD * LL, stats, sWg, sWb, z);
  k_dwconv<<<576, 256, 0, stream>>>(xin, dwconv_w, dwconv_b, xs, xsl);
  k_gemm<192, 192, NTOT><<<dim3(72, 3, 1), 256, 0, stream>>>(At3, xsl, C1);
  k_dtsplit<<<576, 256, 0, stream>>>(C1, dt_w, dt_b, Bsb, Csb, delta);
  k_scan1<<<768, 192, 0, stream>>>(delta, xs, Bsb, A_logs, Pbuf, Sbuf);
  k_scan2<<<96, 256, 0, stream>>>(Pbuf, Sbuf, Hinit);
  k_scan3<<<768, 192, 0, stream>>>(delta, xs, Bsb, Csb, A_logs, Ds, Hinit, ys);
  k_combineF<<<144, 256, 0, stream>>>(ys, z, out_norm_g, out_norm_b, woutb, x, xm);
  // conv branch 1+2 (+1x1 folded): M=576, K=864, split-K 9, bf16 MFMA
  k_cgemm_mfma<576, 864, 96, CIN, HH, 2><<<dim3(18, 9, 9), 256, 0, stream>>>(
      At1b, xm, Cp1);
  k_reduce1<<<2592, 256, 0, stream>>>(Cp1, b1, b31, b32, bn_g, bn_b, bn_m, bn_v,
                                      prelu_a, out, t3);
  // conv branch 3 stage b: M=192, K=1728, split-K 9, bf16 MFMA
  k_cgemm_mfma<192, 1728, 192, COUT, OH, 1><<<dim3(18, 3, 9), 256, 0, stream>>>(
      At2b, t3, Cp2);
  k_reduce2<<<864, 256, 0, stream>>>(Cp2, b33, bn_g, bn_b, bn_m, bn_v, prelu_a, out);
}